// Round 12
// baseline (746.128 us; speedup 1.0000x reference)
//
#include <hip/hip_runtime.h>

// NextBasketEncoder — round 12: item kernel re-split to 1 pair/block with
// wave = head (4 waves): per-wave critical path halves again, LDS 17.6KB ->
// 8 blocks/CU = 32 waves/CU occupancy cap. Rest unchanged from round 11.
// B=1024, O=50, L=20, D=64, H=128, DM=256, FF=512, V=49688.

#define B_ 1024
#define O_ 50
#define CB 512                 // transformer batch chunk (2 chunks)
#define CROWS (CB * O_)        // 25600 rows
#define GCHUNK 512             // GRU batch-row chunk (2 chunks)
#define GROWS (GCHUNK * O_)    // 25600 GI rows per chunk

typedef __attribute__((ext_vector_type(8))) short  short8v;
typedef __attribute__((ext_vector_type(4))) short  short4v;
typedef __attribute__((ext_vector_type(8))) unsigned short ushort8v;
typedef __attribute__((ext_vector_type(4))) unsigned short ushort4v;
typedef __attribute__((ext_vector_type(4))) float f32x4;

__device__ __forceinline__ float sig_(float x)  { return 1.0f / (1.0f + __expf(-x)); }
__device__ __forceinline__ float tanh_(float x) { return 2.0f / (1.0f + __expf(-2.0f * x)) - 1.0f; }

__device__ __forceinline__ unsigned short f2bf(float f) {
  union { float f; unsigned int u; } v; v.f = f;
  unsigned int r = v.u + 0x7FFFu + ((v.u >> 16) & 1u);   // RNE
  return (unsigned short)(r >> 16);
}
__device__ __forceinline__ float bf2f(unsigned short u) {
  union { unsigned int u; float f; } v; v.u = ((unsigned int)u) << 16;
  return v.f;
}
__device__ __forceinline__ unsigned int pk2bf(float lo, float hi) {
  return (unsigned int)f2bf(lo) | ((unsigned int)f2bf(hi) << 16);
}

// ---------------- generic transpose: src[R][C] -> dst[C][R] ----------------
__global__ void k_transpose(const float* __restrict__ src, float* __restrict__ dst, int R, int C) {
  int i = blockIdx.x * 256 + threadIdx.x;
  if (i < R * C) {
    int r = i / C, c = i - r * C;
    dst[c * R + r] = src[i];
  }
}

// ---------------- fp32 -> bf16 elementwise ----------------
__global__ void k_f32bf16(const float* __restrict__ src, unsigned short* __restrict__ dst, int n) {
  int i = blockIdx.x * 256 + threadIdx.x;
  if (i < n) dst[i] = f2bf(src[i]);
}

// ---------------- bias concat: dst[0..383]=a, dst[384..767]=b ---------------
__global__ void k_cat_bias(const float* __restrict__ a, const float* __restrict__ b,
                           float* __restrict__ dst) {
  int i = blockIdx.x * 256 + threadIdx.x;
  if (i < 768) dst[i] = (i < 384) ? a[i] : b[i - 384];
}

// ---------------- 128x128-tile bf16 GEMM: C = A @ W^T + bias (all bf16) -----
template<int RELU>
__global__ __launch_bounds__(256) void k_gemm128(
    const unsigned short* __restrict__ A, int lda,    // [M][lda] bf16
    const unsigned short* __restrict__ W, int K,      // [N][K] bf16
    const float* __restrict__ bias,
    unsigned short* __restrict__ C, int ldc)
{
  __shared__ unsigned short As[128 * 40];
  __shared__ unsigned short Bs[128 * 40];
  int n0 = blockIdx.x * 128, m0 = blockIdx.y * 128;
  int t = threadIdx.x, wv = t >> 6, lane = t & 63;
  int fr = lane & 15, kg = lane >> 4;
  int wr = wv >> 1, wc = wv & 1;
  int sr = t >> 1, sc = (t & 1) * 16;

  f32x4 acc[4][4];
#pragma unroll
  for (int mi = 0; mi < 4; ++mi)
#pragma unroll
    for (int ni = 0; ni < 4; ++ni) acc[mi][ni] = (f32x4){0.f, 0.f, 0.f, 0.f};

  const unsigned short* ga = &A[(size_t)(m0 + sr) * lda + sc];
  const unsigned short* gw = &W[(size_t)(n0 + sr) * K + sc];

  for (int k0 = 0; k0 < K; k0 += 32) {
    ushort8v a0 = *(const ushort8v*)(ga + k0);
    ushort8v a1 = *(const ushort8v*)(ga + k0 + 8);
    ushort8v b0 = *(const ushort8v*)(gw + k0);
    ushort8v b1 = *(const ushort8v*)(gw + k0 + 8);
    __syncthreads();
    *(ushort8v*)&As[sr * 40 + sc]     = a0;
    *(ushort8v*)&As[sr * 40 + sc + 8] = a1;
    *(ushort8v*)&Bs[sr * 40 + sc]     = b0;
    *(ushort8v*)&Bs[sr * 40 + sc + 8] = b1;
    __syncthreads();
    short8v af[4], bfv[4];
#pragma unroll
    for (int mi = 0; mi < 4; ++mi)
      af[mi] = *(const short8v*)&As[(wr * 64 + mi * 16 + fr) * 40 + kg * 8];
#pragma unroll
    for (int ni = 0; ni < 4; ++ni)
      bfv[ni] = *(const short8v*)&Bs[(wc * 64 + ni * 16 + fr) * 40 + kg * 8];
#pragma unroll
    for (int mi = 0; mi < 4; ++mi)
#pragma unroll
      for (int ni = 0; ni < 4; ++ni)
        acc[mi][ni] = __builtin_amdgcn_mfma_f32_16x16x32_bf16(af[mi], bfv[ni], acc[mi][ni], 0, 0, 0);
  }

#pragma unroll
  for (int ni = 0; ni < 4; ++ni) {
    int col = n0 + wc * 64 + ni * 16 + fr;
    float bb = bias[col];
#pragma unroll
    for (int mi = 0; mi < 4; ++mi) {
#pragma unroll
      for (int r = 0; r < 4; ++r) {
        int row = m0 + wr * 64 + mi * 16 + kg * 4 + r;
        float v = acc[mi][ni][r] + bb;
        if (RELU) v = fmaxf(v, 0.f);
        C[(size_t)row * ldc + col] = f2bf(v);
      }
    }
  }
}

// ---------------- fused item attention v3: 1 pair/block, wave = head --------
// 256 thr = 4 waves; wave wv computes QKV n-tiles {wv*3..wv*3+2} then head wv.
// LDS 17.6KB -> 8 blocks/CU = 32 waves/CU. Grid = B*O.
__global__ __launch_bounds__(256) void k_item_fused(
    const int* __restrict__ oh, const unsigned short* __restrict__ embb,
    const unsigned short* __restrict__ Wqkv /*[192][64] bf16*/,
    const float* __restrict__ bqkv,
    const float* __restrict__ wo /*[64][64] f32*/, const float* __restrict__ bob,
    unsigned short* __restrict__ X /*[B*O][64] bf16*/)
{
  __shared__ __align__(16) unsigned short QKs[20][144];   // [seq][Q|K feat]
  __shared__ __align__(16) unsigned short VTs[64][36];    // [V feat][seq]
  __shared__ __align__(16) unsigned short Ps[4][24][36];  // per-wave P; rows 20-23 zero
  __shared__ __align__(16) float mAs[68];

  int t = threadIdx.x, wv = t >> 6, lane = t & 63;
  int fr = lane & 15, lg = lane >> 4;
  int p = blockIdx.x;
  const int* idxp = oh + (size_t)p * 20;

  // one-time zero of MFMA-read padding:
  //  VTs[r][20..35]: 64 rows x 18? -> 16 ushorts = 8 dwords/row; 512 dwords total
  {
    int row = t >> 2, d4 = (t & 3) * 2;                  // 2 dwords per thread
    unsigned int* vz = (unsigned int*)&VTs[row][20];
    vz[d4] = 0; vz[d4 + 1] = 0;
    //  Ps rows 20..23 per wave: 16 rows x 18 dwords = 288 dwords
    if (t < 288) {
      int w2 = t / 72, rem = t - w2 * 72;
      *(unsigned int*)&Ps[w2][20 + rem / 18][(rem - (rem / 18) * 18) * 2] = 0;
    }
  }

  // ---- A-fragments of gathered E: direct bf16 loads (rows >= 20 zero) ----
  short8v aF[2][2];
#pragma unroll
  for (int mt = 0; mt < 2; ++mt) {
    int row = mt * 16 + fr;
    if (row < 20) {
      const unsigned short* er = &embb[(size_t)idxp[row] * 64 + lg * 8];
      aF[mt][0] = *(const short8v*)(er);
      aF[mt][1] = *(const short8v*)(er + 32);
    } else {
      short8v z = {0,0,0,0,0,0,0,0};
      aF[mt][0] = z; aF[mt][1] = z;
    }
  }

  // ---- QKV: wave wv computes n-tiles wv*3 .. wv*3+2 ----
#pragma unroll
  for (int q3 = 0; q3 < 3; ++q3) {
    int nt = wv * 3 + q3;
    const unsigned short* wb = &Wqkv[(size_t)(nt * 16 + fr) * 64 + lg * 8];
    short8v b0 = *(const short8v*)(wb);
    short8v b1 = *(const short8v*)(wb + 32);
    f32x4 a0 = {0.f,0.f,0.f,0.f}, a1 = {0.f,0.f,0.f,0.f};
    a0 = __builtin_amdgcn_mfma_f32_16x16x32_bf16(aF[0][0], b0, a0, 0, 0, 0);
    a0 = __builtin_amdgcn_mfma_f32_16x16x32_bf16(aF[0][1], b1, a0, 0, 0, 0);
    a1 = __builtin_amdgcn_mfma_f32_16x16x32_bf16(aF[1][0], b0, a1, 0, 0, 0);
    a1 = __builtin_amdgcn_mfma_f32_16x16x32_bf16(aF[1][1], b1, a1, 0, 0, 0);
    int n = nt * 16 + fr;
    float bb = bqkv[n];
    if (nt < 8) {
#pragma unroll
      for (int r = 0; r < 4; ++r) {
        QKs[lg * 4 + r][n] = f2bf(a0[r] + bb);
        int row1 = 16 + lg * 4 + r;
        if (row1 < 20) QKs[row1][n] = f2bf(a1[r] + bb);
      }
    } else {
      int c = n - 128;
#pragma unroll
      for (int r = 0; r < 4; ++r) {
        VTs[c][lg * 4 + r] = f2bf(a0[r] + bb);
        int row1 = 16 + lg * 4 + r;
        if (row1 < 20) VTs[c][row1] = f2bf(a1[r] + bb);
      }
    }
  }
  __syncthreads();

  // ---- this wave's head h = wv: S^T = K@Q^T, no-max softmax, AV via MFMA ----
  int h = wv;
  int rj1 = (fr + 16 < 20) ? fr + 16 : 19;   // clamped K/Q row for tile 1
  bool iv1 = fr < 4;                          // query col i=16+fr valid?
  int pr1 = iv1 ? 16 + fr : 20;               // P A-frag row for i-tile 1 (20 = zeros)
  {
    short8v aK0, aK1, bQ0, bQ1;
    {
      short8v z = {0,0,0,0,0,0,0,0};
      aK0 = z; aK1 = z; bQ0 = z; bQ1 = z;
    }
    if (lg < 2) {
      aK0 = *(const short8v*)&QKs[fr][64 + h * 16 + lg * 8];
      aK1 = *(const short8v*)&QKs[rj1][64 + h * 16 + lg * 8];
      bQ0 = *(const short8v*)&QKs[fr][h * 16 + lg * 8];
      bQ1 = *(const short8v*)&QKs[rj1][h * 16 + lg * 8];
    }
    f32x4 s00 = {0.f,0.f,0.f,0.f}, s01 = {0.f,0.f,0.f,0.f};
    f32x4 s10 = {0.f,0.f,0.f,0.f}, s11 = {0.f,0.f,0.f,0.f};
    s00 = __builtin_amdgcn_mfma_f32_16x16x32_bf16(aK0, bQ0, s00, 0, 0, 0);
    s01 = __builtin_amdgcn_mfma_f32_16x16x32_bf16(aK0, bQ1, s01, 0, 0, 0);
    s10 = __builtin_amdgcn_mfma_f32_16x16x32_bf16(aK1, bQ0, s10, 0, 0, 0);
    s11 = __builtin_amdgcn_mfma_f32_16x16x32_bf16(aK1, bQ1, s11, 0, 0, 0);

    float e00[4], e01[4], e10[4], e11[4];
    float d0 = 0.f, d1 = 0.f;
#pragma unroll
    for (int r = 0; r < 4; ++r) {
      int j1 = 16 + lg * 4 + r;
      bool jv1 = j1 < 20;
      float v00 = __expf(0.25f * s00[r]);
      float v01 = iv1 ? __expf(0.25f * s01[r]) : 0.f;
      float v10 = jv1 ? __expf(0.25f * s10[r]) : 0.f;
      float v11 = (jv1 && iv1) ? __expf(0.25f * s11[r]) : 0.f;
      e00[r] = v00; e01[r] = v01; e10[r] = v10; e11[r] = v11;
      d0 += v00 + v10; d1 += v01 + v11;
    }
    d0 += __shfl_xor(d0, 16, 64); d0 += __shfl_xor(d0, 32, 64);
    d1 += __shfl_xor(d1, 16, 64); d1 += __shfl_xor(d1, 32, 64);
    float inv0 = __fdividef(1.f, d0);
    float inv1 = iv1 ? __fdividef(1.f, d1) : 0.f;

    *(unsigned int*)&Ps[wv][fr][lg * 4]          = pk2bf(e00[0]*inv0, e00[1]*inv0);
    *(unsigned int*)&Ps[wv][fr][lg * 4 + 2]      = pk2bf(e00[2]*inv0, e00[3]*inv0);
    *(unsigned int*)&Ps[wv][fr][16 + lg * 4]     = pk2bf(e10[0]*inv0, e10[1]*inv0);
    *(unsigned int*)&Ps[wv][fr][16 + lg * 4 + 2] = pk2bf(e10[2]*inv0, e10[3]*inv0);
    if (iv1) {
      *(unsigned int*)&Ps[wv][16 + fr][lg * 4]          = pk2bf(e01[0]*inv1, e01[1]*inv1);
      *(unsigned int*)&Ps[wv][16 + fr][lg * 4 + 2]      = pk2bf(e01[2]*inv1, e01[3]*inv1);
      *(unsigned int*)&Ps[wv][16 + fr][16 + lg * 4]     = pk2bf(e11[0]*inv1, e11[1]*inv1);
      *(unsigned int*)&Ps[wv][16 + fr][16 + lg * 4 + 2] = pk2bf(e11[2]*inv1, e11[3]*inv1);
    }

    short8v pa0, pa1, bV;
    {
      short4v l0 = *(const short4v*)&Ps[wv][fr][lg * 8];
      short4v h0 = *(const short4v*)&Ps[wv][fr][lg * 8 + 4];
      short4v l1 = *(const short4v*)&Ps[wv][pr1][lg * 8];
      short4v h1 = *(const short4v*)&Ps[wv][pr1][lg * 8 + 4];
      short4v lv = *(const short4v*)&VTs[h * 16 + fr][lg * 8];
      short4v hv = *(const short4v*)&VTs[h * 16 + fr][lg * 8 + 4];
      pa0[0]=l0[0]; pa0[1]=l0[1]; pa0[2]=l0[2]; pa0[3]=l0[3];
      pa0[4]=h0[0]; pa0[5]=h0[1]; pa0[6]=h0[2]; pa0[7]=h0[3];
      pa1[0]=l1[0]; pa1[1]=l1[1]; pa1[2]=l1[2]; pa1[3]=l1[3];
      pa1[4]=h1[0]; pa1[5]=h1[1]; pa1[6]=h1[2]; pa1[7]=h1[3];
      bV[0]=lv[0]; bV[1]=lv[1]; bV[2]=lv[2]; bV[3]=lv[3];
      bV[4]=hv[0]; bV[5]=hv[1]; bV[6]=hv[2]; bV[7]=hv[3];
    }
    f32x4 m20 = {0.f,0.f,0.f,0.f}, m21 = {0.f,0.f,0.f,0.f};
    m20 = __builtin_amdgcn_mfma_f32_16x16x32_bf16(pa0, bV, m20, 0, 0, 0);
    m21 = __builtin_amdgcn_mfma_f32_16x16x32_bf16(pa1, bV, m21, 0, 0, 0);

    float sm = m20[0] + m20[1] + m20[2] + m20[3];
    if (lg == 0) sm += m21[0] + m21[1] + m21[2] + m21[3];   // i=16..19
    sm += __shfl_xor(sm, 16, 64);
    sm += __shfl_xor(sm, 32, 64);
    if (lg == 0) mAs[h * 16 + fr] = sm * 0.05f;
  }
  __syncthreads();

  // ---- out-proj of the mean: 64 threads, bf16 out ----
  if (t < 64) {
    int col = t;
    float acc = bob[col];
    const float* wrow = &wo[(size_t)col * 64];
    for (int k = 0; k < 64; k += 4) {
      float4 m4 = *(const float4*)&mAs[k];
      float4 w4 = *(const float4*)(wrow + k);
      acc += m4.x * w4.x + m4.y * w4.y + m4.z * w4.z + m4.w * w4.w;
    }
    X[(size_t)p * 64 + col] = f2bf(acc);
  }
}

// ---------------- GRU recurrence (bf16 G output) ----------------
__global__ __launch_bounds__(512) void k_gru_mfma(
    const unsigned short* __restrict__ GI,   // [rows][768]: 0-383 fwd, 384-767 bwd
    const unsigned short* __restrict__ whf,
    const unsigned short* __restrict__ whb,
    const float* __restrict__ bh_f, const float* __restrict__ bh_b,
    unsigned short* __restrict__ G /*chunk-offset [GCHUNK*O_][256] bf16*/)
{
  __shared__ unsigned short hsb[16][136];
  __shared__ float ah[4][392];

  int bid = blockIdx.x;
  int dir = bid >> 7;
  int rg  = bid & 127;
  const unsigned short* wh = dir ? whb : whf;
  const float* bh = dir ? bh_b : bh_f;

  int t = threadIdx.x;
  int w = t >> 6, lane = t & 63;
  int fr = lane & 15, kg = lane >> 4;

  short8v bfr[3][4];
#pragma unroll
  for (int n = 0; n < 3; ++n)
#pragma unroll
    for (int kf = 0; kf < 4; ++kf)
      bfr[n][kf] = *(const short8v*)&wh[(size_t)(w * 48 + n * 16 + fr) * 128 + kf * 32 + kg * 8];

  for (int e = t; e < 16 * 136; e += 512) ((unsigned short*)hsb)[e] = 0;

  int grow = t >> 7, gc = t & 127;
  float bh0 = bh[gc], bh1 = bh[128 + gc], bh2 = bh[256 + gc];
  float hold = 0.f;
  const unsigned short* gip = &GI[(size_t)(rg * 4 + grow) * 50 * 768 + dir * 384];
  unsigned short* gout = &G[((size_t)(rg * 4 + grow) * 50) * 256 + dir * 128 + gc];

  __syncthreads();

  int o0 = dir ? 49 : 0;
  unsigned short c0v = gip[(size_t)o0 * 768 + gc];
  unsigned short c1v = gip[(size_t)o0 * 768 + 128 + gc];
  unsigned short c2v = gip[(size_t)o0 * 768 + 256 + gc];

  for (int s = 0; s < 50; ++s) {
    int o  = dir ? 49 - s : s;
    unsigned short n0v = 0, n1v = 0, n2v = 0;
    if (s < 49) {
      int on = dir ? 48 - s : s + 1;
      n0v = gip[(size_t)on * 768 + gc];
      n1v = gip[(size_t)on * 768 + 128 + gc];
      n2v = gip[(size_t)on * 768 + 256 + gc];
    }

    short8v a0 = *(const short8v*)&hsb[fr][0 * 32 + kg * 8];
    short8v a1 = *(const short8v*)&hsb[fr][1 * 32 + kg * 8];
    short8v a2 = *(const short8v*)&hsb[fr][2 * 32 + kg * 8];
    short8v a3 = *(const short8v*)&hsb[fr][3 * 32 + kg * 8];

    f32x4 acc0 = {0.f,0.f,0.f,0.f}, acc1 = {0.f,0.f,0.f,0.f}, acc2 = {0.f,0.f,0.f,0.f};
    acc0 = __builtin_amdgcn_mfma_f32_16x16x32_bf16(a0, bfr[0][0], acc0, 0, 0, 0);
    acc1 = __builtin_amdgcn_mfma_f32_16x16x32_bf16(a0, bfr[1][0], acc1, 0, 0, 0);
    acc2 = __builtin_amdgcn_mfma_f32_16x16x32_bf16(a0, bfr[2][0], acc2, 0, 0, 0);
    acc0 = __builtin_amdgcn_mfma_f32_16x16x32_bf16(a1, bfr[0][1], acc0, 0, 0, 0);
    acc1 = __builtin_amdgcn_mfma_f32_16x16x32_bf16(a1, bfr[1][1], acc1, 0, 0, 0);
    acc2 = __builtin_amdgcn_mfma_f32_16x16x32_bf16(a1, bfr[2][1], acc2, 0, 0, 0);
    acc0 = __builtin_amdgcn_mfma_f32_16x16x32_bf16(a2, bfr[0][2], acc0, 0, 0, 0);
    acc1 = __builtin_amdgcn_mfma_f32_16x16x32_bf16(a2, bfr[1][2], acc1, 0, 0, 0);
    acc2 = __builtin_amdgcn_mfma_f32_16x16x32_bf16(a2, bfr[2][2], acc2, 0, 0, 0);
    acc0 = __builtin_amdgcn_mfma_f32_16x16x32_bf16(a3, bfr[0][3], acc0, 0, 0, 0);
    acc1 = __builtin_amdgcn_mfma_f32_16x16x32_bf16(a3, bfr[1][3], acc1, 0, 0, 0);
    acc2 = __builtin_amdgcn_mfma_f32_16x16x32_bf16(a3, bfr[2][3], acc2, 0, 0, 0);

    if (kg == 0) {
#pragma unroll
      for (int r = 0; r < 4; ++r) {
        ah[r][w * 48 + 0 * 16 + fr] = acc0[r];
        ah[r][w * 48 + 1 * 16 + fr] = acc1[r];
        ah[r][w * 48 + 2 * 16 + fr] = acc2[r];
      }
    }
    __syncthreads();

    float ai0 = bf2f(c0v), ai1 = bf2f(c1v), ai2 = bf2f(c2v);
    float ah0 = ah[grow][gc] + bh0;
    float ah1 = ah[grow][128 + gc] + bh1;
    float ah2 = ah[grow][256 + gc] + bh2;
    float rr = sig_(ai0 + ah0);
    float zz = sig_(ai1 + ah1);
    float nn = tanh_(ai2 + rr * ah2);
    float h2 = (1.f - zz) * nn + zz * hold;
    hold = h2;
    unsigned short hb = f2bf(h2);
    hsb[grow][gc] = hb;
    gout[(size_t)o * 256] = hb;
    c0v = n0v; c1v = n1v; c2v = n2v;
    __syncthreads();
  }
}

// ---------------- transformer attention core (bf16, in-place q-section) -----
__global__ __launch_bounds__(256) void k_attn_core(unsigned short* __restrict__ BIG)
{
  __shared__ __align__(16) float qs[50][68], ks[50][68], vs[50][68];
  __shared__ float P[50][52];
  int bl = blockIdx.x >> 2, h = blockIdx.x & 3;
  int t = threadIdx.x;
  size_t base = (size_t)bl * 50 * 768;
  int hc = h * 64;

  for (int e = t; e < 800; e += 256) {
    int row = e >> 4, c4 = (e & 15) * 4;
    ushort4v q4 = *(const ushort4v*)&BIG[base + (size_t)row * 768 + hc + c4];
    ushort4v k4 = *(const ushort4v*)&BIG[base + (size_t)row * 768 + 256 + hc + c4];
    ushort4v v4 = *(const ushort4v*)&BIG[base + (size_t)row * 768 + 512 + hc + c4];
#pragma unroll
    for (int j = 0; j < 4; ++j) {
      qs[row][c4 + j] = bf2f(q4[j]);
      ks[row][c4 + j] = bf2f(k4[j]);
      vs[row][c4 + j] = bf2f(v4[j]);
    }
  }
  __syncthreads();

  for (int e = t; e < 2500; e += 256) {
    int i = e / 50, j = e - (e / 50) * 50;
    float d = 0.f;
#pragma unroll
    for (int k = 0; k < 64; k += 4) {
      float4 q = *(const float4*)&qs[i][k];
      float4 kk = *(const float4*)&ks[j][k];
      d += q.x * kk.x + q.y * kk.y + q.z * kk.z + q.w * kk.w;
    }
    P[i][j] = d * 0.125f;
  }
  __syncthreads();

  {
    int l = t & 31, rslot = t >> 5;
    for (int i0 = 0; i0 < 50; i0 += 8) {
      int i = i0 + rslot;
      if (i < 50) {
        float p1 = P[i][l];
        float p2 = (l < 18) ? P[i][l + 32] : -1e30f;
        float m = fmaxf(p1, p2);
#pragma unroll
        for (int d2 = 1; d2 < 32; d2 <<= 1) m = fmaxf(m, __shfl_xor(m, d2, 32));
        float e1 = __expf(p1 - m);
        float e2 = (l < 18) ? __expf(p2 - m) : 0.f;
        float s = e1 + e2;
#pragma unroll
        for (int d2 = 1; d2 < 32; d2 <<= 1) s += __shfl_xor(s, d2, 32);
        float inv = __fdividef(1.f, s);
        P[i][l] = e1 * inv;
        if (l < 18) P[i][l + 32] = e2 * inv;
      }
    }
  }
  __syncthreads();
  for (int e = t; e < 1600; e += 256) {
    int i = e >> 5, c2 = (e & 31) * 2;
    float a0 = 0.f, a1 = 0.f;
    for (int j = 0; j < 50; ++j) {
      float pv = P[i][j];
      a0 += pv * vs[j][c2];
      a1 += pv * vs[j][c2 + 1];
    }
    *(unsigned int*)&BIG[base + (size_t)i * 768 + hc + c2] = pk2bf(a0, a1);
  }
}

// ---------------- fused residual + LayerNorm (bf16 I/O, wave per row) -------
__global__ __launch_bounds__(256) void k_ln_res(
    const unsigned short* __restrict__ res, const unsigned short* __restrict__ add,
    int addld, unsigned short* __restrict__ dst,
    const float* __restrict__ g, const float* __restrict__ bt)
{
  int row = blockIdx.x * 4 + (threadIdx.x >> 6);
  int lane = threadIdx.x & 63;
  int c = lane * 4;
  ushort4v rv = *(const ushort4v*)&res[(size_t)row * 256 + c];
  ushort4v av = *(const ushort4v*)&add[(size_t)row * addld + c];
  float x0 = bf2f(rv[0]) + bf2f(av[0]);
  float x1 = bf2f(rv[1]) + bf2f(av[1]);
  float x2 = bf2f(rv[2]) + bf2f(av[2]);
  float x3 = bf2f(rv[3]) + bf2f(av[3]);
  float s = x0 + x1 + x2 + x3;
  float sq = x0 * x0 + x1 * x1 + x2 * x2 + x3 * x3;
#pragma unroll
  for (int d = 1; d < 64; d <<= 1) { s += __shfl_xor(s, d, 64); sq += __shfl_xor(sq, d, 64); }
  float m = s * (1.f / 256.f);
  float var = sq * (1.f / 256.f) - m * m;
  float rs = rsqrtf(var + 1e-5f);
  float4 gv = *(const float4*)&g[c];
  float4 bv = *(const float4*)&bt[c];
  ushort4v ov;
  ov[0] = f2bf((x0 - m) * rs * gv.x + bv.x);
  ov[1] = f2bf((x1 - m) * rs * gv.y + bv.y);
  ov[2] = f2bf((x2 - m) * rs * gv.z + bv.z);
  ov[3] = f2bf((x3 - m) * rs * gv.w + bv.w);
  *(ushort4v*)&dst[(size_t)row * 256 + c] = ov;
}

// ---------------- mean over O (bf16 in, fp32 out) ----------------
__global__ __launch_bounds__(256) void k_reduce_oenc(const unsigned short* __restrict__ H2,
                                                     float* __restrict__ OENC) {
  int b = blockIdx.x, t = threadIdx.x;
  float s = 0.f;
  for (int o = 0; o < 50; ++o) s += bf2f(H2[((size_t)b * 50 + o) * 256 + t]);
  OENC[(size_t)b * 256 + t] = s * 0.02f;
}

// ---------------- temporal encoder + final classifier ----------------
__global__ __launch_bounds__(128) void k_heads(
    const float* __restrict__ daysb, const float* __restrict__ dayss,
    const float* __restrict__ te1_w, const float* __restrict__ te1_b,
    const float* __restrict__ ln1g, const float* __restrict__ ln1b,
    const float* __restrict__ te2_w, const float* __restrict__ te2_b,
    const float* __restrict__ ln2g, const float* __restrict__ ln2b,
    const float* __restrict__ OENC, const float* __restrict__ cWT /*[320][128]*/,
    const float* __restrict__ c_b, const float* __restrict__ clng,
    const float* __restrict__ clnb, float* __restrict__ out)
{
  __shared__ float feat[2];
  __shared__ float s1[32], s2[64], pre[128], stat[2];
  int b = blockIdx.x, t = threadIdx.x;
  if (t == 0) {
    float f0 = 0.f;
    for (int i = 0; i < 10; ++i) f0 += daysb[b * 10 + i];
    feat[0] = f0 * 0.1f;
    feat[1] = dayss[b];
  }
  __syncthreads();
  if (t < 32) s1[t] = te1_b[t] + feat[0] * te1_w[2 * t] + feat[1] * te1_w[2 * t + 1];
  __syncthreads();
  if (t == 0) {
    float s = 0.f; for (int j = 0; j < 32; ++j) s += s1[j];
    float m = s * (1.f / 32.f);
    float v = 0.f; for (int j = 0; j < 32; ++j) { float d = s1[j] - m; v += d * d; }
    stat[0] = m; stat[1] = rsqrtf(v * (1.f / 32.f) + 1e-5f);
  }
  __syncthreads();
  if (t < 32) s1[t] = fmaxf((s1[t] - stat[0]) * stat[1] * ln1g[t] + ln1b[t], 0.f);
  __syncthreads();
  if (t < 64) {
    float a = te2_b[t];
    for (int k = 0; k < 32; ++k) a += s1[k] * te2_w[t * 32 + k];
    s2[t] = a;
  }
  __syncthreads();
  if (t == 0) {
    float s = 0.f; for (int j = 0; j < 64; ++j) s += s2[j];
    float m = s * (1.f / 64.f);
    float v = 0.f; for (int j = 0; j < 64; ++j) { float d = s2[j] - m; v += d * d; }
    stat[0] = m; stat[1] = rsqrtf(v * (1.f / 64.f) + 1e-5f);
  }
  __syncthreads();
  if (t < 64) s2[t] = fmaxf((s2[t] - stat[0]) * stat[1] * ln2g[t] + ln2b[t], 0.f);
  __syncthreads();
  {
    float p = c_b[t];
    const float* oe = OENC + (size_t)b * 256;
    for (int k = 0; k < 256; ++k) p += oe[k] * cWT[k * 128 + t];
    for (int k = 0; k < 64; ++k)  p += s2[k] * cWT[(256 + k) * 128 + t];
    pre[t] = p;
  }
  __syncthreads();
  if (t == 0) {
    float s = 0.f; for (int j = 0; j < 128; ++j) s += pre[j];
    float m = s * (1.f / 128.f);
    float v = 0.f; for (int j = 0; j < 128; ++j) { float d = pre[j] - m; v += d * d; }
    stat[0] = m; stat[1] = rsqrtf(v * (1.f / 128.f) + 1e-5f);
  }
  __syncthreads();
  out[(size_t)b * 128 + t] = fmaxf((pre[t] - stat[0]) * stat[1] * clng[t] + clnb[t], 0.f);
}

// ---------------- host launcher ----------------
extern "C" void kernel_launch(void* const* d_in, const int* in_sizes, int n_in,
                              void* d_out, int out_size, void* d_ws, size_t ws_size,
                              hipStream_t stream)
{
  const int*   oh       = (const int*)d_in[0];
  const float* daysb    = (const float*)d_in[1];
  const float* dayss    = (const float*)d_in[2];
  const float* emb      = (const float*)d_in[3];
  const float* ia_in_w  = (const float*)d_in[4];
  const float* ia_in_b  = (const float*)d_in[5];
  const float* ia_out_w = (const float*)d_in[6];
  const float* ia_out_b = (const float*)d_in[7];
  const float* gf_wi = (const float*)d_in[8];
  const float* gf_wh = (const float*)d_in[9];
  const float* gf_bi = (const float*)d_in[10];
  const float* gf_bh = (const float*)d_in[11];
  const float* gb_wi = (const float*)d_in[12];
  const float* gb_wh = (const float*)d_in[13];
  const float* gb_bi = (const float*)d_in[14];
  const float* gb_bh = (const float*)d_in[15];
  const float* ta_in_w  = (const float*)d_in[16];
  const float* ta_in_b  = (const float*)d_in[17];
  const float* ta_out_w = (const float*)d_in[18];
  const float* ta_out_b = (const float*)d_in[19];
  const float* t_ln1_g = (const float*)d_in[20];
  const float* t_ln1_b = (const float*)d_in[21];
  const float* t_ln2_g = (const float*)d_in[22];
  const float* t_ln2_b = (const float*)d_in[23];
  const float* t_ff1_w = (const float*)d_in[24];
  const float* t_ff1_b = (const float*)d_in[25];
  const float* t_ff2_w = (const float*)d_in[26];
  const float* t_ff2_b = (const float*)d_in[27];
  const float* te1_w = (const float*)d_in[28];
  const float* te1_b = (const float*)d_in[29];
  const float* te_ln1_g = (const float*)d_in[30];
  const float* te_ln1_b = (const float*)d_in[31];
  const float* te2_w = (const float*)d_in[32];
  const float* te2_b = (const float*)d_in[33];
  const float* te_ln2_g = (const float*)d_in[34];
  const float* te_ln2_b = (const float*)d_in[35];
  const float* c_w   = (const float*)d_in[36];
  const float* c_b   = (const float*)d_in[37];
  const float* c_ln_g = (const float*)d_in[38];
  const float* c_ln_b = (const float*)d_in[39];

  float* ws = (float*)d_ws;
  // layout (floats):
  const size_t OFF_GB   = 0;                        // G bf16 [51200][256] = 6,553,600 fl
  const size_t OFF_X    = 6553600;                  // X bf16 [51200][64]  = 1,638,400 fl
  const size_t OFF_S    = OFF_X + 1638400;          // scratch (GI | BIGb) = 9,830,400 fl
  const size_t OFF_OENC = OFF_S + 9830400;          // [B][256] fp32 262,144
  const size_t OW_C     = OFF_OENC + 262144;        // [320][128] 40,960
  const size_t OW_BC    = OW_C + 40960;             // 768
  const size_t OW_BF    = OW_BC + 768;              // bf16 weight pool 342,016 fl
  const size_t OW_EMB   = OW_BF + 342016;           // bf16 emb table 1,590,048 fl
  const size_t TOTAL    = OW_EMB + 1590048;         // 20,258,336 fl = 81.0 MB
  if (ws_size < TOTAL * sizeof(float)) return;

  unsigned short* Gb = (unsigned short*)(ws + OFF_GB);
  unsigned short* Xb = (unsigned short*)(ws + OFF_X);
  float* OENC = ws + OFF_OENC;
  float* w_c  = ws + OW_C;
  float* biascat = ws + OW_BC;
  unsigned short* bfp = (unsigned short*)(ws + OW_BF);
  unsigned short* b_ta_in  = bfp;                  // 196,608
  unsigned short* b_ta_out = b_ta_in + 196608;     //  65,536
  unsigned short* b_ff1    = b_ta_out + 65536;     // 131,072
  unsigned short* b_ff2    = b_ff1 + 131072;       // 131,072
  unsigned short* b_ia_in  = b_ff2 + 131072;       //  12,288
  unsigned short* b_wi_f   = b_ia_in + 12288;      //  24,576 ── Wcat [768][64]
  unsigned short* b_wi_b   = b_wi_f + 24576;       //  24,576 ──┘
  unsigned short* b_wh_f   = b_wi_b + 24576;       //  49,152
  unsigned short* b_wh_b   = b_wh_f + 49152;       //  49,152
  unsigned short* embb = (unsigned short*)(ws + OW_EMB);  // [(V+1)][64] bf16

  // scratch phase views:
  unsigned short* GI   = (unsigned short*)(ws + OFF_S);   // gru: [GROWS][768] bf16
  unsigned short* BIGb = (unsigned short*)(ws + OFF_S);   // transformer: [CROWS][768]

  k_transpose<<<(320 * 128 + 255) / 256, 256, 0, stream>>>(c_w, w_c, 128, 320);
  k_cat_bias<<<3, 256, 0, stream>>>(gf_bi, gb_bi, biascat);
  #define CV(SRC, DST, N) k_f32bf16<<<((N)+255)/256, 256, 0, stream>>>(SRC, DST, N)
  CV(ta_in_w,  b_ta_in,  196608);
  CV(ta_out_w, b_ta_out, 65536);
  CV(t_ff1_w,  b_ff1,    131072);
  CV(t_ff2_w,  b_ff2,    131072);
  CV(ia_in_w,  b_ia_in,  12288);
  CV(gf_wi,    b_wi_f,   24576);
  CV(gb_wi,    b_wi_b,   24576);
  CV(gf_wh,    b_wh_f,   49152);
  CV(gb_wh,    b_wh_b,   49152);
  CV(emb,      embb,     3180096);      // (V+1)*64 bf16 embedding table
  #undef CV

  // ---- item attention: 1 pair per block, wave = head ----
  k_item_fused<<<B_ * O_, 256, 0, stream>>>(oh, embb, b_ia_in, ia_in_b,
                                            ia_out_w, ia_out_b, Xb);

  // ---- bidirectional GRU: 2 chunks; GI via 128-tile bf16 GEMM ----
  for (int gc = 0; gc < B_ / GCHUNK; ++gc) {
    const unsigned short* Xc = Xb + (size_t)gc * GROWS * 64;
    k_gemm128<0><<<dim3(768 / 128, GROWS / 128), 256, 0, stream>>>(
        Xc, 64, b_wi_f /*Wcat [768][64]*/, 64, biascat, GI, 768);
    k_gru_mfma<<<256, 512, 0, stream>>>(GI, b_wh_f, b_wh_b, gf_bh, gb_bh,
                                        Gb + (size_t)gc * GROWS * 256);
  }

  // ---- transformer layer: 2 chunks of CB=512, bf16, in-place in BIGb ----
  for (int c = 0; c < B_ / CB; ++c) {
    unsigned short* Gc = Gb + (size_t)c * CROWS * 256;
    k_gemm128<0><<<dim3(768 / 128, CROWS / 128), 256, 0, stream>>>(
        Gc, 256, b_ta_in, 256, ta_in_b, BIGb, 768);
    k_attn_core<<<CB * 4, 256, 0, stream>>>(BIGb);
    k_gemm128<0><<<dim3(256 / 128, CROWS / 128), 256, 0, stream>>>(
        BIGb, 768, b_ta_out, 256, ta_out_b, BIGb + 256, 768);
    k_ln_res<<<CROWS / 4, 256, 0, stream>>>(Gc, BIGb + 256, 768, Gc, t_ln1_g, t_ln1_b);
    k_gemm128<1><<<dim3(512 / 128, CROWS / 128), 256, 0, stream>>>(
        Gc, 256, b_ff1, 256, t_ff1_b, BIGb, 768);
    k_gemm128<0><<<dim3(256 / 128, CROWS / 128), 256, 0, stream>>>(
        BIGb, 768, b_ff2, 512, t_ff2_b, BIGb + 512, 768);
    k_ln_res<<<CROWS / 4, 256, 0, stream>>>(Gc, BIGb + 512, 768, Gc, t_ln2_g, t_ln2_b);
  }

  k_reduce_oenc<<<B_, 256, 0, stream>>>(Gb, OENC);
  k_heads<<<B_, 128, 0, stream>>>(daysb, dayss, te1_w, te1_b, te_ln1_g, te_ln1_b,
                                  te2_w, te2_b, te_ln2_g, te_ln2_b,
                                  OENC, w_c, c_b, c_ln_g, c_ln_b, (float*)d_out);
}

// Round 13
// 679.265 us; speedup vs baseline: 1.0984x; 1.0984x over previous
//
#include <hip/hip_runtime.h>

// NextBasketEncoder — round 13: revert item kernel to R11 2-pair/block layout
// (+dword-packed V epilogue writes), single-chunk transformer/GRU (CB=1024,
// GCHUNK=1024), reduce_oenc fused into heads. 119.3 MB workspace.
// B=1024, O=50, L=20, D=64, H=128, DM=256, FF=512, V=49688.

#define B_ 1024
#define O_ 50

typedef __attribute__((ext_vector_type(8))) short  short8v;
typedef __attribute__((ext_vector_type(4))) short  short4v;
typedef __attribute__((ext_vector_type(8))) unsigned short ushort8v;
typedef __attribute__((ext_vector_type(4))) unsigned short ushort4v;
typedef __attribute__((ext_vector_type(4))) float f32x4;

__device__ __forceinline__ float sig_(float x)  { return 1.0f / (1.0f + __expf(-x)); }
__device__ __forceinline__ float tanh_(float x) { return 2.0f / (1.0f + __expf(-2.0f * x)) - 1.0f; }

__device__ __forceinline__ unsigned short f2bf(float f) {
  union { float f; unsigned int u; } v; v.f = f;
  unsigned int r = v.u + 0x7FFFu + ((v.u >> 16) & 1u);   // RNE
  return (unsigned short)(r >> 16);
}
__device__ __forceinline__ float bf2f(unsigned short u) {
  union { unsigned int u; float f; } v; v.u = ((unsigned int)u) << 16;
  return v.f;
}
__device__ __forceinline__ unsigned int pk2bf(float lo, float hi) {
  return (unsigned int)f2bf(lo) | ((unsigned int)f2bf(hi) << 16);
}

// ---------------- generic transpose: src[R][C] -> dst[C][R] ----------------
__global__ void k_transpose(const float* __restrict__ src, float* __restrict__ dst, int R, int C) {
  int i = blockIdx.x * 256 + threadIdx.x;
  if (i < R * C) {
    int r = i / C, c = i - r * C;
    dst[c * R + r] = src[i];
  }
}

// ---------------- fp32 -> bf16 elementwise ----------------
__global__ void k_f32bf16(const float* __restrict__ src, unsigned short* __restrict__ dst, int n) {
  int i = blockIdx.x * 256 + threadIdx.x;
  if (i < n) dst[i] = f2bf(src[i]);
}

// ---------------- bias concat: dst[0..383]=a, dst[384..767]=b ---------------
__global__ void k_cat_bias(const float* __restrict__ a, const float* __restrict__ b,
                           float* __restrict__ dst) {
  int i = blockIdx.x * 256 + threadIdx.x;
  if (i < 768) dst[i] = (i < 384) ? a[i] : b[i - 384];
}

// ---------------- 128x128-tile bf16 GEMM: C = A @ W^T + bias (all bf16) -----
template<int RELU>
__global__ __launch_bounds__(256) void k_gemm128(
    const unsigned short* __restrict__ A, int lda,    // [M][lda] bf16
    const unsigned short* __restrict__ W, int K,      // [N][K] bf16
    const float* __restrict__ bias,
    unsigned short* __restrict__ C, int ldc)
{
  __shared__ unsigned short As[128 * 40];
  __shared__ unsigned short Bs[128 * 40];
  int n0 = blockIdx.x * 128, m0 = blockIdx.y * 128;
  int t = threadIdx.x, wv = t >> 6, lane = t & 63;
  int fr = lane & 15, kg = lane >> 4;
  int wr = wv >> 1, wc = wv & 1;
  int sr = t >> 1, sc = (t & 1) * 16;

  f32x4 acc[4][4];
#pragma unroll
  for (int mi = 0; mi < 4; ++mi)
#pragma unroll
    for (int ni = 0; ni < 4; ++ni) acc[mi][ni] = (f32x4){0.f, 0.f, 0.f, 0.f};

  const unsigned short* ga = &A[(size_t)(m0 + sr) * lda + sc];
  const unsigned short* gw = &W[(size_t)(n0 + sr) * K + sc];

  for (int k0 = 0; k0 < K; k0 += 32) {
    ushort8v a0 = *(const ushort8v*)(ga + k0);
    ushort8v a1 = *(const ushort8v*)(ga + k0 + 8);
    ushort8v b0 = *(const ushort8v*)(gw + k0);
    ushort8v b1 = *(const ushort8v*)(gw + k0 + 8);
    __syncthreads();
    *(ushort8v*)&As[sr * 40 + sc]     = a0;
    *(ushort8v*)&As[sr * 40 + sc + 8] = a1;
    *(ushort8v*)&Bs[sr * 40 + sc]     = b0;
    *(ushort8v*)&Bs[sr * 40 + sc + 8] = b1;
    __syncthreads();
    short8v af[4], bfv[4];
#pragma unroll
    for (int mi = 0; mi < 4; ++mi)
      af[mi] = *(const short8v*)&As[(wr * 64 + mi * 16 + fr) * 40 + kg * 8];
#pragma unroll
    for (int ni = 0; ni < 4; ++ni)
      bfv[ni] = *(const short8v*)&Bs[(wc * 64 + ni * 16 + fr) * 40 + kg * 8];
#pragma unroll
    for (int mi = 0; mi < 4; ++mi)
#pragma unroll
      for (int ni = 0; ni < 4; ++ni)
        acc[mi][ni] = __builtin_amdgcn_mfma_f32_16x16x32_bf16(af[mi], bfv[ni], acc[mi][ni], 0, 0, 0);
  }

#pragma unroll
  for (int ni = 0; ni < 4; ++ni) {
    int col = n0 + wc * 64 + ni * 16 + fr;
    float bb = bias[col];
#pragma unroll
    for (int mi = 0; mi < 4; ++mi) {
#pragma unroll
      for (int r = 0; r < 4; ++r) {
        int row = m0 + wr * 64 + mi * 16 + kg * 4 + r;
        float v = acc[mi][ni][r] + bb;
        if (RELU) v = fmaxf(v, 0.f);
        C[(size_t)row * ldc + col] = f2bf(v);
      }
    }
  }
}

// ---------------- fused item attention (R11 layout + packed V writes) -------
// 256 thr = 4 waves = 2 pairs x 2 halves; half does 6/12 QKV n-tiles and
// heads {half*2, half*2+1}. LDS 28KB. Grid = B*O/2.
__global__ __launch_bounds__(256) void k_item_fused(
    const int* __restrict__ oh, const unsigned short* __restrict__ embb,
    const unsigned short* __restrict__ Wqkv /*[192][64] bf16*/,
    const float* __restrict__ bqkv,
    const float* __restrict__ wo /*[64][64] f32*/, const float* __restrict__ bob,
    unsigned short* __restrict__ X /*[B*O][64] bf16*/)
{
  __shared__ __align__(16) unsigned short QKs[2][20][144];
  __shared__ __align__(16) unsigned short VTs[2][64][36];
  __shared__ __align__(16) unsigned short Ps[4][24][36];
  __shared__ __align__(16) float mAs[2][68];

  int t = threadIdx.x, wv = t >> 6, lane = t & 63;
  int fr = lane & 15, lg = lane >> 4;
  int pr = wv >> 1, half = wv & 1;
  int p = blockIdx.x * 2 + pr;
  const int* idxp = oh + (size_t)p * 20;

  // one-time zero of MFMA-read padding (VTs seq 20..35, Ps rows 20..23)
  {
    unsigned int* vz = (unsigned int*)&VTs[t >> 7][(t >> 1) & 63][20 + (t & 1) * 8];
    vz[0] = 0; vz[1] = 0; vz[2] = 0; vz[3] = 0;
    for (int e = t; e < 288; e += 256) {
      int w2 = e / 72, rem = e - w2 * 72;
      *(unsigned int*)&Ps[w2][20 + rem / 18][(rem - (rem / 18) * 18) * 2] = 0;
    }
  }

  // ---- A-fragments of gathered E: direct bf16 loads (rows >= 20 zero) ----
  short8v aF[2][2];
#pragma unroll
  for (int mt = 0; mt < 2; ++mt) {
    int row = mt * 16 + fr;
    if (row < 20) {
      const unsigned short* er = &embb[(size_t)idxp[row] * 64 + lg * 8];
      aF[mt][0] = *(const short8v*)(er);
      aF[mt][1] = *(const short8v*)(er + 32);
    } else {
      short8v z = {0,0,0,0,0,0,0,0};
      aF[mt][0] = z; aF[mt][1] = z;
    }
  }

  // ---- QKV: this half computes n-tiles half*6 .. half*6+5 ----
#pragma unroll
  for (int q6 = 0; q6 < 6; ++q6) {
    int nt = half * 6 + q6;
    const unsigned short* wb = &Wqkv[(size_t)(nt * 16 + fr) * 64 + lg * 8];
    short8v b0 = *(const short8v*)(wb);
    short8v b1 = *(const short8v*)(wb + 32);
    f32x4 a0 = {0.f,0.f,0.f,0.f}, a1 = {0.f,0.f,0.f,0.f};
    a0 = __builtin_amdgcn_mfma_f32_16x16x32_bf16(aF[0][0], b0, a0, 0, 0, 0);
    a0 = __builtin_amdgcn_mfma_f32_16x16x32_bf16(aF[0][1], b1, a0, 0, 0, 0);
    a1 = __builtin_amdgcn_mfma_f32_16x16x32_bf16(aF[1][0], b0, a1, 0, 0, 0);
    a1 = __builtin_amdgcn_mfma_f32_16x16x32_bf16(aF[1][1], b1, a1, 0, 0, 0);
    int n = nt * 16 + fr;
    float bb = bqkv[n];
    if (nt < 8) {
#pragma unroll
      for (int r = 0; r < 4; ++r) {
        QKs[pr][lg * 4 + r][n] = f2bf(a0[r] + bb);
        int row1 = 16 + lg * 4 + r;
        if (row1 < 20) QKs[pr][row1][n] = f2bf(a1[r] + bb);
      }
    } else {
      int c = n - 128;
      // 4 consecutive seq slots -> 2 dword writes (and 2 more for rows 16-19)
      *(unsigned int*)&VTs[pr][c][lg * 4]     = pk2bf(a0[0] + bb, a0[1] + bb);
      *(unsigned int*)&VTs[pr][c][lg * 4 + 2] = pk2bf(a0[2] + bb, a0[3] + bb);
      if (lg == 0) {
        *(unsigned int*)&VTs[pr][c][16] = pk2bf(a1[0] + bb, a1[1] + bb);
        *(unsigned int*)&VTs[pr][c][18] = pk2bf(a1[2] + bb, a1[3] + bb);
      }
    }
  }
  __syncthreads();

  // ---- this half's 2 heads: S^T = K@Q^T, no-max softmax, AV via MFMA ----
  int rj1 = (fr + 16 < 20) ? fr + 16 : 19;
  bool iv1 = fr < 4;
  int pr1 = iv1 ? 16 + fr : 20;
#pragma unroll
  for (int hi = 0; hi < 2; ++hi) {
    int h = half * 2 + hi;
    short8v aK0, aK1, bQ0, bQ1;
    {
      short8v z = {0,0,0,0,0,0,0,0};
      aK0 = z; aK1 = z; bQ0 = z; bQ1 = z;
    }
    if (lg < 2) {
      aK0 = *(const short8v*)&QKs[pr][fr][64 + h * 16 + lg * 8];
      aK1 = *(const short8v*)&QKs[pr][rj1][64 + h * 16 + lg * 8];
      bQ0 = *(const short8v*)&QKs[pr][fr][h * 16 + lg * 8];
      bQ1 = *(const short8v*)&QKs[pr][rj1][h * 16 + lg * 8];
    }
    f32x4 s00 = {0.f,0.f,0.f,0.f}, s01 = {0.f,0.f,0.f,0.f};
    f32x4 s10 = {0.f,0.f,0.f,0.f}, s11 = {0.f,0.f,0.f,0.f};
    s00 = __builtin_amdgcn_mfma_f32_16x16x32_bf16(aK0, bQ0, s00, 0, 0, 0);
    s01 = __builtin_amdgcn_mfma_f32_16x16x32_bf16(aK0, bQ1, s01, 0, 0, 0);
    s10 = __builtin_amdgcn_mfma_f32_16x16x32_bf16(aK1, bQ0, s10, 0, 0, 0);
    s11 = __builtin_amdgcn_mfma_f32_16x16x32_bf16(aK1, bQ1, s11, 0, 0, 0);

    float e00[4], e01[4], e10[4], e11[4];
    float d0 = 0.f, d1 = 0.f;
#pragma unroll
    for (int r = 0; r < 4; ++r) {
      int j1 = 16 + lg * 4 + r;
      bool jv1 = j1 < 20;
      float v00 = __expf(0.25f * s00[r]);
      float v01 = iv1 ? __expf(0.25f * s01[r]) : 0.f;
      float v10 = jv1 ? __expf(0.25f * s10[r]) : 0.f;
      float v11 = (jv1 && iv1) ? __expf(0.25f * s11[r]) : 0.f;
      e00[r] = v00; e01[r] = v01; e10[r] = v10; e11[r] = v11;
      d0 += v00 + v10; d1 += v01 + v11;
    }
    d0 += __shfl_xor(d0, 16, 64); d0 += __shfl_xor(d0, 32, 64);
    d1 += __shfl_xor(d1, 16, 64); d1 += __shfl_xor(d1, 32, 64);
    float inv0 = __fdividef(1.f, d0);
    float inv1 = iv1 ? __fdividef(1.f, d1) : 0.f;

    *(unsigned int*)&Ps[wv][fr][lg * 4]          = pk2bf(e00[0]*inv0, e00[1]*inv0);
    *(unsigned int*)&Ps[wv][fr][lg * 4 + 2]      = pk2bf(e00[2]*inv0, e00[3]*inv0);
    *(unsigned int*)&Ps[wv][fr][16 + lg * 4]     = pk2bf(e10[0]*inv0, e10[1]*inv0);
    *(unsigned int*)&Ps[wv][fr][16 + lg * 4 + 2] = pk2bf(e10[2]*inv0, e10[3]*inv0);
    if (iv1) {
      *(unsigned int*)&Ps[wv][16 + fr][lg * 4]          = pk2bf(e01[0]*inv1, e01[1]*inv1);
      *(unsigned int*)&Ps[wv][16 + fr][lg * 4 + 2]      = pk2bf(e01[2]*inv1, e01[3]*inv1);
      *(unsigned int*)&Ps[wv][16 + fr][16 + lg * 4]     = pk2bf(e11[0]*inv1, e11[1]*inv1);
      *(unsigned int*)&Ps[wv][16 + fr][16 + lg * 4 + 2] = pk2bf(e11[2]*inv1, e11[3]*inv1);
    }

    short8v pa0, pa1, bV;
    {
      short4v l0 = *(const short4v*)&Ps[wv][fr][lg * 8];
      short4v h0 = *(const short4v*)&Ps[wv][fr][lg * 8 + 4];
      short4v l1 = *(const short4v*)&Ps[wv][pr1][lg * 8];
      short4v h1 = *(const short4v*)&Ps[wv][pr1][lg * 8 + 4];
      short4v lv = *(const short4v*)&VTs[pr][h * 16 + fr][lg * 8];
      short4v hv = *(const short4v*)&VTs[pr][h * 16 + fr][lg * 8 + 4];
      pa0[0]=l0[0]; pa0[1]=l0[1]; pa0[2]=l0[2]; pa0[3]=l0[3];
      pa0[4]=h0[0]; pa0[5]=h0[1]; pa0[6]=h0[2]; pa0[7]=h0[3];
      pa1[0]=l1[0]; pa1[1]=l1[1]; pa1[2]=l1[2]; pa1[3]=l1[3];
      pa1[4]=h1[0]; pa1[5]=h1[1]; pa1[6]=h1[2]; pa1[7]=h1[3];
      bV[0]=lv[0]; bV[1]=lv[1]; bV[2]=lv[2]; bV[3]=lv[3];
      bV[4]=hv[0]; bV[5]=hv[1]; bV[6]=hv[2]; bV[7]=hv[3];
    }
    f32x4 m20 = {0.f,0.f,0.f,0.f}, m21 = {0.f,0.f,0.f,0.f};
    m20 = __builtin_amdgcn_mfma_f32_16x16x32_bf16(pa0, bV, m20, 0, 0, 0);
    m21 = __builtin_amdgcn_mfma_f32_16x16x32_bf16(pa1, bV, m21, 0, 0, 0);

    float sm = m20[0] + m20[1] + m20[2] + m20[3];
    if (lg == 0) sm += m21[0] + m21[1] + m21[2] + m21[3];
    sm += __shfl_xor(sm, 16, 64);
    sm += __shfl_xor(sm, 32, 64);
    if (lg == 0) mAs[pr][h * 16 + fr] = sm * 0.05f;
  }
  __syncthreads();

  // ---- out-proj of the mean: 128 threads = 2 pairs x 64 cols, bf16 out ----
  if (t < 128) {
    int p2 = t >> 6, col = t & 63;
    float acc = bob[col];
    const float* wrow = &wo[(size_t)col * 64];
    for (int k = 0; k < 64; k += 4) {
      float4 m4 = *(const float4*)&mAs[p2][k];
      float4 w4 = *(const float4*)(wrow + k);
      acc += m4.x * w4.x + m4.y * w4.y + m4.z * w4.z + m4.w * w4.w;
    }
    X[(size_t)(blockIdx.x * 2 + p2) * 64 + col] = f2bf(acc);
  }
}

// ---------------- GRU recurrence (bf16 G output, full batch) ----------------
__global__ __launch_bounds__(512) void k_gru_mfma(
    const unsigned short* __restrict__ GI,   // [B*O][768]: 0-383 fwd, 384-767 bwd
    const unsigned short* __restrict__ whf,
    const unsigned short* __restrict__ whb,
    const float* __restrict__ bh_f, const float* __restrict__ bh_b,
    unsigned short* __restrict__ G /*[B*O][256] bf16*/)
{
  __shared__ unsigned short hsb[16][136];
  __shared__ float ah[4][392];

  int bid = blockIdx.x;
  int dir = bid >> 8;            // 256 row-groups per dir
  int rg  = bid & 255;
  const unsigned short* wh = dir ? whb : whf;
  const float* bh = dir ? bh_b : bh_f;

  int t = threadIdx.x;
  int w = t >> 6, lane = t & 63;
  int fr = lane & 15, kg = lane >> 4;

  short8v bfr[3][4];
#pragma unroll
  for (int n = 0; n < 3; ++n)
#pragma unroll
    for (int kf = 0; kf < 4; ++kf)
      bfr[n][kf] = *(const short8v*)&wh[(size_t)(w * 48 + n * 16 + fr) * 128 + kf * 32 + kg * 8];

  for (int e = t; e < 16 * 136; e += 512) ((unsigned short*)hsb)[e] = 0;

  int grow = t >> 7, gc = t & 127;
  float bh0 = bh[gc], bh1 = bh[128 + gc], bh2 = bh[256 + gc];
  float hold = 0.f;
  const unsigned short* gip = &GI[(size_t)(rg * 4 + grow) * 50 * 768 + dir * 384];
  unsigned short* gout = &G[((size_t)(rg * 4 + grow) * 50) * 256 + dir * 128 + gc];

  __syncthreads();

  int o0 = dir ? 49 : 0;
  unsigned short c0v = gip[(size_t)o0 * 768 + gc];
  unsigned short c1v = gip[(size_t)o0 * 768 + 128 + gc];
  unsigned short c2v = gip[(size_t)o0 * 768 + 256 + gc];

  for (int s = 0; s < 50; ++s) {
    int o  = dir ? 49 - s : s;
    unsigned short n0v = 0, n1v = 0, n2v = 0;
    if (s < 49) {
      int on = dir ? 48 - s : s + 1;
      n0v = gip[(size_t)on * 768 + gc];
      n1v = gip[(size_t)on * 768 + 128 + gc];
      n2v = gip[(size_t)on * 768 + 256 + gc];
    }

    short8v a0 = *(const short8v*)&hsb[fr][0 * 32 + kg * 8];
    short8v a1 = *(const short8v*)&hsb[fr][1 * 32 + kg * 8];
    short8v a2 = *(const short8v*)&hsb[fr][2 * 32 + kg * 8];
    short8v a3 = *(const short8v*)&hsb[fr][3 * 32 + kg * 8];

    f32x4 acc0 = {0.f,0.f,0.f,0.f}, acc1 = {0.f,0.f,0.f,0.f}, acc2 = {0.f,0.f,0.f,0.f};
    acc0 = __builtin_amdgcn_mfma_f32_16x16x32_bf16(a0, bfr[0][0], acc0, 0, 0, 0);
    acc1 = __builtin_amdgcn_mfma_f32_16x16x32_bf16(a0, bfr[1][0], acc1, 0, 0, 0);
    acc2 = __builtin_amdgcn_mfma_f32_16x16x32_bf16(a0, bfr[2][0], acc2, 0, 0, 0);
    acc0 = __builtin_amdgcn_mfma_f32_16x16x32_bf16(a1, bfr[0][1], acc0, 0, 0, 0);
    acc1 = __builtin_amdgcn_mfma_f32_16x16x32_bf16(a1, bfr[1][1], acc1, 0, 0, 0);
    acc2 = __builtin_amdgcn_mfma_f32_16x16x32_bf16(a1, bfr[2][1], acc2, 0, 0, 0);
    acc0 = __builtin_amdgcn_mfma_f32_16x16x32_bf16(a2, bfr[0][2], acc0, 0, 0, 0);
    acc1 = __builtin_amdgcn_mfma_f32_16x16x32_bf16(a2, bfr[1][2], acc1, 0, 0, 0);
    acc2 = __builtin_amdgcn_mfma_f32_16x16x32_bf16(a2, bfr[2][2], acc2, 0, 0, 0);
    acc0 = __builtin_amdgcn_mfma_f32_16x16x32_bf16(a3, bfr[0][3], acc0, 0, 0, 0);
    acc1 = __builtin_amdgcn_mfma_f32_16x16x32_bf16(a3, bfr[1][3], acc1, 0, 0, 0);
    acc2 = __builtin_amdgcn_mfma_f32_16x16x32_bf16(a3, bfr[2][3], acc2, 0, 0, 0);

    if (kg == 0) {
#pragma unroll
      for (int r = 0; r < 4; ++r) {
        ah[r][w * 48 + 0 * 16 + fr] = acc0[r];
        ah[r][w * 48 + 1 * 16 + fr] = acc1[r];
        ah[r][w * 48 + 2 * 16 + fr] = acc2[r];
      }
    }
    __syncthreads();

    float ai0 = bf2f(c0v), ai1 = bf2f(c1v), ai2 = bf2f(c2v);
    float ah0 = ah[grow][gc] + bh0;
    float ah1 = ah[grow][128 + gc] + bh1;
    float ah2 = ah[grow][256 + gc] + bh2;
    float rr = sig_(ai0 + ah0);
    float zz = sig_(ai1 + ah1);
    float nn = tanh_(ai2 + rr * ah2);
    float h2 = (1.f - zz) * nn + zz * hold;
    hold = h2;
    unsigned short hb = f2bf(h2);
    hsb[grow][gc] = hb;
    gout[(size_t)o * 256] = hb;
    c0v = n0v; c1v = n1v; c2v = n2v;
    __syncthreads();
  }
}

// ---------------- transformer attention core (bf16, in-place q-section) -----
__global__ __launch_bounds__(256) void k_attn_core(unsigned short* __restrict__ BIG)
{
  __shared__ __align__(16) float qs[50][68], ks[50][68], vs[50][68];
  __shared__ float P[50][52];
  int bl = blockIdx.x >> 2, h = blockIdx.x & 3;
  int t = threadIdx.x;
  size_t base = (size_t)bl * 50 * 768;
  int hc = h * 64;

  for (int e = t; e < 800; e += 256) {
    int row = e >> 4, c4 = (e & 15) * 4;
    ushort4v q4 = *(const ushort4v*)&BIG[base + (size_t)row * 768 + hc + c4];
    ushort4v k4 = *(const ushort4v*)&BIG[base + (size_t)row * 768 + 256 + hc + c4];
    ushort4v v4 = *(const ushort4v*)&BIG[base + (size_t)row * 768 + 512 + hc + c4];
#pragma unroll
    for (int j = 0; j < 4; ++j) {
      qs[row][c4 + j] = bf2f(q4[j]);
      ks[row][c4 + j] = bf2f(k4[j]);
      vs[row][c4 + j] = bf2f(v4[j]);
    }
  }
  __syncthreads();

  for (int e = t; e < 2500; e += 256) {
    int i = e / 50, j = e - (e / 50) * 50;
    float d = 0.f;
#pragma unroll
    for (int k = 0; k < 64; k += 4) {
      float4 q = *(const float4*)&qs[i][k];
      float4 kk = *(const float4*)&ks[j][k];
      d += q.x * kk.x + q.y * kk.y + q.z * kk.z + q.w * kk.w;
    }
    P[i][j] = d * 0.125f;
  }
  __syncthreads();

  {
    int l = t & 31, rslot = t >> 5;
    for (int i0 = 0; i0 < 50; i0 += 8) {
      int i = i0 + rslot;
      if (i < 50) {
        float p1 = P[i][l];
        float p2 = (l < 18) ? P[i][l + 32] : -1e30f;
        float m = fmaxf(p1, p2);
#pragma unroll
        for (int d2 = 1; d2 < 32; d2 <<= 1) m = fmaxf(m, __shfl_xor(m, d2, 32));
        float e1 = __expf(p1 - m);
        float e2 = (l < 18) ? __expf(p2 - m) : 0.f;
        float s = e1 + e2;
#pragma unroll
        for (int d2 = 1; d2 < 32; d2 <<= 1) s += __shfl_xor(s, d2, 32);
        float inv = __fdividef(1.f, s);
        P[i][l] = e1 * inv;
        if (l < 18) P[i][l + 32] = e2 * inv;
      }
    }
  }
  __syncthreads();
  for (int e = t; e < 1600; e += 256) {
    int i = e >> 5, c2 = (e & 31) * 2;
    float a0 = 0.f, a1 = 0.f;
    for (int j = 0; j < 50; ++j) {
      float pv = P[i][j];
      a0 += pv * vs[j][c2];
      a1 += pv * vs[j][c2 + 1];
    }
    *(unsigned int*)&BIG[base + (size_t)i * 768 + hc + c2] = pk2bf(a0, a1);
  }
}

// ---------------- fused residual + LayerNorm (bf16 I/O, wave per row) -------
__global__ __launch_bounds__(256) void k_ln_res(
    const unsigned short* __restrict__ res, const unsigned short* __restrict__ add,
    int addld, unsigned short* __restrict__ dst,
    const float* __restrict__ g, const float* __restrict__ bt)
{
  int row = blockIdx.x * 4 + (threadIdx.x >> 6);
  int lane = threadIdx.x & 63;
  int c = lane * 4;
  ushort4v rv = *(const ushort4v*)&res[(size_t)row * 256 + c];
  ushort4v av = *(const ushort4v*)&add[(size_t)row * addld + c];
  float x0 = bf2f(rv[0]) + bf2f(av[0]);
  float x1 = bf2f(rv[1]) + bf2f(av[1]);
  float x2 = bf2f(rv[2]) + bf2f(av[2]);
  float x3 = bf2f(rv[3]) + bf2f(av[3]);
  float s = x0 + x1 + x2 + x3;
  float sq = x0 * x0 + x1 * x1 + x2 * x2 + x3 * x3;
#pragma unroll
  for (int d = 1; d < 64; d <<= 1) { s += __shfl_xor(s, d, 64); sq += __shfl_xor(sq, d, 64); }
  float m = s * (1.f / 256.f);
  float var = sq * (1.f / 256.f) - m * m;
  float rs = rsqrtf(var + 1e-5f);
  float4 gv = *(const float4*)&g[c];
  float4 bv = *(const float4*)&bt[c];
  ushort4v ov;
  ov[0] = f2bf((x0 - m) * rs * gv.x + bv.x);
  ov[1] = f2bf((x1 - m) * rs * gv.y + bv.y);
  ov[2] = f2bf((x2 - m) * rs * gv.z + bv.z);
  ov[3] = f2bf((x3 - m) * rs * gv.w + bv.w);
  *(ushort4v*)&dst[(size_t)row * 256 + c] = ov;
}

// ---------------- temporal encoder + O-mean + final classifier (fused) ------
__global__ __launch_bounds__(256) void k_heads(
    const unsigned short* __restrict__ H2 /*[B*O][256] bf16*/,
    const float* __restrict__ daysb, const float* __restrict__ dayss,
    const float* __restrict__ te1_w, const float* __restrict__ te1_b,
    const float* __restrict__ ln1g, const float* __restrict__ ln1b,
    const float* __restrict__ te2_w, const float* __restrict__ te2_b,
    const float* __restrict__ ln2g, const float* __restrict__ ln2b,
    const float* __restrict__ cWT /*[320][128]*/,
    const float* __restrict__ c_b, const float* __restrict__ clng,
    const float* __restrict__ clnb, float* __restrict__ out)
{
  __shared__ float oe[256];
  __shared__ float feat[2];
  __shared__ float s1[32], s2[64], pre[128], stat[2];
  int b = blockIdx.x, t = threadIdx.x;
  // O-mean into LDS (all 256 threads) + temporal feats (t==0)
  {
    float s = 0.f;
    for (int o = 0; o < 50; ++o) s += bf2f(H2[((size_t)b * 50 + o) * 256 + t]);
    oe[t] = s * 0.02f;
  }
  if (t == 0) {
    float f0 = 0.f;
    for (int i = 0; i < 10; ++i) f0 += daysb[b * 10 + i];
    feat[0] = f0 * 0.1f;
    feat[1] = dayss[b];
  }
  __syncthreads();
  if (t < 32) s1[t] = te1_b[t] + feat[0] * te1_w[2 * t] + feat[1] * te1_w[2 * t + 1];
  __syncthreads();
  if (t == 0) {
    float s = 0.f; for (int j = 0; j < 32; ++j) s += s1[j];
    float m = s * (1.f / 32.f);
    float v = 0.f; for (int j = 0; j < 32; ++j) { float d = s1[j] - m; v += d * d; }
    stat[0] = m; stat[1] = rsqrtf(v * (1.f / 32.f) + 1e-5f);
  }
  __syncthreads();
  if (t < 32) s1[t] = fmaxf((s1[t] - stat[0]) * stat[1] * ln1g[t] + ln1b[t], 0.f);
  __syncthreads();
  if (t < 64) {
    float a = te2_b[t];
    for (int k = 0; k < 32; ++k) a += s1[k] * te2_w[t * 32 + k];
    s2[t] = a;
  }
  __syncthreads();
  if (t == 0) {
    float s = 0.f; for (int j = 0; j < 64; ++j) s += s2[j];
    float m = s * (1.f / 64.f);
    float v = 0.f; for (int j = 0; j < 64; ++j) { float d = s2[j] - m; v += d * d; }
    stat[0] = m; stat[1] = rsqrtf(v * (1.f / 64.f) + 1e-5f);
  }
  __syncthreads();
  if (t < 64) s2[t] = fmaxf((s2[t] - stat[0]) * stat[1] * ln2g[t] + ln2b[t], 0.f);
  __syncthreads();
  if (t < 128) {
    float p = c_b[t];
    for (int k = 0; k < 256; ++k) p += oe[k] * cWT[k * 128 + t];
    for (int k = 0; k < 64; ++k)  p += s2[k] * cWT[(256 + k) * 128 + t];
    pre[t] = p;
  }
  __syncthreads();
  if (t == 0) {
    float s = 0.f; for (int j = 0; j < 128; ++j) s += pre[j];
    float m = s * (1.f / 128.f);
    float v = 0.f; for (int j = 0; j < 128; ++j) { float d = pre[j] - m; v += d * d; }
    stat[0] = m; stat[1] = rsqrtf(v * (1.f / 128.f) + 1e-5f);
  }
  __syncthreads();
  if (t < 128)
    out[(size_t)b * 128 + t] = fmaxf((pre[t] - stat[0]) * stat[1] * clng[t] + clnb[t], 0.f);
}

// ---------------- host launcher ----------------
extern "C" void kernel_launch(void* const* d_in, const int* in_sizes, int n_in,
                              void* d_out, int out_size, void* d_ws, size_t ws_size,
                              hipStream_t stream)
{
  const int*   oh       = (const int*)d_in[0];
  const float* daysb    = (const float*)d_in[1];
  const float* dayss    = (const float*)d_in[2];
  const float* emb      = (const float*)d_in[3];
  const float* ia_in_w  = (const float*)d_in[4];
  const float* ia_in_b  = (const float*)d_in[5];
  const float* ia_out_w = (const float*)d_in[6];
  const float* ia_out_b = (const float*)d_in[7];
  const float* gf_wi = (const float*)d_in[8];
  const float* gf_wh = (const float*)d_in[9];
  const float* gf_bi = (const float*)d_in[10];
  const float* gf_bh = (const float*)d_in[11];
  const float* gb_wi = (const float*)d_in[12];
  const float* gb_wh = (const float*)d_in[13];
  const float* gb_bi = (const float*)d_in[14];
  const float* gb_bh = (const float*)d_in[15];
  const float* ta_in_w  = (const float*)d_in[16];
  const float* ta_in_b  = (const float*)d_in[17];
  const float* ta_out_w = (const float*)d_in[18];
  const float* ta_out_b = (const float*)d_in[19];
  const float* t_ln1_g = (const float*)d_in[20];
  const float* t_ln1_b = (const float*)d_in[21];
  const float* t_ln2_g = (const float*)d_in[22];
  const float* t_ln2_b = (const float*)d_in[23];
  const float* t_ff1_w = (const float*)d_in[24];
  const float* t_ff1_b = (const float*)d_in[25];
  const float* t_ff2_w = (const float*)d_in[26];
  const float* t_ff2_b = (const float*)d_in[27];
  const float* te1_w = (const float*)d_in[28];
  const float* te1_b = (const float*)d_in[29];
  const float* te_ln1_g = (const float*)d_in[30];
  const float* te_ln1_b = (const float*)d_in[31];
  const float* te2_w = (const float*)d_in[32];
  const float* te2_b = (const float*)d_in[33];
  const float* te_ln2_g = (const float*)d_in[34];
  const float* te_ln2_b = (const float*)d_in[35];
  const float* c_w   = (const float*)d_in[36];
  const float* c_b   = (const float*)d_in[37];
  const float* c_ln_g = (const float*)d_in[38];
  const float* c_ln_b = (const float*)d_in[39];

  float* ws = (float*)d_ws;
  // layout (floats):
  const size_t OFF_GB   = 0;                        // G bf16 [51200][256] = 6,553,600 fl
  const size_t OFF_X    = 6553600;                  // X bf16 [51200][64]  = 1,638,400 fl
  const size_t OFF_S    = OFF_X + 1638400;          // GI|BIGb bf16 [51200][768] = 19,660,800 fl
  const size_t OW_C     = OFF_S + 19660800;         // [320][128] 40,960
  const size_t OW_BC    = OW_C + 40960;             // 768
  const size_t OW_BF    = OW_BC + 768;              // bf16 weight pool 342,016 fl
  const size_t OW_EMB   = OW_BF + 342016;           // bf16 emb table 1,590,048 fl
  const size_t TOTAL    = OW_EMB + 1590048;         // 29,826,592 fl = 119.3 MB
  if (ws_size < TOTAL * sizeof(float)) return;

  unsigned short* Gb = (unsigned short*)(ws + OFF_GB);
  unsigned short* Xb = (unsigned short*)(ws + OFF_X);
  float* w_c  = ws + OW_C;
  float* biascat = ws + OW_BC;
  unsigned short* bfp = (unsigned short*)(ws + OW_BF);
  unsigned short* b_ta_in  = bfp;                  // 196,608
  unsigned short* b_ta_out = b_ta_in + 196608;     //  65,536
  unsigned short* b_ff1    = b_ta_out + 65536;     // 131,072
  unsigned short* b_ff2    = b_ff1 + 131072;       // 131,072
  unsigned short* b_ia_in  = b_ff2 + 131072;       //  12,288
  unsigned short* b_wi_f   = b_ia_in + 12288;      //  24,576 ── Wcat [768][64]
  unsigned short* b_wi_b   = b_wi_f + 24576;       //  24,576 ──┘
  unsigned short* b_wh_f   = b_wi_b + 24576;       //  49,152
  unsigned short* b_wh_b   = b_wh_f + 49152;       //  49,152
  unsigned short* embb = (unsigned short*)(ws + OW_EMB);  // [(V+1)][64] bf16

  // scratch phase views (aliased):
  unsigned short* GI   = (unsigned short*)(ws + OFF_S);   // gru: [51200][768] bf16
  unsigned short* BIGb = (unsigned short*)(ws + OFF_S);   // transformer: [51200][768]

  k_transpose<<<(320 * 128 + 255) / 256, 256, 0, stream>>>(c_w, w_c, 128, 320);
  k_cat_bias<<<3, 256, 0, stream>>>(gf_bi, gb_bi, biascat);
  #define CV(SRC, DST, N) k_f32bf16<<<((N)+255)/256, 256, 0, stream>>>(SRC, DST, N)
  CV(ta_in_w,  b_ta_in,  196608);
  CV(ta_out_w, b_ta_out, 65536);
  CV(t_ff1_w,  b_ff1,    131072);
  CV(t_ff2_w,  b_ff2,    131072);
  CV(ia_in_w,  b_ia_in,  12288);
  CV(gf_wi,    b_wi_f,   24576);
  CV(gb_wi,    b_wi_b,   24576);
  CV(gf_wh,    b_wh_f,   49152);
  CV(gb_wh,    b_wh_b,   49152);
  CV(emb,      embb,     3180096);      // (V+1)*64 bf16 embedding table
  #undef CV

  // ---- item attention: single fused dispatch (2 pairs/block) ----
  k_item_fused<<<B_ * O_ / 2, 256, 0, stream>>>(oh, embb, b_ia_in, ia_in_b,
                                                ia_out_w, ia_out_b, Xb);

  // ---- bidirectional GRU: single chunk over full batch ----
  k_gemm128<0><<<dim3(768 / 128, 51200 / 128), 256, 0, stream>>>(
      Xb, 64, b_wi_f /*Wcat [768][64]*/, 64, biascat, GI, 768);
  k_gru_mfma<<<512, 512, 0, stream>>>(GI, b_wh_f, b_wh_b, gf_bh, gb_bh, Gb);

  // ---- transformer layer: single chunk, bf16, in-place in BIGb ----
  k_gemm128<0><<<dim3(768 / 128, 51200 / 128), 256, 0, stream>>>(
      Gb, 256, b_ta_in, 256, ta_in_b, BIGb, 768);
  k_attn_core<<<B_ * 4, 256, 0, stream>>>(BIGb);
  k_gemm128<0><<<dim3(256 / 128, 51200 / 128), 256, 0, stream>>>(
      BIGb, 768, b_ta_out, 256, ta_out_b, BIGb + 256, 768);
  k_ln_res<<<51200 / 4, 256, 0, stream>>>(Gb, BIGb + 256, 768, Gb, t_ln1_g, t_ln1_b);
  k_gemm128<1><<<dim3(512 / 128, 51200 / 128), 256, 0, stream>>>(
      Gb, 256, b_ff1, 256, t_ff1_b, BIGb, 768);
  k_gemm128<0><<<dim3(256 / 128, 51200 / 128), 256, 0, stream>>>(
      BIGb, 768, b_ff2, 512, t_ff2_b, BIGb + 512, 768);
  k_ln_res<<<51200 / 4, 256, 0, stream>>>(Gb, BIGb + 512, 768, Gb, t_ln2_g, t_ln2_b);

  // ---- fused O-mean + temporal encoder + classifier ----
  k_heads<<<B_, 256, 0, stream>>>(Gb, daysb, dayss, te1_w, te1_b, te_ln1_g, te_ln1_b,
                                  te2_w, te2_b, te_ln2_g, te_ln2_b,
                                  w_c, c_b, c_ln_g, c_ln_b, (float*)d_out);
}

// Round 14
// 622.565 us; speedup vs baseline: 1.1985x; 1.0911x over previous
//
#include <hip/hip_runtime.h>

// NextBasketEncoder — round 14: QKV projection commuted through the gather —
// precompute QKVall[vocab][256] once via k_gemm128 (Mclamp'd), item kernel
// becomes gather+attention only (QKV-compute phase deleted). Table aliases
// the GI/BIGb scratch region. Rest unchanged from round 13.
// B=1024, O=50, L=20, D=64, H=128, DM=256, FF=512, V=49688.

#define B_ 1024
#define O_ 50
#define VROWS 49689            // V+1 embedding rows
#define VPAD  49792            // 389*128

typedef __attribute__((ext_vector_type(8))) short  short8v;
typedef __attribute__((ext_vector_type(4))) short  short4v;
typedef __attribute__((ext_vector_type(8))) unsigned short ushort8v;
typedef __attribute__((ext_vector_type(4))) unsigned short ushort4v;
typedef __attribute__((ext_vector_type(4))) float f32x4;

__device__ __forceinline__ float sig_(float x)  { return 1.0f / (1.0f + __expf(-x)); }
__device__ __forceinline__ float tanh_(float x) { return 2.0f / (1.0f + __expf(-2.0f * x)) - 1.0f; }

__device__ __forceinline__ unsigned short f2bf(float f) {
  union { float f; unsigned int u; } v; v.f = f;
  unsigned int r = v.u + 0x7FFFu + ((v.u >> 16) & 1u);   // RNE
  return (unsigned short)(r >> 16);
}
__device__ __forceinline__ float bf2f(unsigned short u) {
  union { unsigned int u; float f; } v; v.u = ((unsigned int)u) << 16;
  return v.f;
}
__device__ __forceinline__ unsigned int pk2bf(float lo, float hi) {
  return (unsigned int)f2bf(lo) | ((unsigned int)f2bf(hi) << 16);
}

// ---------------- generic transpose: src[R][C] -> dst[C][R] ----------------
__global__ void k_transpose(const float* __restrict__ src, float* __restrict__ dst, int R, int C) {
  int i = blockIdx.x * 256 + threadIdx.x;
  if (i < R * C) {
    int r = i / C, c = i - r * C;
    dst[c * R + r] = src[i];
  }
}

// ---------------- fp32 -> bf16 elementwise ----------------
__global__ void k_f32bf16(const float* __restrict__ src, unsigned short* __restrict__ dst, int n) {
  int i = blockIdx.x * 256 + threadIdx.x;
  if (i < n) dst[i] = f2bf(src[i]);
}

// ---------------- zero-fill u16 ----------------
__global__ void k_fill_u16(unsigned short* __restrict__ dst, int n) {
  int i = blockIdx.x * 256 + threadIdx.x;
  if (i < n) dst[i] = 0;
}

// ---------------- padded bias: dst[0..ns-1]=src, dst[ns..nt-1]=0 ------------
__global__ void k_pad_bias(const float* __restrict__ src, float* __restrict__ dst,
                           int ns, int nt) {
  int i = blockIdx.x * 256 + threadIdx.x;
  if (i < nt) dst[i] = (i < ns) ? src[i] : 0.f;
}

// ---------------- bias concat: dst[0..383]=a, dst[384..767]=b ---------------
__global__ void k_cat_bias(const float* __restrict__ a, const float* __restrict__ b,
                           float* __restrict__ dst) {
  int i = blockIdx.x * 256 + threadIdx.x;
  if (i < 768) dst[i] = (i < 384) ? a[i] : b[i - 384];
}

// ---------------- 128x128-tile bf16 GEMM: C = A @ W^T + bias (all bf16) -----
// Mclamp: A row index clamped to Mclamp-1 (for vocab-padded GEMM).
template<int RELU>
__global__ __launch_bounds__(256) void k_gemm128(
    const unsigned short* __restrict__ A, int lda,    // [M][lda] bf16
    const unsigned short* __restrict__ W, int K,      // [N][K] bf16
    const float* __restrict__ bias,
    unsigned short* __restrict__ C, int ldc, int Mclamp)
{
  __shared__ unsigned short As[128 * 40];
  __shared__ unsigned short Bs[128 * 40];
  int n0 = blockIdx.x * 128, m0 = blockIdx.y * 128;
  int t = threadIdx.x, wv = t >> 6, lane = t & 63;
  int fr = lane & 15, kg = lane >> 4;
  int wr = wv >> 1, wc = wv & 1;
  int sr = t >> 1, sc = (t & 1) * 16;

  f32x4 acc[4][4];
#pragma unroll
  for (int mi = 0; mi < 4; ++mi)
#pragma unroll
    for (int ni = 0; ni < 4; ++ni) acc[mi][ni] = (f32x4){0.f, 0.f, 0.f, 0.f};

  int arow = m0 + sr; if (arow >= Mclamp) arow = Mclamp - 1;
  const unsigned short* ga = &A[(size_t)arow * lda + sc];
  const unsigned short* gw = &W[(size_t)(n0 + sr) * K + sc];

  for (int k0 = 0; k0 < K; k0 += 32) {
    ushort8v a0 = *(const ushort8v*)(ga + k0);
    ushort8v a1 = *(const ushort8v*)(ga + k0 + 8);
    ushort8v b0 = *(const ushort8v*)(gw + k0);
    ushort8v b1 = *(const ushort8v*)(gw + k0 + 8);
    __syncthreads();
    *(ushort8v*)&As[sr * 40 + sc]     = a0;
    *(ushort8v*)&As[sr * 40 + sc + 8] = a1;
    *(ushort8v*)&Bs[sr * 40 + sc]     = b0;
    *(ushort8v*)&Bs[sr * 40 + sc + 8] = b1;
    __syncthreads();
    short8v af[4], bfv[4];
#pragma unroll
    for (int mi = 0; mi < 4; ++mi)
      af[mi] = *(const short8v*)&As[(wr * 64 + mi * 16 + fr) * 40 + kg * 8];
#pragma unroll
    for (int ni = 0; ni < 4; ++ni)
      bfv[ni] = *(const short8v*)&Bs[(wc * 64 + ni * 16 + fr) * 40 + kg * 8];
#pragma unroll
    for (int mi = 0; mi < 4; ++mi)
#pragma unroll
      for (int ni = 0; ni < 4; ++ni)
        acc[mi][ni] = __builtin_amdgcn_mfma_f32_16x16x32_bf16(af[mi], bfv[ni], acc[mi][ni], 0, 0, 0);
  }

#pragma unroll
  for (int ni = 0; ni < 4; ++ni) {
    int col = n0 + wc * 64 + ni * 16 + fr;
    float bb = bias[col];
#pragma unroll
    for (int mi = 0; mi < 4; ++mi) {
#pragma unroll
      for (int r = 0; r < 4; ++r) {
        int row = m0 + wr * 64 + mi * 16 + kg * 4 + r;
        float v = acc[mi][ni][r] + bb;
        if (RELU) v = fmaxf(v, 0.f);
        C[(size_t)row * ldc + col] = f2bf(v);
      }
    }
  }
}

// ---------------- fused item attention v4: gather precomputed QKV -----------
// 256 thr = 4 waves = 2 pairs x 2 halves; staging is pure gather from
// QKVall[idx][256] (Q|K cols 0-127, V cols 128-191). LDS 28KB. Grid = B*O/2.
__global__ __launch_bounds__(256) void k_item_fused(
    const int* __restrict__ oh,
    const unsigned short* __restrict__ QKVall /*[VPAD][256] bf16*/,
    const float* __restrict__ wo /*[64][64] f32*/, const float* __restrict__ bob,
    unsigned short* __restrict__ X /*[B*O][64] bf16*/)
{
  __shared__ __align__(16) unsigned short QKs[2][20][144];
  __shared__ __align__(16) unsigned short VTs[2][64][36];
  __shared__ __align__(16) unsigned short Ps[4][24][36];
  __shared__ __align__(16) float mAs[2][68];
  __shared__ int ids[2][20];

  int t = threadIdx.x, wv = t >> 6, lane = t & 63;
  int fr = lane & 15, lg = lane >> 4;
  int pr = wv >> 1, half = wv & 1;

  // index preload + one-time zero of MFMA-read padding
  if (t < 40) ids[t / 20][t % 20] = oh[(size_t)(blockIdx.x * 2 + t / 20) * 20 + (t % 20)];
  {
    unsigned int* vz = (unsigned int*)&VTs[t >> 7][(t >> 1) & 63][20 + (t & 1) * 8];
    vz[0] = 0; vz[1] = 0; vz[2] = 0; vz[3] = 0;
    for (int e = t; e < 288; e += 256) {
      int w2 = e / 72, rem = e - w2 * 72;
      *(unsigned int*)&Ps[w2][20 + rem / 18][(rem - (rem / 18) * 18) * 2] = 0;
    }
  }
  __syncthreads();

  // ---- gather Q|K rows (b128): 2 pairs x 20 rows x 16 chunks = 640 jobs ----
  for (int e = t; e < 640; e += 256) {
    int pp = e / 320, rem = e - pp * 320;
    int row = rem >> 4, ch = (rem & 15) * 8;
    const unsigned short* src = QKVall + (size_t)ids[pp][row] * 256 + ch;
    *(ushort8v*)&QKs[pp][row][ch] = *(const ushort8v*)src;
  }
  // ---- gather V transposed (packed b32): 2 x 10 jpairs x 64 cols = 1280 ----
  for (int e = t; e < 1280; e += 256) {
    int pp = e / 640, rem = e - pp * 640;
    int jp = rem >> 6, c = rem & 63;
    unsigned int u0 = QKVall[(size_t)ids[pp][2 * jp] * 256 + 128 + c];
    unsigned int u1 = QKVall[(size_t)ids[pp][2 * jp + 1] * 256 + 128 + c];
    *(unsigned int*)&VTs[pp][c][2 * jp] = u0 | (u1 << 16);
  }
  __syncthreads();

  // ---- this half's 2 heads: S^T = K@Q^T, no-max softmax, AV via MFMA ----
  int rj1 = (fr + 16 < 20) ? fr + 16 : 19;
  bool iv1 = fr < 4;
  int pr1 = iv1 ? 16 + fr : 20;
#pragma unroll
  for (int hi = 0; hi < 2; ++hi) {
    int h = half * 2 + hi;
    short8v aK0, aK1, bQ0, bQ1;
    {
      short8v z = {0,0,0,0,0,0,0,0};
      aK0 = z; aK1 = z; bQ0 = z; bQ1 = z;
    }
    if (lg < 2) {
      aK0 = *(const short8v*)&QKs[pr][fr][64 + h * 16 + lg * 8];
      aK1 = *(const short8v*)&QKs[pr][rj1][64 + h * 16 + lg * 8];
      bQ0 = *(const short8v*)&QKs[pr][fr][h * 16 + lg * 8];
      bQ1 = *(const short8v*)&QKs[pr][rj1][h * 16 + lg * 8];
    }
    f32x4 s00 = {0.f,0.f,0.f,0.f}, s01 = {0.f,0.f,0.f,0.f};
    f32x4 s10 = {0.f,0.f,0.f,0.f}, s11 = {0.f,0.f,0.f,0.f};
    s00 = __builtin_amdgcn_mfma_f32_16x16x32_bf16(aK0, bQ0, s00, 0, 0, 0);
    s01 = __builtin_amdgcn_mfma_f32_16x16x32_bf16(aK0, bQ1, s01, 0, 0, 0);
    s10 = __builtin_amdgcn_mfma_f32_16x16x32_bf16(aK1, bQ0, s10, 0, 0, 0);
    s11 = __builtin_amdgcn_mfma_f32_16x16x32_bf16(aK1, bQ1, s11, 0, 0, 0);

    float e00[4], e01[4], e10[4], e11[4];
    float d0 = 0.f, d1 = 0.f;
#pragma unroll
    for (int r = 0; r < 4; ++r) {
      int j1 = 16 + lg * 4 + r;
      bool jv1 = j1 < 20;
      float v00 = __expf(0.25f * s00[r]);
      float v01 = iv1 ? __expf(0.25f * s01[r]) : 0.f;
      float v10 = jv1 ? __expf(0.25f * s10[r]) : 0.f;
      float v11 = (jv1 && iv1) ? __expf(0.25f * s11[r]) : 0.f;
      e00[r] = v00; e01[r] = v01; e10[r] = v10; e11[r] = v11;
      d0 += v00 + v10; d1 += v01 + v11;
    }
    d0 += __shfl_xor(d0, 16, 64); d0 += __shfl_xor(d0, 32, 64);
    d1 += __shfl_xor(d1, 16, 64); d1 += __shfl_xor(d1, 32, 64);
    float inv0 = __fdividef(1.f, d0);
    float inv1 = iv1 ? __fdividef(1.f, d1) : 0.f;

    *(unsigned int*)&Ps[wv][fr][lg * 4]          = pk2bf(e00[0]*inv0, e00[1]*inv0);
    *(unsigned int*)&Ps[wv][fr][lg * 4 + 2]      = pk2bf(e00[2]*inv0, e00[3]*inv0);
    *(unsigned int*)&Ps[wv][fr][16 + lg * 4]     = pk2bf(e10[0]*inv0, e10[1]*inv0);
    *(unsigned int*)&Ps[wv][fr][16 + lg * 4 + 2] = pk2bf(e10[2]*inv0, e10[3]*inv0);
    if (iv1) {
      *(unsigned int*)&Ps[wv][16 + fr][lg * 4]          = pk2bf(e01[0]*inv1, e01[1]*inv1);
      *(unsigned int*)&Ps[wv][16 + fr][lg * 4 + 2]      = pk2bf(e01[2]*inv1, e01[3]*inv1);
      *(unsigned int*)&Ps[wv][16 + fr][16 + lg * 4]     = pk2bf(e11[0]*inv1, e11[1]*inv1);
      *(unsigned int*)&Ps[wv][16 + fr][16 + lg * 4 + 2] = pk2bf(e11[2]*inv1, e11[3]*inv1);
    }

    short8v pa0, pa1, bV;
    {
      short4v l0 = *(const short4v*)&Ps[wv][fr][lg * 8];
      short4v h0 = *(const short4v*)&Ps[wv][fr][lg * 8 + 4];
      short4v l1 = *(const short4v*)&Ps[wv][pr1][lg * 8];
      short4v h1 = *(const short4v*)&Ps[wv][pr1][lg * 8 + 4];
      short4v lv = *(const short4v*)&VTs[pr][h * 16 + fr][lg * 8];
      short4v hv = *(const short4v*)&VTs[pr][h * 16 + fr][lg * 8 + 4];
      pa0[0]=l0[0]; pa0[1]=l0[1]; pa0[2]=l0[2]; pa0[3]=l0[3];
      pa0[4]=h0[0]; pa0[5]=h0[1]; pa0[6]=h0[2]; pa0[7]=h0[3];
      pa1[0]=l1[0]; pa1[1]=l1[1]; pa1[2]=l1[2]; pa1[3]=l1[3];
      pa1[4]=h1[0]; pa1[5]=h1[1]; pa1[6]=h1[2]; pa1[7]=h1[3];
      bV[0]=lv[0]; bV[1]=lv[1]; bV[2]=lv[2]; bV[3]=lv[3];
      bV[4]=hv[0]; bV[5]=hv[1]; bV[6]=hv[2]; bV[7]=hv[3];
    }
    f32x4 m20 = {0.f,0.f,0.f,0.f}, m21 = {0.f,0.f,0.f,0.f};
    m20 = __builtin_amdgcn_mfma_f32_16x16x32_bf16(pa0, bV, m20, 0, 0, 0);
    m21 = __builtin_amdgcn_mfma_f32_16x16x32_bf16(pa1, bV, m21, 0, 0, 0);

    float sm = m20[0] + m20[1] + m20[2] + m20[3];
    if (lg == 0) sm += m21[0] + m21[1] + m21[2] + m21[3];
    sm += __shfl_xor(sm, 16, 64);
    sm += __shfl_xor(sm, 32, 64);
    if (lg == 0) mAs[pr][h * 16 + fr] = sm * 0.05f;
  }
  __syncthreads();

  // ---- out-proj of the mean: 128 threads = 2 pairs x 64 cols, bf16 out ----
  if (t < 128) {
    int p2 = t >> 6, col = t & 63;
    float acc = bob[col];
    const float* wrow = &wo[(size_t)col * 64];
    for (int k = 0; k < 64; k += 4) {
      float4 m4 = *(const float4*)&mAs[p2][k];
      float4 w4 = *(const float4*)(wrow + k);
      acc += m4.x * w4.x + m4.y * w4.y + m4.z * w4.z + m4.w * w4.w;
    }
    X[(size_t)(blockIdx.x * 2 + p2) * 64 + col] = f2bf(acc);
  }
}

// ---------------- GRU recurrence (bf16 G output, full batch) ----------------
__global__ __launch_bounds__(512) void k_gru_mfma(
    const unsigned short* __restrict__ GI,   // [B*O][768]: 0-383 fwd, 384-767 bwd
    const unsigned short* __restrict__ whf,
    const unsigned short* __restrict__ whb,
    const float* __restrict__ bh_f, const float* __restrict__ bh_b,
    unsigned short* __restrict__ G /*[B*O][256] bf16*/)
{
  __shared__ unsigned short hsb[16][136];
  __shared__ float ah[4][392];

  int bid = blockIdx.x;
  int dir = bid >> 8;            // 256 row-groups per dir
  int rg  = bid & 255;
  const unsigned short* wh = dir ? whb : whf;
  const float* bh = dir ? bh_b : bh_f;

  int t = threadIdx.x;
  int w = t >> 6, lane = t & 63;
  int fr = lane & 15, kg = lane >> 4;

  short8v bfr[3][4];
#pragma unroll
  for (int n = 0; n < 3; ++n)
#pragma unroll
    for (int kf = 0; kf < 4; ++kf)
      bfr[n][kf] = *(const short8v*)&wh[(size_t)(w * 48 + n * 16 + fr) * 128 + kf * 32 + kg * 8];

  for (int e = t; e < 16 * 136; e += 512) ((unsigned short*)hsb)[e] = 0;

  int grow = t >> 7, gc = t & 127;
  float bh0 = bh[gc], bh1 = bh[128 + gc], bh2 = bh[256 + gc];
  float hold = 0.f;
  const unsigned short* gip = &GI[(size_t)(rg * 4 + grow) * 50 * 768 + dir * 384];
  unsigned short* gout = &G[((size_t)(rg * 4 + grow) * 50) * 256 + dir * 128 + gc];

  __syncthreads();

  int o0 = dir ? 49 : 0;
  unsigned short c0v = gip[(size_t)o0 * 768 + gc];
  unsigned short c1v = gip[(size_t)o0 * 768 + 128 + gc];
  unsigned short c2v = gip[(size_t)o0 * 768 + 256 + gc];

  for (int s = 0; s < 50; ++s) {
    int o  = dir ? 49 - s : s;
    unsigned short n0v = 0, n1v = 0, n2v = 0;
    if (s < 49) {
      int on = dir ? 48 - s : s + 1;
      n0v = gip[(size_t)on * 768 + gc];
      n1v = gip[(size_t)on * 768 + 128 + gc];
      n2v = gip[(size_t)on * 768 + 256 + gc];
    }

    short8v a0 = *(const short8v*)&hsb[fr][0 * 32 + kg * 8];
    short8v a1 = *(const short8v*)&hsb[fr][1 * 32 + kg * 8];
    short8v a2 = *(const short8v*)&hsb[fr][2 * 32 + kg * 8];
    short8v a3 = *(const short8v*)&hsb[fr][3 * 32 + kg * 8];

    f32x4 acc0 = {0.f,0.f,0.f,0.f}, acc1 = {0.f,0.f,0.f,0.f}, acc2 = {0.f,0.f,0.f,0.f};
    acc0 = __builtin_amdgcn_mfma_f32_16x16x32_bf16(a0, bfr[0][0], acc0, 0, 0, 0);
    acc1 = __builtin_amdgcn_mfma_f32_16x16x32_bf16(a0, bfr[1][0], acc1, 0, 0, 0);
    acc2 = __builtin_amdgcn_mfma_f32_16x16x32_bf16(a0, bfr[2][0], acc2, 0, 0, 0);
    acc0 = __builtin_amdgcn_mfma_f32_16x16x32_bf16(a1, bfr[0][1], acc0, 0, 0, 0);
    acc1 = __builtin_amdgcn_mfma_f32_16x16x32_bf16(a1, bfr[1][1], acc1, 0, 0, 0);
    acc2 = __builtin_amdgcn_mfma_f32_16x16x32_bf16(a1, bfr[2][1], acc2, 0, 0, 0);
    acc0 = __builtin_amdgcn_mfma_f32_16x16x32_bf16(a2, bfr[0][2], acc0, 0, 0, 0);
    acc1 = __builtin_amdgcn_mfma_f32_16x16x32_bf16(a2, bfr[1][2], acc1, 0, 0, 0);
    acc2 = __builtin_amdgcn_mfma_f32_16x16x32_bf16(a2, bfr[2][2], acc2, 0, 0, 0);
    acc0 = __builtin_amdgcn_mfma_f32_16x16x32_bf16(a3, bfr[0][3], acc0, 0, 0, 0);
    acc1 = __builtin_amdgcn_mfma_f32_16x16x32_bf16(a3, bfr[1][3], acc1, 0, 0, 0);
    acc2 = __builtin_amdgcn_mfma_f32_16x16x32_bf16(a3, bfr[2][3], acc2, 0, 0, 0);

    if (kg == 0) {
#pragma unroll
      for (int r = 0; r < 4; ++r) {
        ah[r][w * 48 + 0 * 16 + fr] = acc0[r];
        ah[r][w * 48 + 1 * 16 + fr] = acc1[r];
        ah[r][w * 48 + 2 * 16 + fr] = acc2[r];
      }
    }
    __syncthreads();

    float ai0 = bf2f(c0v), ai1 = bf2f(c1v), ai2 = bf2f(c2v);
    float ah0 = ah[grow][gc] + bh0;
    float ah1 = ah[grow][128 + gc] + bh1;
    float ah2 = ah[grow][256 + gc] + bh2;
    float rr = sig_(ai0 + ah0);
    float zz = sig_(ai1 + ah1);
    float nn = tanh_(ai2 + rr * ah2);
    float h2 = (1.f - zz) * nn + zz * hold;
    hold = h2;
    unsigned short hb = f2bf(h2);
    hsb[grow][gc] = hb;
    gout[(size_t)o * 256] = hb;
    c0v = n0v; c1v = n1v; c2v = n2v;
    __syncthreads();
  }
}

// ---------------- transformer attention core (bf16, in-place q-section) -----
__global__ __launch_bounds__(256) void k_attn_core(unsigned short* __restrict__ BIG)
{
  __shared__ __align__(16) float qs[50][68], ks[50][68], vs[50][68];
  __shared__ float P[50][52];
  int bl = blockIdx.x >> 2, h = blockIdx.x & 3;
  int t = threadIdx.x;
  size_t base = (size_t)bl * 50 * 768;
  int hc = h * 64;

  for (int e = t; e < 800; e += 256) {
    int row = e >> 4, c4 = (e & 15) * 4;
    ushort4v q4 = *(const ushort4v*)&BIG[base + (size_t)row * 768 + hc + c4];
    ushort4v k4 = *(const ushort4v*)&BIG[base + (size_t)row * 768 + 256 + hc + c4];
    ushort4v v4 = *(const ushort4v*)&BIG[base + (size_t)row * 768 + 512 + hc + c4];
#pragma unroll
    for (int j = 0; j < 4; ++j) {
      qs[row][c4 + j] = bf2f(q4[j]);
      ks[row][c4 + j] = bf2f(k4[j]);
      vs[row][c4 + j] = bf2f(v4[j]);
    }
  }
  __syncthreads();

  for (int e = t; e < 2500; e += 256) {
    int i = e / 50, j = e - (e / 50) * 50;
    float d = 0.f;
#pragma unroll
    for (int k = 0; k < 64; k += 4) {
      float4 q = *(const float4*)&qs[i][k];
      float4 kk = *(const float4*)&ks[j][k];
      d += q.x * kk.x + q.y * kk.y + q.z * kk.z + q.w * kk.w;
    }
    P[i][j] = d * 0.125f;
  }
  __syncthreads();

  {
    int l = t & 31, rslot = t >> 5;
    for (int i0 = 0; i0 < 50; i0 += 8) {
      int i = i0 + rslot;
      if (i < 50) {
        float p1 = P[i][l];
        float p2 = (l < 18) ? P[i][l + 32] : -1e30f;
        float m = fmaxf(p1, p2);
#pragma unroll
        for (int d2 = 1; d2 < 32; d2 <<= 1) m = fmaxf(m, __shfl_xor(m, d2, 32));
        float e1 = __expf(p1 - m);
        float e2 = (l < 18) ? __expf(p2 - m) : 0.f;
        float s = e1 + e2;
#pragma unroll
        for (int d2 = 1; d2 < 32; d2 <<= 1) s += __shfl_xor(s, d2, 32);
        float inv = __fdividef(1.f, s);
        P[i][l] = e1 * inv;
        if (l < 18) P[i][l + 32] = e2 * inv;
      }
    }
  }
  __syncthreads();
  for (int e = t; e < 1600; e += 256) {
    int i = e >> 5, c2 = (e & 31) * 2;
    float a0 = 0.f, a1 = 0.f;
    for (int j = 0; j < 50; ++j) {
      float pv = P[i][j];
      a0 += pv * vs[j][c2];
      a1 += pv * vs[j][c2 + 1];
    }
    *(unsigned int*)&BIG[base + (size_t)i * 768 + hc + c2] = pk2bf(a0, a1);
  }
}

// ---------------- fused residual + LayerNorm (bf16 I/O, wave per row) -------
__global__ __launch_bounds__(256) void k_ln_res(
    const unsigned short* __restrict__ res, const unsigned short* __restrict__ add,
    int addld, unsigned short* __restrict__ dst,
    const float* __restrict__ g, const float* __restrict__ bt)
{
  int row = blockIdx.x * 4 + (threadIdx.x >> 6);
  int lane = threadIdx.x & 63;
  int c = lane * 4;
  ushort4v rv = *(const ushort4v*)&res[(size_t)row * 256 + c];
  ushort4v av = *(const ushort4v*)&add[(size_t)row * addld + c];
  float x0 = bf2f(rv[0]) + bf2f(av[0]);
  float x1 = bf2f(rv[1]) + bf2f(av[1]);
  float x2 = bf2f(rv[2]) + bf2f(av[2]);
  float x3 = bf2f(rv[3]) + bf2f(av[3]);
  float s = x0 + x1 + x2 + x3;
  float sq = x0 * x0 + x1 * x1 + x2 * x2 + x3 * x3;
#pragma unroll
  for (int d = 1; d < 64; d <<= 1) { s += __shfl_xor(s, d, 64); sq += __shfl_xor(sq, d, 64); }
  float m = s * (1.f / 256.f);
  float var = sq * (1.f / 256.f) - m * m;
  float rs = rsqrtf(var + 1e-5f);
  float4 gv = *(const float4*)&g[c];
  float4 bv = *(const float4*)&bt[c];
  ushort4v ov;
  ov[0] = f2bf((x0 - m) * rs * gv.x + bv.x);
  ov[1] = f2bf((x1 - m) * rs * gv.y + bv.y);
  ov[2] = f2bf((x2 - m) * rs * gv.z + bv.z);
  ov[3] = f2bf((x3 - m) * rs * gv.w + bv.w);
  *(ushort4v*)&dst[(size_t)row * 256 + c] = ov;
}

// ---------------- temporal encoder + O-mean + final classifier (fused) ------
__global__ __launch_bounds__(256) void k_heads(
    const unsigned short* __restrict__ H2 /*[B*O][256] bf16*/,
    const float* __restrict__ daysb, const float* __restrict__ dayss,
    const float* __restrict__ te1_w, const float* __restrict__ te1_b,
    const float* __restrict__ ln1g, const float* __restrict__ ln1b,
    const float* __restrict__ te2_w, const float* __restrict__ te2_b,
    const float* __restrict__ ln2g, const float* __restrict__ ln2b,
    const float* __restrict__ cWT /*[320][128]*/,
    const float* __restrict__ c_b, const float* __restrict__ clng,
    const float* __restrict__ clnb, float* __restrict__ out)
{
  __shared__ float oe[256];
  __shared__ float feat[2];
  __shared__ float s1[32], s2[64], pre[128], stat[2];
  int b = blockIdx.x, t = threadIdx.x;
  {
    float s = 0.f;
    for (int o = 0; o < 50; ++o) s += bf2f(H2[((size_t)b * 50 + o) * 256 + t]);
    oe[t] = s * 0.02f;
  }
  if (t == 0) {
    float f0 = 0.f;
    for (int i = 0; i < 10; ++i) f0 += daysb[b * 10 + i];
    feat[0] = f0 * 0.1f;
    feat[1] = dayss[b];
  }
  __syncthreads();
  if (t < 32) s1[t] = te1_b[t] + feat[0] * te1_w[2 * t] + feat[1] * te1_w[2 * t + 1];
  __syncthreads();
  if (t == 0) {
    float s = 0.f; for (int j = 0; j < 32; ++j) s += s1[j];
    float m = s * (1.f / 32.f);
    float v = 0.f; for (int j = 0; j < 32; ++j) { float d = s1[j] - m; v += d * d; }
    stat[0] = m; stat[1] = rsqrtf(v * (1.f / 32.f) + 1e-5f);
  }
  __syncthreads();
  if (t < 32) s1[t] = fmaxf((s1[t] - stat[0]) * stat[1] * ln1g[t] + ln1b[t], 0.f);
  __syncthreads();
  if (t < 64) {
    float a = te2_b[t];
    for (int k = 0; k < 32; ++k) a += s1[k] * te2_w[t * 32 + k];
    s2[t] = a;
  }
  __syncthreads();
  if (t == 0) {
    float s = 0.f; for (int j = 0; j < 64; ++j) s += s2[j];
    float m = s * (1.f / 64.f);
    float v = 0.f; for (int j = 0; j < 64; ++j) { float d = s2[j] - m; v += d * d; }
    stat[0] = m; stat[1] = rsqrtf(v * (1.f / 64.f) + 1e-5f);
  }
  __syncthreads();
  if (t < 64) s2[t] = fmaxf((s2[t] - stat[0]) * stat[1] * ln2g[t] + ln2b[t], 0.f);
  __syncthreads();
  if (t < 128) {
    float p = c_b[t];
    for (int k = 0; k < 256; ++k) p += oe[k] * cWT[k * 128 + t];
    for (int k = 0; k < 64; ++k)  p += s2[k] * cWT[(256 + k) * 128 + t];
    pre[t] = p;
  }
  __syncthreads();
  if (t == 0) {
    float s = 0.f; for (int j = 0; j < 128; ++j) s += pre[j];
    float m = s * (1.f / 128.f);
    float v = 0.f; for (int j = 0; j < 128; ++j) { float d = pre[j] - m; v += d * d; }
    stat[0] = m; stat[1] = rsqrtf(v * (1.f / 128.f) + 1e-5f);
  }
  __syncthreads();
  if (t < 128)
    out[(size_t)b * 128 + t] = fmaxf((pre[t] - stat[0]) * stat[1] * clng[t] + clnb[t], 0.f);
}

// ---------------- host launcher ----------------
extern "C" void kernel_launch(void* const* d_in, const int* in_sizes, int n_in,
                              void* d_out, int out_size, void* d_ws, size_t ws_size,
                              hipStream_t stream)
{
  const int*   oh       = (const int*)d_in[0];
  const float* daysb    = (const float*)d_in[1];
  const float* dayss    = (const float*)d_in[2];
  const float* emb      = (const float*)d_in[3];
  const float* ia_in_w  = (const float*)d_in[4];
  const float* ia_in_b  = (const float*)d_in[5];
  const float* ia_out_w = (const float*)d_in[6];
  const float* ia_out_b = (const float*)d_in[7];
  const float* gf_wi = (const float*)d_in[8];
  const float* gf_wh = (const float*)d_in[9];
  const float* gf_bi = (const float*)d_in[10];
  const float* gf_bh = (const float*)d_in[11];
  const float* gb_wi = (const float*)d_in[12];
  const float* gb_wh = (const float*)d_in[13];
  const float* gb_bi = (const float*)d_in[14];
  const float* gb_bh = (const float*)d_in[15];
  const float* ta_in_w  = (const float*)d_in[16];
  const float* ta_in_b  = (const float*)d_in[17];
  const float* ta_out_w = (const float*)d_in[18];
  const float* ta_out_b = (const float*)d_in[19];
  const float* t_ln1_g = (const float*)d_in[20];
  const float* t_ln1_b = (const float*)d_in[21];
  const float* t_ln2_g = (const float*)d_in[22];
  const float* t_ln2_b = (const float*)d_in[23];
  const float* t_ff1_w = (const float*)d_in[24];
  const float* t_ff1_b = (const float*)d_in[25];
  const float* t_ff2_w = (const float*)d_in[26];
  const float* t_ff2_b = (const float*)d_in[27];
  const float* te1_w = (const float*)d_in[28];
  const float* te1_b = (const float*)d_in[29];
  const float* te_ln1_g = (const float*)d_in[30];
  const float* te_ln1_b = (const float*)d_in[31];
  const float* te2_w = (const float*)d_in[32];
  const float* te2_b = (const float*)d_in[33];
  const float* te_ln2_g = (const float*)d_in[34];
  const float* te_ln2_b = (const float*)d_in[35];
  const float* c_w   = (const float*)d_in[36];
  const float* c_b   = (const float*)d_in[37];
  const float* c_ln_g = (const float*)d_in[38];
  const float* c_ln_b = (const float*)d_in[39];

  float* ws = (float*)d_ws;
  // layout (floats):
  const size_t OFF_GB   = 0;                        // G bf16 [51200][256] = 6,553,600 fl
  const size_t OFF_X    = 6553600;                  // X bf16 [51200][64]  = 1,638,400 fl
  const size_t OFF_S    = OFF_X + 1638400;          // QKVall | GI | BIGb  = 19,660,800 fl
  const size_t OW_C     = OFF_S + 19660800;         // [320][128] 40,960
  const size_t OW_BC    = OW_C + 40960;             // 768
  const size_t OW_BQ    = OW_BC + 768;              // padded qkv bias 256
  const size_t OW_BF    = OW_BQ + 256;              // bf16 weight pool 344,064 fl
  const size_t OW_EMB   = OW_BF + 344064;           // bf16 emb table 1,590,048 fl
  const size_t TOTAL    = OW_EMB + 1590048;         // 29,828,896 fl = 119.3 MB
  if (ws_size < TOTAL * sizeof(float)) return;

  unsigned short* Gb = (unsigned short*)(ws + OFF_GB);
  unsigned short* Xb = (unsigned short*)(ws + OFF_X);
  float* w_c  = ws + OW_C;
  float* biascat = ws + OW_BC;
  float* biasq   = ws + OW_BQ;
  unsigned short* bfp = (unsigned short*)(ws + OW_BF);
  unsigned short* b_ta_in  = bfp;                  // 196,608
  unsigned short* b_ta_out = b_ta_in + 196608;     //  65,536
  unsigned short* b_ff1    = b_ta_out + 65536;     // 131,072
  unsigned short* b_ff2    = b_ff1 + 131072;       // 131,072
  unsigned short* b_qkvw   = b_ff2 + 131072;       //  16,384 (padded [256][64])
  unsigned short* b_wi_f   = b_qkvw + 16384;       //  24,576 ── Wcat [768][64]
  unsigned short* b_wi_b   = b_wi_f + 24576;       //  24,576 ──┘
  unsigned short* b_wh_f   = b_wi_b + 24576;       //  49,152
  unsigned short* b_wh_b   = b_wh_f + 49152;       //  49,152
  unsigned short* embb = (unsigned short*)(ws + OW_EMB);  // [(V+1)][64] bf16

  // scratch phase views (aliased; QKVall dead before GI is written):
  unsigned short* QKVall = (unsigned short*)(ws + OFF_S); // [VPAD][256] bf16 (25.5MB)
  unsigned short* GI     = (unsigned short*)(ws + OFF_S); // gru: [51200][768] bf16
  unsigned short* BIGb   = (unsigned short*)(ws + OFF_S); // transformer: [51200][768]

  k_transpose<<<(320 * 128 + 255) / 256, 256, 0, stream>>>(c_w, w_c, 128, 320);
  k_cat_bias<<<3, 256, 0, stream>>>(gf_bi, gb_bi, biascat);
  k_pad_bias<<<1, 256, 0, stream>>>(ia_in_b, biasq, 192, 256);
  #define CV(SRC, DST, N) k_f32bf16<<<((N)+255)/256, 256, 0, stream>>>(SRC, DST, N)
  CV(ta_in_w,  b_ta_in,  196608);
  CV(ta_out_w, b_ta_out, 65536);
  CV(t_ff1_w,  b_ff1,    131072);
  CV(t_ff2_w,  b_ff2,    131072);
  CV(ia_in_w,  b_qkvw,   12288);
  CV(gf_wi,    b_wi_f,   24576);
  CV(gb_wi,    b_wi_b,   24576);
  CV(gf_wh,    b_wh_f,   49152);
  CV(gb_wh,    b_wh_b,   49152);
  CV(emb,      embb,     3180096);      // (V+1)*64 bf16 embedding table
  #undef CV
  k_fill_u16<<<(4096 + 255) / 256, 256, 0, stream>>>(b_qkvw + 12288, 4096);

  // ---- precompute QKVall = embb @ Wqkv^T + b (vocab-wide, once) ----
  k_gemm128<0><<<dim3(256 / 128, VPAD / 128), 256, 0, stream>>>(
      embb, 64, b_qkvw, 64, biasq, QKVall, 256, VROWS);

  // ---- item attention: gather + attend (2 pairs/block) ----
  k_item_fused<<<B_ * O_ / 2, 256, 0, stream>>>(oh, QKVall, ia_out_w, ia_out_b, Xb);

  // ---- bidirectional GRU: single chunk over full batch ----
  k_gemm128<0><<<dim3(768 / 128, 51200 / 128), 256, 0, stream>>>(
      Xb, 64, b_wi_f /*Wcat [768][64]*/, 64, biascat, GI, 768, 51200);
  k_gru_mfma<<<512, 512, 0, stream>>>(GI, b_wh_f, b_wh_b, gf_bh, gb_bh, Gb);

  // ---- transformer layer: single chunk, bf16, in-place in BIGb ----
  k_gemm128<0><<<dim3(768 / 128, 51200 / 128), 256, 0, stream>>>(
      Gb, 256, b_ta_in, 256, ta_in_b, BIGb, 768, 51200);
  k_attn_core<<<B_ * 4, 256, 0, stream>>>(BIGb);
  k_gemm128<0><<<dim3(256 / 128, 51200 / 128), 256, 0, stream>>>(
      BIGb, 768, b_ta_out, 256, ta_out_b, BIGb + 256, 768, 51200);
  k_ln_res<<<51200 / 4, 256, 0, stream>>>(Gb, BIGb + 256, 768, Gb, t_ln1_g, t_ln1_b);
  k_gemm128<1><<<dim3(512 / 128, 51200 / 128), 256, 0, stream>>>(
      Gb, 256, b_ff1, 256, t_ff1_b, BIGb, 768, 51200);
  k_gemm128<0><<<dim3(256 / 128, 51200 / 128), 256, 0, stream>>>(
      BIGb, 768, b_ff2, 512, t_ff2_b, BIGb + 512, 768, 51200);
  k_ln_res<<<51200 / 4, 256, 0, stream>>>(Gb, BIGb + 512, 768, Gb, t_ln2_g, t_ln2_b);

  // ---- fused O-mean + temporal encoder + classifier ----
  k_heads<<<B_, 256, 0, stream>>>(Gb, daysb, dayss, te1_w, te1_b, te_ln1_g, te_ln1_b,
                                  te2_w, te2_b, te_ln2_g, te_ln2_b,
                                  w_c, c_b, c_ln_g, c_ln_b, (float*)d_out);
}

// Round 15
// 576.905 us; speedup vs baseline: 1.2933x; 1.0791x over previous
//
#include <hip/hip_runtime.h>

// NextBasketEncoder — round 15: item V staging via natural b128 gather +
// in-LDS transpose (aliased over Ps scratch); prologue folded to 2 launches
// (k_cv_multi segmented bf16 conversion + k_prep_small). Rest = round 14.
// B=1024, O=50, L=20, D=64, H=128, DM=256, FF=512, V=49688.

#define B_ 1024
#define O_ 50
#define VROWS 49689            // V+1 embedding rows
#define VPAD  49792            // 389*128

typedef __attribute__((ext_vector_type(8))) short  short8v;
typedef __attribute__((ext_vector_type(4))) short  short4v;
typedef __attribute__((ext_vector_type(8))) unsigned short ushort8v;
typedef __attribute__((ext_vector_type(4))) unsigned short ushort4v;
typedef __attribute__((ext_vector_type(4))) float f32x4;

__device__ __forceinline__ float sig_(float x)  { return 1.0f / (1.0f + __expf(-x)); }
__device__ __forceinline__ float tanh_(float x) { return 2.0f / (1.0f + __expf(-2.0f * x)) - 1.0f; }

__device__ __forceinline__ unsigned short f2bf(float f) {
  union { float f; unsigned int u; } v; v.f = f;
  unsigned int r = v.u + 0x7FFFu + ((v.u >> 16) & 1u);   // RNE
  return (unsigned short)(r >> 16);
}
__device__ __forceinline__ float bf2f(unsigned short u) {
  union { unsigned int u; float f; } v; v.u = ((unsigned int)u) << 16;
  return v.f;
}
__device__ __forceinline__ unsigned int pk2bf(float lo, float hi) {
  return (unsigned int)f2bf(lo) | ((unsigned int)f2bf(hi) << 16);
}

// ---------------- segmented fp32 -> bf16 (one launch for all weights) -------
struct CvArgs {
  const float* src[10];
  unsigned short* dst[10];
  int n[10];
};
__global__ void k_cv_multi(CvArgs a) {
  int i = blockIdx.x * 256 + threadIdx.x;
#pragma unroll
  for (int s = 0; s < 10; ++s) {
    if (i < a.n[s]) { a.dst[s][i] = f2bf(a.src[s][i]); return; }
    i -= a.n[s];
  }
}

// ---------------- small prep: c_w transpose | bias concat | bias pad | fill -
__global__ void k_prep_small(const float* __restrict__ c_w, float* __restrict__ w_c,
                             const float* __restrict__ bia, const float* __restrict__ bib,
                             float* __restrict__ biascat,
                             const float* __restrict__ qb, float* __restrict__ biasq,
                             unsigned short* __restrict__ wpad) {
  int i = blockIdx.x * 256 + threadIdx.x;
  if (i < 40960) {                        // transpose c_w [128][320] -> [320][128]
    int r = i / 320, c = i - r * 320;
    w_c[c * 128 + r] = c_w[i];
    return;
  }
  i -= 40960;
  if (i < 768) { biascat[i] = (i < 384) ? bia[i] : bib[i - 384]; return; }
  i -= 768;
  if (i < 256) { biasq[i] = (i < 192) ? qb[i] : 0.f; return; }
  i -= 256;
  if (i < 4096) wpad[i] = 0;              // zero rows 192..255 of padded Wqkv
}

// ---------------- 128x128-tile bf16 GEMM: C = A @ W^T + bias (all bf16) -----
template<int RELU>
__global__ __launch_bounds__(256) void k_gemm128(
    const unsigned short* __restrict__ A, int lda,    // [M][lda] bf16
    const unsigned short* __restrict__ W, int K,      // [N][K] bf16
    const float* __restrict__ bias,
    unsigned short* __restrict__ C, int ldc, int Mclamp)
{
  __shared__ unsigned short As[128 * 40];
  __shared__ unsigned short Bs[128 * 40];
  int n0 = blockIdx.x * 128, m0 = blockIdx.y * 128;
  int t = threadIdx.x, wv = t >> 6, lane = t & 63;
  int fr = lane & 15, kg = lane >> 4;
  int wr = wv >> 1, wc = wv & 1;
  int sr = t >> 1, sc = (t & 1) * 16;

  f32x4 acc[4][4];
#pragma unroll
  for (int mi = 0; mi < 4; ++mi)
#pragma unroll
    for (int ni = 0; ni < 4; ++ni) acc[mi][ni] = (f32x4){0.f, 0.f, 0.f, 0.f};

  int arow = m0 + sr; if (arow >= Mclamp) arow = Mclamp - 1;
  const unsigned short* ga = &A[(size_t)arow * lda + sc];
  const unsigned short* gw = &W[(size_t)(n0 + sr) * K + sc];

  for (int k0 = 0; k0 < K; k0 += 32) {
    ushort8v a0 = *(const ushort8v*)(ga + k0);
    ushort8v a1 = *(const ushort8v*)(ga + k0 + 8);
    ushort8v b0 = *(const ushort8v*)(gw + k0);
    ushort8v b1 = *(const ushort8v*)(gw + k0 + 8);
    __syncthreads();
    *(ushort8v*)&As[sr * 40 + sc]     = a0;
    *(ushort8v*)&As[sr * 40 + sc + 8] = a1;
    *(ushort8v*)&Bs[sr * 40 + sc]     = b0;
    *(ushort8v*)&Bs[sr * 40 + sc + 8] = b1;
    __syncthreads();
    short8v af[4], bfv[4];
#pragma unroll
    for (int mi = 0; mi < 4; ++mi)
      af[mi] = *(const short8v*)&As[(wr * 64 + mi * 16 + fr) * 40 + kg * 8];
#pragma unroll
    for (int ni = 0; ni < 4; ++ni)
      bfv[ni] = *(const short8v*)&Bs[(wc * 64 + ni * 16 + fr) * 40 + kg * 8];
#pragma unroll
    for (int mi = 0; mi < 4; ++mi)
#pragma unroll
      for (int ni = 0; ni < 4; ++ni)
        acc[mi][ni] = __builtin_amdgcn_mfma_f32_16x16x32_bf16(af[mi], bfv[ni], acc[mi][ni], 0, 0, 0);
  }

#pragma unroll
  for (int ni = 0; ni < 4; ++ni) {
    int col = n0 + wc * 64 + ni * 16 + fr;
    float bb = bias[col];
#pragma unroll
    for (int mi = 0; mi < 4; ++mi) {
#pragma unroll
      for (int r = 0; r < 4; ++r) {
        int row = m0 + wr * 64 + mi * 16 + kg * 4 + r;
        float v = acc[mi][ni][r] + bb;
        if (RELU) v = fmaxf(v, 0.f);
        C[(size_t)row * ldc + col] = f2bf(v);
      }
    }
  }
}

// ---------------- fused item attention v5: b128 V gather + LDS transpose ----
// 256 thr = 4 waves = 2 pairs x 2 halves. Natural-V buffer aliases Ps.
__global__ __launch_bounds__(256) void k_item_fused(
    const int* __restrict__ oh,
    const unsigned short* __restrict__ QKVall /*[VPAD][256] bf16*/,
    const float* __restrict__ wo /*[64][64] f32*/, const float* __restrict__ bob,
    unsigned short* __restrict__ X /*[B*O][64] bf16*/)
{
  __shared__ __align__(16) unsigned short QKs[2][20][144];
  __shared__ __align__(16) unsigned short VTs[2][64][36];
  __shared__ __align__(16) unsigned short Ps[4][24][36];   // staging: aliased as Vs[2][20][72]
  __shared__ __align__(16) float mAs[2][68];
  __shared__ int ids[2][20];

  int t = threadIdx.x, wv = t >> 6, lane = t & 63;
  int fr = lane & 15, lg = lane >> 4;
  int pr = wv >> 1, half = wv & 1;
  unsigned short (*Vs)[20][72] = (unsigned short (*)[20][72])&Ps[0][0][0];  // 5760B <= 6912B

  // index preload + VTs seq-pad zero (20..35)
  if (t < 40) ids[t / 20][t % 20] = oh[(size_t)(blockIdx.x * 2 + t / 20) * 20 + (t % 20)];
  {
    unsigned int* vz = (unsigned int*)&VTs[t >> 7][(t >> 1) & 63][20 + (t & 1) * 8];
    vz[0] = 0; vz[1] = 0; vz[2] = 0; vz[3] = 0;
  }
  __syncthreads();

  // ---- gather Q|K rows (b128): 2 pairs x 20 rows x 16 chunks = 640 jobs ----
  for (int e = t; e < 640; e += 256) {
    int pp = e / 320, rem = e - pp * 320;
    int row = rem >> 4, ch = (rem & 15) * 8;
    const unsigned short* src = QKVall + (size_t)ids[pp][row] * 256 + ch;
    *(ushort8v*)&QKs[pp][row][ch] = *(const ushort8v*)src;
  }
  // ---- gather V rows natural (b128): 2 x 20 x 8 chunks = 320 jobs ----
  for (int e = t; e < 320; e += 256) {
    int pp = e / 160, rem = e - pp * 160;
    int row = rem >> 3, ch = (rem & 7) * 8;
    const unsigned short* src = QKVall + (size_t)ids[pp][row] * 256 + 128 + ch;
    *(ushort8v*)&Vs[pp][row][ch] = *(const ushort8v*)src;
  }
  __syncthreads();

  // ---- transpose V in LDS: 2 pairs x 10 jpairs x 32 cpairs = 640 jobs ----
  for (int e = t; e < 640; e += 256) {
    int pp = e / 320, rem = e - pp * 320;
    int jp = rem >> 5, c0 = (rem & 31) * 2;
    unsigned int a = *(const unsigned int*)&Vs[pp][2 * jp][c0];
    unsigned int b = *(const unsigned int*)&Vs[pp][2 * jp + 1][c0];
    *(unsigned int*)&VTs[pp][c0][2 * jp]     = (a & 0xFFFFu) | (b << 16);
    *(unsigned int*)&VTs[pp][c0 + 1][2 * jp] = (a >> 16) | (b & 0xFFFF0000u);
  }
  __syncthreads();

  // per-wave zero of Ps[wv] rows 20..23 (read as zero-pad by AV A-frags)
  for (int e = lane; e < 72; e += 64) {
    int row = 20 + e / 18, col = (e - (e / 18) * 18) * 2;
    *(unsigned int*)&Ps[wv][row][col] = 0;
  }

  // ---- this half's 2 heads: S^T = K@Q^T, no-max softmax, AV via MFMA ----
  int rj1 = (fr + 16 < 20) ? fr + 16 : 19;
  bool iv1 = fr < 4;
  int pr1 = iv1 ? 16 + fr : 20;
#pragma unroll
  for (int hi = 0; hi < 2; ++hi) {
    int h = half * 2 + hi;
    short8v aK0, aK1, bQ0, bQ1;
    {
      short8v z = {0,0,0,0,0,0,0,0};
      aK0 = z; aK1 = z; bQ0 = z; bQ1 = z;
    }
    if (lg < 2) {
      aK0 = *(const short8v*)&QKs[pr][fr][64 + h * 16 + lg * 8];
      aK1 = *(const short8v*)&QKs[pr][rj1][64 + h * 16 + lg * 8];
      bQ0 = *(const short8v*)&QKs[pr][fr][h * 16 + lg * 8];
      bQ1 = *(const short8v*)&QKs[pr][rj1][h * 16 + lg * 8];
    }
    f32x4 s00 = {0.f,0.f,0.f,0.f}, s01 = {0.f,0.f,0.f,0.f};
    f32x4 s10 = {0.f,0.f,0.f,0.f}, s11 = {0.f,0.f,0.f,0.f};
    s00 = __builtin_amdgcn_mfma_f32_16x16x32_bf16(aK0, bQ0, s00, 0, 0, 0);
    s01 = __builtin_amdgcn_mfma_f32_16x16x32_bf16(aK0, bQ1, s01, 0, 0, 0);
    s10 = __builtin_amdgcn_mfma_f32_16x16x32_bf16(aK1, bQ0, s10, 0, 0, 0);
    s11 = __builtin_amdgcn_mfma_f32_16x16x32_bf16(aK1, bQ1, s11, 0, 0, 0);

    float e00[4], e01[4], e10[4], e11[4];
    float d0 = 0.f, d1 = 0.f;
#pragma unroll
    for (int r = 0; r < 4; ++r) {
      int j1 = 16 + lg * 4 + r;
      bool jv1 = j1 < 20;
      float v00 = __expf(0.25f * s00[r]);
      float v01 = iv1 ? __expf(0.25f * s01[r]) : 0.f;
      float v10 = jv1 ? __expf(0.25f * s10[r]) : 0.f;
      float v11 = (jv1 && iv1) ? __expf(0.25f * s11[r]) : 0.f;
      e00[r] = v00; e01[r] = v01; e10[r] = v10; e11[r] = v11;
      d0 += v00 + v10; d1 += v01 + v11;
    }
    d0 += __shfl_xor(d0, 16, 64); d0 += __shfl_xor(d0, 32, 64);
    d1 += __shfl_xor(d1, 16, 64); d1 += __shfl_xor(d1, 32, 64);
    float inv0 = __fdividef(1.f, d0);
    float inv1 = iv1 ? __fdividef(1.f, d1) : 0.f;

    *(unsigned int*)&Ps[wv][fr][lg * 4]          = pk2bf(e00[0]*inv0, e00[1]*inv0);
    *(unsigned int*)&Ps[wv][fr][lg * 4 + 2]      = pk2bf(e00[2]*inv0, e00[3]*inv0);
    *(unsigned int*)&Ps[wv][fr][16 + lg * 4]     = pk2bf(e10[0]*inv0, e10[1]*inv0);
    *(unsigned int*)&Ps[wv][fr][16 + lg * 4 + 2] = pk2bf(e10[2]*inv0, e10[3]*inv0);
    if (iv1) {
      *(unsigned int*)&Ps[wv][16 + fr][lg * 4]          = pk2bf(e01[0]*inv1, e01[1]*inv1);
      *(unsigned int*)&Ps[wv][16 + fr][lg * 4 + 2]      = pk2bf(e01[2]*inv1, e01[3]*inv1);
      *(unsigned int*)&Ps[wv][16 + fr][16 + lg * 4]     = pk2bf(e11[0]*inv1, e11[1]*inv1);
      *(unsigned int*)&Ps[wv][16 + fr][16 + lg * 4 + 2] = pk2bf(e11[2]*inv1, e11[3]*inv1);
    }

    short8v pa0, pa1, bV;
    {
      short4v l0 = *(const short4v*)&Ps[wv][fr][lg * 8];
      short4v h0 = *(const short4v*)&Ps[wv][fr][lg * 8 + 4];
      short4v l1 = *(const short4v*)&Ps[wv][pr1][lg * 8];
      short4v h1 = *(const short4v*)&Ps[wv][pr1][lg * 8 + 4];
      short4v lv = *(const short4v*)&VTs[pr][h * 16 + fr][lg * 8];
      short4v hv = *(const short4v*)&VTs[pr][h * 16 + fr][lg * 8 + 4];
      pa0[0]=l0[0]; pa0[1]=l0[1]; pa0[2]=l0[2]; pa0[3]=l0[3];
      pa0[4]=h0[0]; pa0[5]=h0[1]; pa0[6]=h0[2]; pa0[7]=h0[3];
      pa1[0]=l1[0]; pa1[1]=l1[1]; pa1[2]=l1[2]; pa1[3]=l1[3];
      pa1[4]=h1[0]; pa1[5]=h1[1]; pa1[6]=h1[2]; pa1[7]=h1[3];
      bV[0]=lv[0]; bV[1]=lv[1]; bV[2]=lv[2]; bV[3]=lv[3];
      bV[4]=hv[0]; bV[5]=hv[1]; bV[6]=hv[2]; bV[7]=hv[3];
    }
    f32x4 m20 = {0.f,0.f,0.f,0.f}, m21 = {0.f,0.f,0.f,0.f};
    m20 = __builtin_amdgcn_mfma_f32_16x16x32_bf16(pa0, bV, m20, 0, 0, 0);
    m21 = __builtin_amdgcn_mfma_f32_16x16x32_bf16(pa1, bV, m21, 0, 0, 0);

    float sm = m20[0] + m20[1] + m20[2] + m20[3];
    if (lg == 0) sm += m21[0] + m21[1] + m21[2] + m21[3];
    sm += __shfl_xor(sm, 16, 64);
    sm += __shfl_xor(sm, 32, 64);
    if (lg == 0) mAs[pr][h * 16 + fr] = sm * 0.05f;
  }
  __syncthreads();

  // ---- out-proj of the mean: 128 threads = 2 pairs x 64 cols, bf16 out ----
  if (t < 128) {
    int p2 = t >> 6, col = t & 63;
    float acc = bob[col];
    const float* wrow = &wo[(size_t)col * 64];
    for (int k = 0; k < 64; k += 4) {
      float4 m4 = *(const float4*)&mAs[p2][k];
      float4 w4 = *(const float4*)(wrow + k);
      acc += m4.x * w4.x + m4.y * w4.y + m4.z * w4.z + m4.w * w4.w;
    }
    X[(size_t)(blockIdx.x * 2 + p2) * 64 + col] = f2bf(acc);
  }
}

// ---------------- GRU recurrence (bf16 G output, full batch) ----------------
__global__ __launch_bounds__(512) void k_gru_mfma(
    const unsigned short* __restrict__ GI,   // [B*O][768]: 0-383 fwd, 384-767 bwd
    const unsigned short* __restrict__ whf,
    const unsigned short* __restrict__ whb,
    const float* __restrict__ bh_f, const float* __restrict__ bh_b,
    unsigned short* __restrict__ G /*[B*O][256] bf16*/)
{
  __shared__ unsigned short hsb[16][136];
  __shared__ float ah[4][392];

  int bid = blockIdx.x;
  int dir = bid >> 8;            // 256 row-groups per dir
  int rg  = bid & 255;
  const unsigned short* wh = dir ? whb : whf;
  const float* bh = dir ? bh_b : bh_f;

  int t = threadIdx.x;
  int w = t >> 6, lane = t & 63;
  int fr = lane & 15, kg = lane >> 4;

  short8v bfr[3][4];
#pragma unroll
  for (int n = 0; n < 3; ++n)
#pragma unroll
    for (int kf = 0; kf < 4; ++kf)
      bfr[n][kf] = *(const short8v*)&wh[(size_t)(w * 48 + n * 16 + fr) * 128 + kf * 32 + kg * 8];

  for (int e = t; e < 16 * 136; e += 512) ((unsigned short*)hsb)[e] = 0;

  int grow = t >> 7, gc = t & 127;
  float bh0 = bh[gc], bh1 = bh[128 + gc], bh2 = bh[256 + gc];
  float hold = 0.f;
  const unsigned short* gip = &GI[(size_t)(rg * 4 + grow) * 50 * 768 + dir * 384];
  unsigned short* gout = &G[((size_t)(rg * 4 + grow) * 50) * 256 + dir * 128 + gc];

  __syncthreads();

  int o0 = dir ? 49 : 0;
  unsigned short c0v = gip[(size_t)o0 * 768 + gc];
  unsigned short c1v = gip[(size_t)o0 * 768 + 128 + gc];
  unsigned short c2v = gip[(size_t)o0 * 768 + 256 + gc];

  for (int s = 0; s < 50; ++s) {
    int o  = dir ? 49 - s : s;
    unsigned short n0v = 0, n1v = 0, n2v = 0;
    if (s < 49) {
      int on = dir ? 48 - s : s + 1;
      n0v = gip[(size_t)on * 768 + gc];
      n1v = gip[(size_t)on * 768 + 128 + gc];
      n2v = gip[(size_t)on * 768 + 256 + gc];
    }

    short8v a0 = *(const short8v*)&hsb[fr][0 * 32 + kg * 8];
    short8v a1 = *(const short8v*)&hsb[fr][1 * 32 + kg * 8];
    short8v a2 = *(const short8v*)&hsb[fr][2 * 32 + kg * 8];
    short8v a3 = *(const short8v*)&hsb[fr][3 * 32 + kg * 8];

    f32x4 acc0 = {0.f,0.f,0.f,0.f}, acc1 = {0.f,0.f,0.f,0.f}, acc2 = {0.f,0.f,0.f,0.f};
    acc0 = __builtin_amdgcn_mfma_f32_16x16x32_bf16(a0, bfr[0][0], acc0, 0, 0, 0);
    acc1 = __builtin_amdgcn_mfma_f32_16x16x32_bf16(a0, bfr[1][0], acc1, 0, 0, 0);
    acc2 = __builtin_amdgcn_mfma_f32_16x16x32_bf16(a0, bfr[2][0], acc2, 0, 0, 0);
    acc0 = __builtin_amdgcn_mfma_f32_16x16x32_bf16(a1, bfr[0][1], acc0, 0, 0, 0);
    acc1 = __builtin_amdgcn_mfma_f32_16x16x32_bf16(a1, bfr[1][1], acc1, 0, 0, 0);
    acc2 = __builtin_amdgcn_mfma_f32_16x16x32_bf16(a1, bfr[2][1], acc2, 0, 0, 0);
    acc0 = __builtin_amdgcn_mfma_f32_16x16x32_bf16(a2, bfr[0][2], acc0, 0, 0, 0);
    acc1 = __builtin_amdgcn_mfma_f32_16x16x32_bf16(a2, bfr[1][2], acc1, 0, 0, 0);
    acc2 = __builtin_amdgcn_mfma_f32_16x16x32_bf16(a2, bfr[2][2], acc2, 0, 0, 0);
    acc0 = __builtin_amdgcn_mfma_f32_16x16x32_bf16(a3, bfr[0][3], acc0, 0, 0, 0);
    acc1 = __builtin_amdgcn_mfma_f32_16x16x32_bf16(a3, bfr[1][3], acc1, 0, 0, 0);
    acc2 = __builtin_amdgcn_mfma_f32_16x16x32_bf16(a3, bfr[2][3], acc2, 0, 0, 0);

    if (kg == 0) {
#pragma unroll
      for (int r = 0; r < 4; ++r) {
        ah[r][w * 48 + 0 * 16 + fr] = acc0[r];
        ah[r][w * 48 + 1 * 16 + fr] = acc1[r];
        ah[r][w * 48 + 2 * 16 + fr] = acc2[r];
      }
    }
    __syncthreads();

    float ai0 = bf2f(c0v), ai1 = bf2f(c1v), ai2 = bf2f(c2v);
    float ah0 = ah[grow][gc] + bh0;
    float ah1 = ah[grow][128 + gc] + bh1;
    float ah2 = ah[grow][256 + gc] + bh2;
    float rr = sig_(ai0 + ah0);
    float zz = sig_(ai1 + ah1);
    float nn = tanh_(ai2 + rr * ah2);
    float h2 = (1.f - zz) * nn + zz * hold;
    hold = h2;
    unsigned short hb = f2bf(h2);
    hsb[grow][gc] = hb;
    gout[(size_t)o * 256] = hb;
    c0v = n0v; c1v = n1v; c2v = n2v;
    __syncthreads();
  }
}

// ---------------- transformer attention core (bf16, in-place q-section) -----
__global__ __launch_bounds__(256) void k_attn_core(unsigned short* __restrict__ BIG)
{
  __shared__ __align__(16) float qs[50][68], ks[50][68], vs[50][68];
  __shared__ float P[50][52];
  int bl = blockIdx.x >> 2, h = blockIdx.x & 3;
  int t = threadIdx.x;
  size_t base = (size_t)bl * 50 * 768;
  int hc = h * 64;

  for (int e = t; e < 800; e += 256) {
    int row = e >> 4, c4 = (e & 15) * 4;
    ushort4v q4 = *(const ushort4v*)&BIG[base + (size_t)row * 768 + hc + c4];
    ushort4v k4 = *(const ushort4v*)&BIG[base + (size_t)row * 768 + 256 + hc + c4];
    ushort4v v4 = *(const ushort4v*)&BIG[base + (size_t)row * 768 + 512 + hc + c4];
#pragma unroll
    for (int j = 0; j < 4; ++j) {
      qs[row][c4 + j] = bf2f(q4[j]);
      ks[row][c4 + j] = bf2f(k4[j]);
      vs[row][c4 + j] = bf2f(v4[j]);
    }
  }
  __syncthreads();

  for (int e = t; e < 2500; e += 256) {
    int i = e / 50, j = e - (e / 50) * 50;
    float d = 0.f;
#pragma unroll
    for (int k = 0; k < 64; k += 4) {
      float4 q = *(const float4*)&qs[i][k];
      float4 kk = *(const float4*)&ks[j][k];
      d += q.x * kk.x + q.y * kk.y + q.z * kk.z + q.w * kk.w;
    }
    P[i][j] = d * 0.125f;
  }
  __syncthreads();

  {
    int l = t & 31, rslot = t >> 5;
    for (int i0 = 0; i0 < 50; i0 += 8) {
      int i = i0 + rslot;
      if (i < 50) {
        float p1 = P[i][l];
        float p2 = (l < 18) ? P[i][l + 32] : -1e30f;
        float m = fmaxf(p1, p2);
#pragma unroll
        for (int d2 = 1; d2 < 32; d2 <<= 1) m = fmaxf(m, __shfl_xor(m, d2, 32));
        float e1 = __expf(p1 - m);
        float e2 = (l < 18) ? __expf(p2 - m) : 0.f;
        float s = e1 + e2;
#pragma unroll
        for (int d2 = 1; d2 < 32; d2 <<= 1) s += __shfl_xor(s, d2, 32);
        float inv = __fdividef(1.f, s);
        P[i][l] = e1 * inv;
        if (l < 18) P[i][l + 32] = e2 * inv;
      }
    }
  }
  __syncthreads();
  for (int e = t; e < 1600; e += 256) {
    int i = e >> 5, c2 = (e & 31) * 2;
    float a0 = 0.f, a1 = 0.f;
    for (int j = 0; j < 50; ++j) {
      float pv = P[i][j];
      a0 += pv * vs[j][c2];
      a1 += pv * vs[j][c2 + 1];
    }
    *(unsigned int*)&BIG[base + (size_t)i * 768 + hc + c2] = pk2bf(a0, a1);
  }
}

// ---------------- fused residual + LayerNorm (bf16 I/O, wave per row) -------
__global__ __launch_bounds__(256) void k_ln_res(
    const unsigned short* __restrict__ res, const unsigned short* __restrict__ add,
    int addld, unsigned short* __restrict__ dst,
    const float* __restrict__ g, const float* __restrict__ bt)
{
  int row = blockIdx.x * 4 + (threadIdx.x >> 6);
  int lane = threadIdx.x & 63;
  int c = lane * 4;
  ushort4v rv = *(const ushort4v*)&res[(size_t)row * 256 + c];
  ushort4v av = *(const ushort4v*)&add[(size_t)row * addld + c];
  float x0 = bf2f(rv[0]) + bf2f(av[0]);
  float x1 = bf2f(rv[1]) + bf2f(av[1]);
  float x2 = bf2f(rv[2]) + bf2f(av[2]);
  float x3 = bf2f(rv[3]) + bf2f(av[3]);
  float s = x0 + x1 + x2 + x3;
  float sq = x0 * x0 + x1 * x1 + x2 * x2 + x3 * x3;
#pragma unroll
  for (int d = 1; d < 64; d <<= 1) { s += __shfl_xor(s, d, 64); sq += __shfl_xor(sq, d, 64); }
  float m = s * (1.f / 256.f);
  float var = sq * (1.f / 256.f) - m * m;
  float rs = rsqrtf(var + 1e-5f);
  float4 gv = *(const float4*)&g[c];
  float4 bv = *(const float4*)&bt[c];
  ushort4v ov;
  ov[0] = f2bf((x0 - m) * rs * gv.x + bv.x);
  ov[1] = f2bf((x1 - m) * rs * gv.y + bv.y);
  ov[2] = f2bf((x2 - m) * rs * gv.z + bv.z);
  ov[3] = f2bf((x3 - m) * rs * gv.w + bv.w);
  *(ushort4v*)&dst[(size_t)row * 256 + c] = ov;
}

// ---------------- temporal encoder + O-mean + final classifier (fused) ------
__global__ __launch_bounds__(256) void k_heads(
    const unsigned short* __restrict__ H2 /*[B*O][256] bf16*/,
    const float* __restrict__ daysb, const float* __restrict__ dayss,
    const float* __restrict__ te1_w, const float* __restrict__ te1_b,
    const float* __restrict__ ln1g, const float* __restrict__ ln1b,
    const float* __restrict__ te2_w, const float* __restrict__ te2_b,
    const float* __restrict__ ln2g, const float* __restrict__ ln2b,
    const float* __restrict__ cWT /*[320][128]*/,
    const float* __restrict__ c_b, const float* __restrict__ clng,
    const float* __restrict__ clnb, float* __restrict__ out)
{
  __shared__ float oe[256];
  __shared__ float feat[2];
  __shared__ float s1[32], s2[64], pre[128], stat[2];
  int b = blockIdx.x, t = threadIdx.x;
  {
    float s = 0.f;
    for (int o = 0; o < 50; ++o) s += bf2f(H2[((size_t)b * 50 + o) * 256 + t]);
    oe[t] = s * 0.02f;
  }
  if (t == 0) {
    float f0 = 0.f;
    for (int i = 0; i < 10; ++i) f0 += daysb[b * 10 + i];
    feat[0] = f0 * 0.1f;
    feat[1] = dayss[b];
  }
  __syncthreads();
  if (t < 32) s1[t] = te1_b[t] + feat[0] * te1_w[2 * t] + feat[1] * te1_w[2 * t + 1];
  __syncthreads();
  if (t == 0) {
    float s = 0.f; for (int j = 0; j < 32; ++j) s += s1[j];
    float m = s * (1.f / 32.f);
    float v = 0.f; for (int j = 0; j < 32; ++j) { float d = s1[j] - m; v += d * d; }
    stat[0] = m; stat[1] = rsqrtf(v * (1.f / 32.f) + 1e-5f);
  }
  __syncthreads();
  if (t < 32) s1[t] = fmaxf((s1[t] - stat[0]) * stat[1] * ln1g[t] + ln1b[t], 0.f);
  __syncthreads();
  if (t < 64) {
    float a = te2_b[t];
    for (int k = 0; k < 32; ++k) a += s1[k] * te2_w[t * 32 + k];
    s2[t] = a;
  }
  __syncthreads();
  if (t == 0) {
    float s = 0.f; for (int j = 0; j < 64; ++j) s += s2[j];
    float m = s * (1.f / 64.f);
    float v = 0.f; for (int j = 0; j < 64; ++j) { float d = s2[j] - m; v += d * d; }
    stat[0] = m; stat[1] = rsqrtf(v * (1.f / 64.f) + 1e-5f);
  }
  __syncthreads();
  if (t < 64) s2[t] = fmaxf((s2[t] - stat[0]) * stat[1] * ln2g[t] + ln2b[t], 0.f);
  __syncthreads();
  if (t < 128) {
    float p = c_b[t];
    for (int k = 0; k < 256; ++k) p += oe[k] * cWT[k * 128 + t];
    for (int k = 0; k < 64; ++k)  p += s2[k] * cWT[(256 + k) * 128 + t];
    pre[t] = p;
  }
  __syncthreads();
  if (t == 0) {
    float s = 0.f; for (int j = 0; j < 128; ++j) s += pre[j];
    float m = s * (1.f / 128.f);
    float v = 0.f; for (int j = 0; j < 128; ++j) { float d = pre[j] - m; v += d * d; }
    stat[0] = m; stat[1] = rsqrtf(v * (1.f / 128.f) + 1e-5f);
  }
  __syncthreads();
  if (t < 128)
    out[(size_t)b * 128 + t] = fmaxf((pre[t] - stat[0]) * stat[1] * clng[t] + clnb[t], 0.f);
}

// ---------------- host launcher ----------------
extern "C" void kernel_launch(void* const* d_in, const int* in_sizes, int n_in,
                              void* d_out, int out_size, void* d_ws, size_t ws_size,
                              hipStream_t stream)
{
  const int*   oh       = (const int*)d_in[0];
  const float* daysb    = (const float*)d_in[1];
  const float* dayss    = (const float*)d_in[2];
  const float* emb      = (const float*)d_in[3];
  const float* ia_in_w  = (const float*)d_in[4];
  const float* ia_in_b  = (const float*)d_in[5];
  const float* ia_out_w = (const float*)d_in[6];
  const float* ia_out_b = (const float*)d_in[7];
  const float* gf_wi = (const float*)d_in[8];
  const float* gf_wh = (const float*)d_in[9];
  const float* gf_bi = (const float*)d_in[10];
  const float* gf_bh = (const float*)d_in[11];
  const float* gb_wi = (const float*)d_in[12];
  const float* gb_wh = (const float*)d_in[13];
  const float* gb_bi = (const float*)d_in[14];
  const float* gb_bh = (const float*)d_in[15];
  const float* ta_in_w  = (const float*)d_in[16];
  const float* ta_in_b  = (const float*)d_in[17];
  const float* ta_out_w = (const float*)d_in[18];
  const float* ta_out_b = (const float*)d_in[19];
  const float* t_ln1_g = (const float*)d_in[20];
  const float* t_ln1_b = (const float*)d_in[21];
  const float* t_ln2_g = (const float*)d_in[22];
  const float* t_ln2_b = (const float*)d_in[23];
  const float* t_ff1_w = (const float*)d_in[24];
  const float* t_ff1_b = (const float*)d_in[25];
  const float* t_ff2_w = (const float*)d_in[26];
  const float* t_ff2_b = (const float*)d_in[27];
  const float* te1_w = (const float*)d_in[28];
  const float* te1_b = (const float*)d_in[29];
  const float* te_ln1_g = (const float*)d_in[30];
  const float* te_ln1_b = (const float*)d_in[31];
  const float* te2_w = (const float*)d_in[32];
  const float* te2_b = (const float*)d_in[33];
  const float* te_ln2_g = (const float*)d_in[34];
  const float* te_ln2_b = (const float*)d_in[35];
  const float* c_w   = (const float*)d_in[36];
  const float* c_b   = (const float*)d_in[37];
  const float* c_ln_g = (const float*)d_in[38];
  const float* c_ln_b = (const float*)d_in[39];

  float* ws = (float*)d_ws;
  // layout (floats):
  const size_t OFF_GB   = 0;                        // G bf16 [51200][256] = 6,553,600 fl
  const size_t OFF_X    = 6553600;                  // X bf16 [51200][64]  = 1,638,400 fl
  const size_t OFF_S    = OFF_X + 1638400;          // QKVall | GI | BIGb  = 19,660,800 fl
  const size_t OW_C     = OFF_S + 19660800;         // [320][128] 40,960
  const size_t OW_BC    = OW_C + 40960;             // 768
  const size_t OW_BQ    = OW_BC + 768;              // padded qkv bias 256
  const size_t OW_BF    = OW_BQ + 256;              // bf16 weight pool 344,064 fl
  const size_t OW_EMB   = OW_BF + 344064;           // bf16 emb table 1,590,048 fl
  const size_t TOTAL    = OW_EMB + 1590048;         // 29,828,896 fl = 119.3 MB
  if (ws_size < TOTAL * sizeof(float)) return;

  unsigned short* Gb = (unsigned short*)(ws + OFF_GB);
  unsigned short* Xb = (unsigned short*)(ws + OFF_X);
  float* w_c  = ws + OW_C;
  float* biascat = ws + OW_BC;
  float* biasq   = ws + OW_BQ;
  unsigned short* bfp = (unsigned short*)(ws + OW_BF);
  unsigned short* b_ta_in  = bfp;                  // 196,608
  unsigned short* b_ta_out = b_ta_in + 196608;     //  65,536
  unsigned short* b_ff1    = b_ta_out + 65536;     // 131,072
  unsigned short* b_ff2    = b_ff1 + 131072;       // 131,072
  unsigned short* b_qkvw   = b_ff2 + 131072;       //  16,384 (padded [256][64])
  unsigned short* b_wi_f   = b_qkvw + 16384;       //  24,576 ── Wcat [768][64]
  unsigned short* b_wi_b   = b_wi_f + 24576;       //  24,576 ──┘
  unsigned short* b_wh_f   = b_wi_b + 24576;       //  49,152
  unsigned short* b_wh_b   = b_wh_f + 49152;       //  49,152
  unsigned short* embb = (unsigned short*)(ws + OW_EMB);  // [(V+1)][64] bf16

  // scratch phase views (aliased; QKVall dead before GI is written):
  unsigned short* QKVall = (unsigned short*)(ws + OFF_S); // [VPAD][256] bf16 (25.5MB)
  unsigned short* GI     = (unsigned short*)(ws + OFF_S); // gru: [51200][768] bf16
  unsigned short* BIGb   = (unsigned short*)(ws + OFF_S); // transformer: [51200][768]

  // ---- prologue: 2 launches ----
  k_prep_small<<<(40960 + 768 + 256 + 4096 + 255) / 256, 256, 0, stream>>>(
      c_w, w_c, gf_bi, gb_bi, biascat, ia_in_b, biasq, b_qkvw + 12288);
  {
    CvArgs a;
    a.src[0] = ta_in_w;  a.dst[0] = b_ta_in;  a.n[0] = 196608;
    a.src[1] = ta_out_w; a.dst[1] = b_ta_out; a.n[1] = 65536;
    a.src[2] = t_ff1_w;  a.dst[2] = b_ff1;    a.n[2] = 131072;
    a.src[3] = t_ff2_w;  a.dst[3] = b_ff2;    a.n[3] = 131072;
    a.src[4] = ia_in_w;  a.dst[4] = b_qkvw;   a.n[4] = 12288;
    a.src[5] = gf_wi;    a.dst[5] = b_wi_f;   a.n[5] = 24576;
    a.src[6] = gb_wi;    a.dst[6] = b_wi_b;   a.n[6] = 24576;
    a.src[7] = gf_wh;    a.dst[7] = b_wh_f;   a.n[7] = 49152;
    a.src[8] = gb_wh;    a.dst[8] = b_wh_b;   a.n[8] = 49152;
    a.src[9] = emb;      a.dst[9] = embb;     a.n[9] = 3180096;
    int total = 196608 + 65536 + 131072 + 131072 + 12288 + 24576 + 24576 + 49152 + 49152 + 3180096;
    k_cv_multi<<<(total + 255) / 256, 256, 0, stream>>>(a);
  }

  // ---- precompute QKVall = embb @ Wqkv^T + b (vocab-wide, once) ----
  k_gemm128<0><<<dim3(256 / 128, VPAD / 128), 256, 0, stream>>>(
      embb, 64, b_qkvw, 64, biasq, QKVall, 256, VROWS);

  // ---- item attention: gather + attend (2 pairs/block) ----
  k_item_fused<<<B_ * O_ / 2, 256, 0, stream>>>(oh, QKVall, ia_out_w, ia_out_b, Xb);

  // ---- bidirectional GRU: single chunk over full batch ----
  k_gemm128<0><<<dim3(768 / 128, 51200 / 128), 256, 0, stream>>>(
      Xb, 64, b_wi_f /*Wcat [768][64]*/, 64, biascat, GI, 768, 51200);
  k_gru_mfma<<<512, 512, 0, stream>>>(GI, b_wh_f, b_wh_b, gf_bh, gb_bh, Gb);

  // ---- transformer layer: single chunk, bf16, in-place in BIGb ----
  k_gemm128<0><<<dim3(768 / 128, 51200 / 128), 256, 0, stream>>>(
      Gb, 256, b_ta_in, 256, ta_in_b, BIGb, 768, 51200);
  k_attn_core<<<B_ * 4, 256, 0, stream>>>(BIGb);
  k_gemm128<0><<<dim3(256 / 128, 51200 / 128), 256, 0, stream>>>(
      BIGb, 768, b_ta_out, 256, ta_out_b, BIGb + 256, 768, 51200);
  k_ln_res<<<51200 / 4, 256, 0, stream>>>(Gb, BIGb + 256, 768, Gb, t_ln1_g, t_ln1_b);
  k_gemm128<1><<<dim3(512 / 128, 51200 / 128), 256, 0, stream>>>(
      Gb, 256, b_ff1, 256, t_ff1_b, BIGb, 768, 51200);
  k_gemm128<0><<<dim3(256 / 128, 51200 / 128), 256, 0, stream>>>(
      BIGb, 768, b_ff2, 512, t_ff2_b, BIGb + 512, 768, 51200);
  k_ln_res<<<51200 / 4, 256, 0, stream>>>(Gb, BIGb + 512, 768, Gb, t_ln2_g, t_ln2_b);

  // ---- fused O-mean + temporal encoder + classifier ----
  k_heads<<<B_, 256, 0, stream>>>(Gb, daysb, dayss, te1_w, te1_b, te_ln1_g, te_ln1_b,
                                  te2_w, te2_b, te_ln2_g, te_ln2_b,
                                  w_c, c_b, c_ln_g, c_ln_b, (float*)d_out);
}

// Round 16
// 516.521 us; speedup vs baseline: 1.4445x; 1.1169x over previous
//
#include <hip/hip_runtime.h>

// NextBasketEncoder — round 16: k_attn_core rebuilt on MFMA (swapped-operand
// QK^T, bf16 P, MFMA PV) mirroring the verified item-kernel pattern; max-
// subtracting softmax retained. All other kernels identical to round 15.
// B=1024, O=50, L=20, D=64, H=128, DM=256, FF=512, V=49688.

#define B_ 1024
#define O_ 50
#define VROWS 49689            // V+1 embedding rows
#define VPAD  49792            // 389*128

typedef __attribute__((ext_vector_type(8))) short  short8v;
typedef __attribute__((ext_vector_type(4))) short  short4v;
typedef __attribute__((ext_vector_type(8))) unsigned short ushort8v;
typedef __attribute__((ext_vector_type(4))) unsigned short ushort4v;
typedef __attribute__((ext_vector_type(4))) float f32x4;

__device__ __forceinline__ float sig_(float x)  { return 1.0f / (1.0f + __expf(-x)); }
__device__ __forceinline__ float tanh_(float x) { return 2.0f / (1.0f + __expf(-2.0f * x)) - 1.0f; }

__device__ __forceinline__ unsigned short f2bf(float f) {
  union { float f; unsigned int u; } v; v.f = f;
  unsigned int r = v.u + 0x7FFFu + ((v.u >> 16) & 1u);   // RNE
  return (unsigned short)(r >> 16);
}
__device__ __forceinline__ float bf2f(unsigned short u) {
  union { unsigned int u; float f; } v; v.u = ((unsigned int)u) << 16;
  return v.f;
}
__device__ __forceinline__ unsigned int pk2bf(float lo, float hi) {
  return (unsigned int)f2bf(lo) | ((unsigned int)f2bf(hi) << 16);
}

// ---------------- segmented fp32 -> bf16 (one launch for all weights) -------
struct CvArgs {
  const float* src[10];
  unsigned short* dst[10];
  int n[10];
};
__global__ void k_cv_multi(CvArgs a) {
  int i = blockIdx.x * 256 + threadIdx.x;
#pragma unroll
  for (int s = 0; s < 10; ++s) {
    if (i < a.n[s]) { a.dst[s][i] = f2bf(a.src[s][i]); return; }
    i -= a.n[s];
  }
}

// ---------------- small prep: c_w transpose | bias concat | bias pad | fill -
__global__ void k_prep_small(const float* __restrict__ c_w, float* __restrict__ w_c,
                             const float* __restrict__ bia, const float* __restrict__ bib,
                             float* __restrict__ biascat,
                             const float* __restrict__ qb, float* __restrict__ biasq,
                             unsigned short* __restrict__ wpad) {
  int i = blockIdx.x * 256 + threadIdx.x;
  if (i < 40960) {                        // transpose c_w [128][320] -> [320][128]
    int r = i / 320, c = i - r * 320;
    w_c[c * 128 + r] = c_w[i];
    return;
  }
  i -= 40960;
  if (i < 768) { biascat[i] = (i < 384) ? bia[i] : bib[i - 384]; return; }
  i -= 768;
  if (i < 256) { biasq[i] = (i < 192) ? qb[i] : 0.f; return; }
  i -= 256;
  if (i < 4096) wpad[i] = 0;              // zero rows 192..255 of padded Wqkv
}

// ---------------- 128x128-tile bf16 GEMM: C = A @ W^T + bias (all bf16) -----
template<int RELU>
__global__ __launch_bounds__(256) void k_gemm128(
    const unsigned short* __restrict__ A, int lda,    // [M][lda] bf16
    const unsigned short* __restrict__ W, int K,      // [N][K] bf16
    const float* __restrict__ bias,
    unsigned short* __restrict__ C, int ldc, int Mclamp)
{
  __shared__ unsigned short As[128 * 40];
  __shared__ unsigned short Bs[128 * 40];
  int n0 = blockIdx.x * 128, m0 = blockIdx.y * 128;
  int t = threadIdx.x, wv = t >> 6, lane = t & 63;
  int fr = lane & 15, kg = lane >> 4;
  int wr = wv >> 1, wc = wv & 1;
  int sr = t >> 1, sc = (t & 1) * 16;

  f32x4 acc[4][4];
#pragma unroll
  for (int mi = 0; mi < 4; ++mi)
#pragma unroll
    for (int ni = 0; ni < 4; ++ni) acc[mi][ni] = (f32x4){0.f, 0.f, 0.f, 0.f};

  int arow = m0 + sr; if (arow >= Mclamp) arow = Mclamp - 1;
  const unsigned short* ga = &A[(size_t)arow * lda + sc];
  const unsigned short* gw = &W[(size_t)(n0 + sr) * K + sc];

  for (int k0 = 0; k0 < K; k0 += 32) {
    ushort8v a0 = *(const ushort8v*)(ga + k0);
    ushort8v a1 = *(const ushort8v*)(ga + k0 + 8);
    ushort8v b0 = *(const ushort8v*)(gw + k0);
    ushort8v b1 = *(const ushort8v*)(gw + k0 + 8);
    __syncthreads();
    *(ushort8v*)&As[sr * 40 + sc]     = a0;
    *(ushort8v*)&As[sr * 40 + sc + 8] = a1;
    *(ushort8v*)&Bs[sr * 40 + sc]     = b0;
    *(ushort8v*)&Bs[sr * 40 + sc + 8] = b1;
    __syncthreads();
    short8v af[4], bfv[4];
#pragma unroll
    for (int mi = 0; mi < 4; ++mi)
      af[mi] = *(const short8v*)&As[(wr * 64 + mi * 16 + fr) * 40 + kg * 8];
#pragma unroll
    for (int ni = 0; ni < 4; ++ni)
      bfv[ni] = *(const short8v*)&Bs[(wc * 64 + ni * 16 + fr) * 40 + kg * 8];
#pragma unroll
    for (int mi = 0; mi < 4; ++mi)
#pragma unroll
      for (int ni = 0; ni < 4; ++ni)
        acc[mi][ni] = __builtin_amdgcn_mfma_f32_16x16x32_bf16(af[mi], bfv[ni], acc[mi][ni], 0, 0, 0);
  }

#pragma unroll
  for (int ni = 0; ni < 4; ++ni) {
    int col = n0 + wc * 64 + ni * 16 + fr;
    float bb = bias[col];
#pragma unroll
    for (int mi = 0; mi < 4; ++mi) {
#pragma unroll
      for (int r = 0; r < 4; ++r) {
        int row = m0 + wr * 64 + mi * 16 + kg * 4 + r;
        float v = acc[mi][ni][r] + bb;
        if (RELU) v = fmaxf(v, 0.f);
        C[(size_t)row * ldc + col] = f2bf(v);
      }
    }
  }
}

// ---------------- fused item attention v5 (unchanged from R15) --------------
__global__ __launch_bounds__(256) void k_item_fused(
    const int* __restrict__ oh,
    const unsigned short* __restrict__ QKVall /*[VPAD][256] bf16*/,
    const float* __restrict__ wo /*[64][64] f32*/, const float* __restrict__ bob,
    unsigned short* __restrict__ X /*[B*O][64] bf16*/)
{
  __shared__ __align__(16) unsigned short QKs[2][20][144];
  __shared__ __align__(16) unsigned short VTs[2][64][36];
  __shared__ __align__(16) unsigned short Ps[4][24][36];   // staging: aliased as Vs[2][20][72]
  __shared__ __align__(16) float mAs[2][68];
  __shared__ int ids[2][20];

  int t = threadIdx.x, wv = t >> 6, lane = t & 63;
  int fr = lane & 15, lg = lane >> 4;
  int pr = wv >> 1, half = wv & 1;
  unsigned short (*Vs)[20][72] = (unsigned short (*)[20][72])&Ps[0][0][0];

  if (t < 40) ids[t / 20][t % 20] = oh[(size_t)(blockIdx.x * 2 + t / 20) * 20 + (t % 20)];
  {
    unsigned int* vz = (unsigned int*)&VTs[t >> 7][(t >> 1) & 63][20 + (t & 1) * 8];
    vz[0] = 0; vz[1] = 0; vz[2] = 0; vz[3] = 0;
  }
  __syncthreads();

  for (int e = t; e < 640; e += 256) {
    int pp = e / 320, rem = e - pp * 320;
    int row = rem >> 4, ch = (rem & 15) * 8;
    const unsigned short* src = QKVall + (size_t)ids[pp][row] * 256 + ch;
    *(ushort8v*)&QKs[pp][row][ch] = *(const ushort8v*)src;
  }
  for (int e = t; e < 320; e += 256) {
    int pp = e / 160, rem = e - pp * 160;
    int row = rem >> 3, ch = (rem & 7) * 8;
    const unsigned short* src = QKVall + (size_t)ids[pp][row] * 256 + 128 + ch;
    *(ushort8v*)&Vs[pp][row][ch] = *(const ushort8v*)src;
  }
  __syncthreads();

  for (int e = t; e < 640; e += 256) {
    int pp = e / 320, rem = e - pp * 320;
    int jp = rem >> 5, c0 = (rem & 31) * 2;
    unsigned int a = *(const unsigned int*)&Vs[pp][2 * jp][c0];
    unsigned int b = *(const unsigned int*)&Vs[pp][2 * jp + 1][c0];
    *(unsigned int*)&VTs[pp][c0][2 * jp]     = (a & 0xFFFFu) | (b << 16);
    *(unsigned int*)&VTs[pp][c0 + 1][2 * jp] = (a >> 16) | (b & 0xFFFF0000u);
  }
  __syncthreads();

  for (int e = lane; e < 72; e += 64) {
    int row = 20 + e / 18, col = (e - (e / 18) * 18) * 2;
    *(unsigned int*)&Ps[wv][row][col] = 0;
  }

  int rj1 = (fr + 16 < 20) ? fr + 16 : 19;
  bool iv1 = fr < 4;
  int pr1 = iv1 ? 16 + fr : 20;
#pragma unroll
  for (int hi = 0; hi < 2; ++hi) {
    int h = half * 2 + hi;
    short8v aK0, aK1, bQ0, bQ1;
    {
      short8v z = {0,0,0,0,0,0,0,0};
      aK0 = z; aK1 = z; bQ0 = z; bQ1 = z;
    }
    if (lg < 2) {
      aK0 = *(const short8v*)&QKs[pr][fr][64 + h * 16 + lg * 8];
      aK1 = *(const short8v*)&QKs[pr][rj1][64 + h * 16 + lg * 8];
      bQ0 = *(const short8v*)&QKs[pr][fr][h * 16 + lg * 8];
      bQ1 = *(const short8v*)&QKs[pr][rj1][h * 16 + lg * 8];
    }
    f32x4 s00 = {0.f,0.f,0.f,0.f}, s01 = {0.f,0.f,0.f,0.f};
    f32x4 s10 = {0.f,0.f,0.f,0.f}, s11 = {0.f,0.f,0.f,0.f};
    s00 = __builtin_amdgcn_mfma_f32_16x16x32_bf16(aK0, bQ0, s00, 0, 0, 0);
    s01 = __builtin_amdgcn_mfma_f32_16x16x32_bf16(aK0, bQ1, s01, 0, 0, 0);
    s10 = __builtin_amdgcn_mfma_f32_16x16x32_bf16(aK1, bQ0, s10, 0, 0, 0);
    s11 = __builtin_amdgcn_mfma_f32_16x16x32_bf16(aK1, bQ1, s11, 0, 0, 0);

    float e00[4], e01[4], e10[4], e11[4];
    float d0 = 0.f, d1 = 0.f;
#pragma unroll
    for (int r = 0; r < 4; ++r) {
      int j1 = 16 + lg * 4 + r;
      bool jv1 = j1 < 20;
      float v00 = __expf(0.25f * s00[r]);
      float v01 = iv1 ? __expf(0.25f * s01[r]) : 0.f;
      float v10 = jv1 ? __expf(0.25f * s10[r]) : 0.f;
      float v11 = (jv1 && iv1) ? __expf(0.25f * s11[r]) : 0.f;
      e00[r] = v00; e01[r] = v01; e10[r] = v10; e11[r] = v11;
      d0 += v00 + v10; d1 += v01 + v11;
    }
    d0 += __shfl_xor(d0, 16, 64); d0 += __shfl_xor(d0, 32, 64);
    d1 += __shfl_xor(d1, 16, 64); d1 += __shfl_xor(d1, 32, 64);
    float inv0 = __fdividef(1.f, d0);
    float inv1 = iv1 ? __fdividef(1.f, d1) : 0.f;

    *(unsigned int*)&Ps[wv][fr][lg * 4]          = pk2bf(e00[0]*inv0, e00[1]*inv0);
    *(unsigned int*)&Ps[wv][fr][lg * 4 + 2]      = pk2bf(e00[2]*inv0, e00[3]*inv0);
    *(unsigned int*)&Ps[wv][fr][16 + lg * 4]     = pk2bf(e10[0]*inv0, e10[1]*inv0);
    *(unsigned int*)&Ps[wv][fr][16 + lg * 4 + 2] = pk2bf(e10[2]*inv0, e10[3]*inv0);
    if (iv1) {
      *(unsigned int*)&Ps[wv][16 + fr][lg * 4]          = pk2bf(e01[0]*inv1, e01[1]*inv1);
      *(unsigned int*)&Ps[wv][16 + fr][lg * 4 + 2]      = pk2bf(e01[2]*inv1, e01[3]*inv1);
      *(unsigned int*)&Ps[wv][16 + fr][16 + lg * 4]     = pk2bf(e11[0]*inv1, e11[1]*inv1);
      *(unsigned int*)&Ps[wv][16 + fr][16 + lg * 4 + 2] = pk2bf(e11[2]*inv1, e11[3]*inv1);
    }

    short8v pa0, pa1, bV;
    {
      short4v l0 = *(const short4v*)&Ps[wv][fr][lg * 8];
      short4v h0 = *(const short4v*)&Ps[wv][fr][lg * 8 + 4];
      short4v l1 = *(const short4v*)&Ps[wv][pr1][lg * 8];
      short4v h1 = *(const short4v*)&Ps[wv][pr1][lg * 8 + 4];
      short4v lv = *(const short4v*)&VTs[pr][h * 16 + fr][lg * 8];
      short4v hv = *(const short4v*)&VTs[pr][h * 16 + fr][lg * 8 + 4];
      pa0[0]=l0[0]; pa0[1]=l0[1]; pa0[2]=l0[2]; pa0[3]=l0[3];
      pa0[4]=h0[0]; pa0[5]=h0[1]; pa0[6]=h0[2]; pa0[7]=h0[3];
      pa1[0]=l1[0]; pa1[1]=l1[1]; pa1[2]=l1[2]; pa1[3]=l1[3];
      pa1[4]=h1[0]; pa1[5]=h1[1]; pa1[6]=h1[2]; pa1[7]=h1[3];
      bV[0]=lv[0]; bV[1]=lv[1]; bV[2]=lv[2]; bV[3]=lv[3];
      bV[4]=hv[0]; bV[5]=hv[1]; bV[6]=hv[2]; bV[7]=hv[3];
    }
    f32x4 m20 = {0.f,0.f,0.f,0.f}, m21 = {0.f,0.f,0.f,0.f};
    m20 = __builtin_amdgcn_mfma_f32_16x16x32_bf16(pa0, bV, m20, 0, 0, 0);
    m21 = __builtin_amdgcn_mfma_f32_16x16x32_bf16(pa1, bV, m21, 0, 0, 0);

    float sm = m20[0] + m20[1] + m20[2] + m20[3];
    if (lg == 0) sm += m21[0] + m21[1] + m21[2] + m21[3];
    sm += __shfl_xor(sm, 16, 64);
    sm += __shfl_xor(sm, 32, 64);
    if (lg == 0) mAs[pr][h * 16 + fr] = sm * 0.05f;
  }
  __syncthreads();

  if (t < 128) {
    int p2 = t >> 6, col = t & 63;
    float acc = bob[col];
    const float* wrow = &wo[(size_t)col * 64];
    for (int k = 0; k < 64; k += 4) {
      float4 m4 = *(const float4*)&mAs[p2][k];
      float4 w4 = *(const float4*)(wrow + k);
      acc += m4.x * w4.x + m4.y * w4.y + m4.z * w4.z + m4.w * w4.w;
    }
    X[(size_t)(blockIdx.x * 2 + p2) * 64 + col] = f2bf(acc);
  }
}

// ---------------- GRU recurrence (bf16 G output, full batch) ----------------
__global__ __launch_bounds__(512) void k_gru_mfma(
    const unsigned short* __restrict__ GI,   // [B*O][768]: 0-383 fwd, 384-767 bwd
    const unsigned short* __restrict__ whf,
    const unsigned short* __restrict__ whb,
    const float* __restrict__ bh_f, const float* __restrict__ bh_b,
    unsigned short* __restrict__ G /*[B*O][256] bf16*/)
{
  __shared__ unsigned short hsb[16][136];
  __shared__ float ah[4][392];

  int bid = blockIdx.x;
  int dir = bid >> 8;            // 256 row-groups per dir
  int rg  = bid & 255;
  const unsigned short* wh = dir ? whb : whf;
  const float* bh = dir ? bh_b : bh_f;

  int t = threadIdx.x;
  int w = t >> 6, lane = t & 63;
  int fr = lane & 15, kg = lane >> 4;

  short8v bfr[3][4];
#pragma unroll
  for (int n = 0; n < 3; ++n)
#pragma unroll
    for (int kf = 0; kf < 4; ++kf)
      bfr[n][kf] = *(const short8v*)&wh[(size_t)(w * 48 + n * 16 + fr) * 128 + kf * 32 + kg * 8];

  for (int e = t; e < 16 * 136; e += 512) ((unsigned short*)hsb)[e] = 0;

  int grow = t >> 7, gc = t & 127;
  float bh0 = bh[gc], bh1 = bh[128 + gc], bh2 = bh[256 + gc];
  float hold = 0.f;
  const unsigned short* gip = &GI[(size_t)(rg * 4 + grow) * 50 * 768 + dir * 384];
  unsigned short* gout = &G[((size_t)(rg * 4 + grow) * 50) * 256 + dir * 128 + gc];

  __syncthreads();

  int o0 = dir ? 49 : 0;
  unsigned short c0v = gip[(size_t)o0 * 768 + gc];
  unsigned short c1v = gip[(size_t)o0 * 768 + 128 + gc];
  unsigned short c2v = gip[(size_t)o0 * 768 + 256 + gc];

  for (int s = 0; s < 50; ++s) {
    int o  = dir ? 49 - s : s;
    unsigned short n0v = 0, n1v = 0, n2v = 0;
    if (s < 49) {
      int on = dir ? 48 - s : s + 1;
      n0v = gip[(size_t)on * 768 + gc];
      n1v = gip[(size_t)on * 768 + 128 + gc];
      n2v = gip[(size_t)on * 768 + 256 + gc];
    }

    short8v a0 = *(const short8v*)&hsb[fr][0 * 32 + kg * 8];
    short8v a1 = *(const short8v*)&hsb[fr][1 * 32 + kg * 8];
    short8v a2 = *(const short8v*)&hsb[fr][2 * 32 + kg * 8];
    short8v a3 = *(const short8v*)&hsb[fr][3 * 32 + kg * 8];

    f32x4 acc0 = {0.f,0.f,0.f,0.f}, acc1 = {0.f,0.f,0.f,0.f}, acc2 = {0.f,0.f,0.f,0.f};
    acc0 = __builtin_amdgcn_mfma_f32_16x16x32_bf16(a0, bfr[0][0], acc0, 0, 0, 0);
    acc1 = __builtin_amdgcn_mfma_f32_16x16x32_bf16(a0, bfr[1][0], acc1, 0, 0, 0);
    acc2 = __builtin_amdgcn_mfma_f32_16x16x32_bf16(a0, bfr[2][0], acc2, 0, 0, 0);
    acc0 = __builtin_amdgcn_mfma_f32_16x16x32_bf16(a1, bfr[0][1], acc0, 0, 0, 0);
    acc1 = __builtin_amdgcn_mfma_f32_16x16x32_bf16(a1, bfr[1][1], acc1, 0, 0, 0);
    acc2 = __builtin_amdgcn_mfma_f32_16x16x32_bf16(a1, bfr[2][1], acc2, 0, 0, 0);
    acc0 = __builtin_amdgcn_mfma_f32_16x16x32_bf16(a2, bfr[0][2], acc0, 0, 0, 0);
    acc1 = __builtin_amdgcn_mfma_f32_16x16x32_bf16(a2, bfr[1][2], acc1, 0, 0, 0);
    acc2 = __builtin_amdgcn_mfma_f32_16x16x32_bf16(a2, bfr[2][2], acc2, 0, 0, 0);
    acc0 = __builtin_amdgcn_mfma_f32_16x16x32_bf16(a3, bfr[0][3], acc0, 0, 0, 0);
    acc1 = __builtin_amdgcn_mfma_f32_16x16x32_bf16(a3, bfr[1][3], acc1, 0, 0, 0);
    acc2 = __builtin_amdgcn_mfma_f32_16x16x32_bf16(a3, bfr[2][3], acc2, 0, 0, 0);

    if (kg == 0) {
#pragma unroll
      for (int r = 0; r < 4; ++r) {
        ah[r][w * 48 + 0 * 16 + fr] = acc0[r];
        ah[r][w * 48 + 1 * 16 + fr] = acc1[r];
        ah[r][w * 48 + 2 * 16 + fr] = acc2[r];
      }
    }
    __syncthreads();

    float ai0 = bf2f(c0v), ai1 = bf2f(c1v), ai2 = bf2f(c2v);
    float ah0 = ah[grow][gc] + bh0;
    float ah1 = ah[grow][128 + gc] + bh1;
    float ah2 = ah[grow][256 + gc] + bh2;
    float rr = sig_(ai0 + ah0);
    float zz = sig_(ai1 + ah1);
    float nn = tanh_(ai2 + rr * ah2);
    float h2 = (1.f - zz) * nn + zz * hold;
    hold = h2;
    unsigned short hb = f2bf(h2);
    hsb[grow][gc] = hb;
    gout[(size_t)o * 256] = hb;
    c0v = n0v; c1v = n1v; c2v = n2v;
    __syncthreads();
  }
}

// ---------------- transformer attention core v2: MFMA QK^T + MFMA PV --------
// one block per (b,head); 4 waves, wave = i-tile of 16 query rows. Q,K rows
// 50..63 zeroed; V^T pre-zeroed (j-pad). P bf16 [i][j], invalid j = 0.
// Max-subtracting softmax (transformer scores not bounded-tiny).
__global__ __launch_bounds__(256) void k_attn_core(unsigned short* __restrict__ BIG)
{
  __shared__ __align__(16) unsigned short Qs[64][72];
  __shared__ __align__(16) unsigned short Ks[64][72];
  __shared__ __align__(16) unsigned short VTs[64][72];   // [d][j]
  __shared__ __align__(16) unsigned short Ps[4][16][72]; // per-wave P[i][j]
  unsigned short (*Vs)[64] = (unsigned short (*)[64])&Ps[0][0][0];  // [50][64] alias

  int bl = blockIdx.x >> 2, h = blockIdx.x & 3;
  int t = threadIdx.x, wv = t >> 6, lane = t & 63;
  int fr = lane & 15, lg = lane >> 4;
  size_t base = (size_t)bl * 50 * 768;
  int hc = h * 64;

  // zero pads: Qs/Ks rows 50..63 (504 dw each), VTs fully (2304 dw)
  for (int e = t; e < 504; e += 256) {
    int r = e / 36, c = (e - r * 36) * 2;
    *(unsigned int*)&Qs[50 + r][c] = 0;
    *(unsigned int*)&Ks[50 + r][c] = 0;
  }
  for (int e = t; e < 2304; e += 256) {
    int r = e / 36, c = (e - r * 36) * 2;
    *(unsigned int*)&VTs[r][c] = 0;
  }
  __syncthreads();   // (Vs aliases Ps; ensure zero-writes ordered before staging)

  // stage Q, K, V-natural (b128): 3 x 50 rows x 8 chunks
  for (int e = t; e < 400; e += 256) {
    int row = e >> 3, ch = (e & 7) * 8;
    *(ushort8v*)&Qs[row][ch] = *(const ushort8v*)&BIG[base + (size_t)row * 768 + hc + ch];
  }
  for (int e = t; e < 400; e += 256) {
    int row = e >> 3, ch = (e & 7) * 8;
    *(ushort8v*)&Ks[row][ch] = *(const ushort8v*)&BIG[base + (size_t)row * 768 + 256 + hc + ch];
  }
  for (int e = t; e < 400; e += 256) {
    int row = e >> 3, ch = (e & 7) * 8;
    *(ushort8v*)&Vs[row][ch] = *(const ushort8v*)&BIG[base + (size_t)row * 768 + 512 + hc + ch];
  }
  __syncthreads();

  // transpose V -> VTs[d][j]: 25 j-pairs x 32 col-pairs = 800 jobs
  for (int e = t; e < 800; e += 256) {
    int jp = e >> 5, c0 = (e & 31) * 2;
    unsigned int a = *(const unsigned int*)&Vs[2 * jp][c0];
    unsigned int b = *(const unsigned int*)&Vs[2 * jp + 1][c0];
    *(unsigned int*)&VTs[c0][2 * jp]     = (a & 0xFFFFu) | (b << 16);
    *(unsigned int*)&VTs[c0 + 1][2 * jp] = (a >> 16) | (b & 0xFFFF0000u);
  }
  __syncthreads();   // Vs (alias Ps) fully consumed; Ps writes below are safe

  // ---- this wave's i-tile: S^T = K·Q^T (8 MFMA), softmax, PV (8 MFMA) ----
  int i0 = wv * 16;
  short8v bQ0 = *(const short8v*)&Qs[i0 + fr][lg * 8];
  short8v bQ1 = *(const short8v*)&Qs[i0 + fr][32 + lg * 8];

  f32x4 s[4];
#pragma unroll
  for (int jt = 0; jt < 4; ++jt) {
    short8v aK0 = *(const short8v*)&Ks[jt * 16 + fr][lg * 8];
    short8v aK1 = *(const short8v*)&Ks[jt * 16 + fr][32 + lg * 8];
    f32x4 acc = {0.f, 0.f, 0.f, 0.f};
    acc = __builtin_amdgcn_mfma_f32_16x16x32_bf16(aK0, bQ0, acc, 0, 0, 0);
    acc = __builtin_amdgcn_mfma_f32_16x16x32_bf16(aK1, bQ1, acc, 0, 0, 0);
    s[jt] = acc;
  }

  // per-col (i) max over valid j, then exp/denominator
  float m = -1e30f;
#pragma unroll
  for (int jt = 0; jt < 4; ++jt)
#pragma unroll
    for (int r = 0; r < 4; ++r) {
      int j = jt * 16 + lg * 4 + r;
      float v = s[jt][r] * 0.125f;
      if (j < 50) m = fmaxf(m, v);
    }
  m = fmaxf(m, __shfl_xor(m, 16, 64));
  m = fmaxf(m, __shfl_xor(m, 32, 64));

  float ev[4][4];
  float den = 0.f;
#pragma unroll
  for (int jt = 0; jt < 4; ++jt)
#pragma unroll
    for (int r = 0; r < 4; ++r) {
      int j = jt * 16 + lg * 4 + r;
      float e = (j < 50) ? __expf(s[jt][r] * 0.125f - m) : 0.f;
      ev[jt][r] = e;
      den += e;
    }
  den += __shfl_xor(den, 16, 64);
  den += __shfl_xor(den, 32, 64);
  float inv = __fdividef(1.f, den);

  // write P[i][j] bf16 (8 packed dwords; all j 0..63 covered, invalid = 0)
#pragma unroll
  for (int jt = 0; jt < 4; ++jt) {
    *(unsigned int*)&Ps[wv][fr][jt * 16 + lg * 4]     = pk2bf(ev[jt][0] * inv, ev[jt][1] * inv);
    *(unsigned int*)&Ps[wv][fr][jt * 16 + lg * 4 + 2] = pk2bf(ev[jt][2] * inv, ev[jt][3] * inv);
  }

  // PV: O[i][d] = P·V^T ; A = P rows i, B = V^T cols d, k = j
  short8v pa0 = *(const short8v*)&Ps[wv][fr][lg * 8];
  short8v pa1 = *(const short8v*)&Ps[wv][fr][32 + lg * 8];
#pragma unroll
  for (int dt = 0; dt < 4; ++dt) {
    short8v bV0 = *(const short8v*)&VTs[dt * 16 + fr][lg * 8];
    short8v bV1 = *(const short8v*)&VTs[dt * 16 + fr][32 + lg * 8];
    f32x4 o = {0.f, 0.f, 0.f, 0.f};
    o = __builtin_amdgcn_mfma_f32_16x16x32_bf16(pa0, bV0, o, 0, 0, 0);
    o = __builtin_amdgcn_mfma_f32_16x16x32_bf16(pa1, bV1, o, 0, 0, 0);
#pragma unroll
    for (int r = 0; r < 4; ++r) {
      int i = i0 + lg * 4 + r;
      if (i < 50)
        BIG[base + (size_t)i * 768 + hc + dt * 16 + fr] = f2bf(o[r]);
    }
  }
}

// ---------------- fused residual + LayerNorm (bf16 I/O, wave per row) -------
__global__ __launch_bounds__(256) void k_ln_res(
    const unsigned short* __restrict__ res, const unsigned short* __restrict__ add,
    int addld, unsigned short* __restrict__ dst,
    const float* __restrict__ g, const float* __restrict__ bt)
{
  int row = blockIdx.x * 4 + (threadIdx.x >> 6);
  int lane = threadIdx.x & 63;
  int c = lane * 4;
  ushort4v rv = *(const ushort4v*)&res[(size_t)row * 256 + c];
  ushort4v av = *(const ushort4v*)&add[(size_t)row * addld + c];
  float x0 = bf2f(rv[0]) + bf2f(av[0]);
  float x1 = bf2f(rv[1]) + bf2f(av[1]);
  float x2 = bf2f(rv[2]) + bf2f(av[2]);
  float x3 = bf2f(rv[3]) + bf2f(av[3]);
  float s = x0 + x1 + x2 + x3;
  float sq = x0 * x0 + x1 * x1 + x2 * x2 + x3 * x3;
#pragma unroll
  for (int d = 1; d < 64; d <<= 1) { s += __shfl_xor(s, d, 64); sq += __shfl_xor(sq, d, 64); }
  float m = s * (1.f / 256.f);
  float var = sq * (1.f / 256.f) - m * m;
  float rs = rsqrtf(var + 1e-5f);
  float4 gv = *(const float4*)&g[c];
  float4 bv = *(const float4*)&bt[c];
  ushort4v ov;
  ov[0] = f2bf((x0 - m) * rs * gv.x + bv.x);
  ov[1] = f2bf((x1 - m) * rs * gv.y + bv.y);
  ov[2] = f2bf((x2 - m) * rs * gv.z + bv.z);
  ov[3] = f2bf((x3 - m) * rs * gv.w + bv.w);
  *(ushort4v*)&dst[(size_t)row * 256 + c] = ov;
}

// ---------------- temporal encoder + O-mean + final classifier (fused) ------
__global__ __launch_bounds__(256) void k_heads(
    const unsigned short* __restrict__ H2 /*[B*O][256] bf16*/,
    const float* __restrict__ daysb, const float* __restrict__ dayss,
    const float* __restrict__ te1_w, const float* __restrict__ te1_b,
    const float* __restrict__ ln1g, const float* __restrict__ ln1b,
    const float* __restrict__ te2_w, const float* __restrict__ te2_b,
    const float* __restrict__ ln2g, const float* __restrict__ ln2b,
    const float* __restrict__ cWT /*[320][128]*/,
    const float* __restrict__ c_b, const float* __restrict__ clng,
    const float* __restrict__ clnb, float* __restrict__ out)
{
  __shared__ float oe[256];
  __shared__ float feat[2];
  __shared__ float s1[32], s2[64], pre[128], stat[2];
  int b = blockIdx.x, t = threadIdx.x;
  {
    float s = 0.f;
    for (int o = 0; o < 50; ++o) s += bf2f(H2[((size_t)b * 50 + o) * 256 + t]);
    oe[t] = s * 0.02f;
  }
  if (t == 0) {
    float f0 = 0.f;
    for (int i = 0; i < 10; ++i) f0 += daysb[b * 10 + i];
    feat[0] = f0 * 0.1f;
    feat[1] = dayss[b];
  }
  __syncthreads();
  if (t < 32) s1[t] = te1_b[t] + feat[0] * te1_w[2 * t] + feat[1] * te1_w[2 * t + 1];
  __syncthreads();
  if (t == 0) {
    float s = 0.f; for (int j = 0; j < 32; ++j) s += s1[j];
    float m = s * (1.f / 32.f);
    float v = 0.f; for (int j = 0; j < 32; ++j) { float d = s1[j] - m; v += d * d; }
    stat[0] = m; stat[1] = rsqrtf(v * (1.f / 32.f) + 1e-5f);
  }
  __syncthreads();
  if (t < 32) s1[t] = fmaxf((s1[t] - stat[0]) * stat[1] * ln1g[t] + ln1b[t], 0.f);
  __syncthreads();
  if (t < 64) {
    float a = te2_b[t];
    for (int k = 0; k < 32; ++k) a += s1[k] * te2_w[t * 32 + k];
    s2[t] = a;
  }
  __syncthreads();
  if (t == 0) {
    float s = 0.f; for (int j = 0; j < 64; ++j) s += s2[j];
    float m = s * (1.f / 64.f);
    float v = 0.f; for (int j = 0; j < 64; ++j) { float d = s2[j] - m; v += d * d; }
    stat[0] = m; stat[1] = rsqrtf(v * (1.f / 64.f) + 1e-5f);
  }
  __syncthreads();
  if (t < 64) s2[t] = fmaxf((s2[t] - stat[0]) * stat[1] * ln2g[t] + ln2b[t], 0.f);
  __syncthreads();
  if (t < 128) {
    float p = c_b[t];
    for (int k = 0; k < 256; ++k) p += oe[k] * cWT[k * 128 + t];
    for (int k = 0; k < 64; ++k)  p += s2[k] * cWT[(256 + k) * 128 + t];
    pre[t] = p;
  }
  __syncthreads();
  if (t == 0) {
    float s = 0.f; for (int j = 0; j < 128; ++j) s += pre[j];
    float m = s * (1.f / 128.f);
    float v = 0.f; for (int j = 0; j < 128; ++j) { float d = pre[j] - m; v += d * d; }
    stat[0] = m; stat[1] = rsqrtf(v * (1.f / 128.f) + 1e-5f);
  }
  __syncthreads();
  if (t < 128)
    out[(size_t)b * 128 + t] = fmaxf((pre[t] - stat[0]) * stat[1] * clng[t] + clnb[t], 0.f);
}

// ---------------- host launcher ----------------
extern "C" void kernel_launch(void* const* d_in, const int* in_sizes, int n_in,
                              void* d_out, int out_size, void* d_ws, size_t ws_size,
                              hipStream_t stream)
{
  const int*   oh       = (const int*)d_in[0];
  const float* daysb    = (const float*)d_in[1];
  const float* dayss    = (const float*)d_in[2];
  const float* emb      = (const float*)d_in[3];
  const float* ia_in_w  = (const float*)d_in[4];
  const float* ia_in_b  = (const float*)d_in[5];
  const float* ia_out_w = (const float*)d_in[6];
  const float* ia_out_b = (const float*)d_in[7];
  const float* gf_wi = (const float*)d_in[8];
  const float* gf_wh = (const float*)d_in[9];
  const float* gf_bi = (const float*)d_in[10];
  const float* gf_bh = (const float*)d_in[11];
  const float* gb_wi = (const float*)d_in[12];
  const float* gb_wh = (const float*)d_in[13];
  const float* gb_bi = (const float*)d_in[14];
  const float* gb_bh = (const float*)d_in[15];
  const float* ta_in_w  = (const float*)d_in[16];
  const float* ta_in_b  = (const float*)d_in[17];
  const float* ta_out_w = (const float*)d_in[18];
  const float* ta_out_b = (const float*)d_in[19];
  const float* t_ln1_g = (const float*)d_in[20];
  const float* t_ln1_b = (const float*)d_in[21];
  const float* t_ln2_g = (const float*)d_in[22];
  const float* t_ln2_b = (const float*)d_in[23];
  const float* t_ff1_w = (const float*)d_in[24];
  const float* t_ff1_b = (const float*)d_in[25];
  const float* t_ff2_w = (const float*)d_in[26];
  const float* t_ff2_b = (const float*)d_in[27];
  const float* te1_w = (const float*)d_in[28];
  const float* te1_b = (const float*)d_in[29];
  const float* te_ln1_g = (const float*)d_in[30];
  const float* te_ln1_b = (const float*)d_in[31];
  const float* te2_w = (const float*)d_in[32];
  const float* te2_b = (const float*)d_in[33];
  const float* te_ln2_g = (const float*)d_in[34];
  const float* te_ln2_b = (const float*)d_in[35];
  const float* c_w   = (const float*)d_in[36];
  const float* c_b   = (const float*)d_in[37];
  const float* c_ln_g = (const float*)d_in[38];
  const float* c_ln_b = (const float*)d_in[39];

  float* ws = (float*)d_ws;
  // layout (floats):
  const size_t OFF_GB   = 0;                        // G bf16 [51200][256] = 6,553,600 fl
  const size_t OFF_X    = 6553600;                  // X bf16 [51200][64]  = 1,638,400 fl
  const size_t OFF_S    = OFF_X + 1638400;          // QKVall | GI | BIGb  = 19,660,800 fl
  const size_t OW_C     = OFF_S + 19660800;         // [320][128] 40,960
  const size_t OW_BC    = OW_C + 40960;             // 768
  const size_t OW_BQ    = OW_BC + 768;              // padded qkv bias 256
  const size_t OW_BF    = OW_BQ + 256;              // bf16 weight pool 344,064 fl
  const size_t OW_EMB   = OW_BF + 344064;           // bf16 emb table 1,590,048 fl
  const size_t TOTAL    = OW_EMB + 1590048;         // 29,828,896 fl = 119.3 MB
  if (ws_size < TOTAL * sizeof(float)) return;

  unsigned short* Gb = (unsigned short*)(ws + OFF_GB);
  unsigned short* Xb = (unsigned short*)(ws + OFF_X);
  float* w_c  = ws + OW_C;
  float* biascat = ws + OW_BC;
  float* biasq   = ws + OW_BQ;
  unsigned short* bfp = (unsigned short*)(ws + OW_BF);
  unsigned short* b_ta_in  = bfp;                  // 196,608
  unsigned short* b_ta_out = b_ta_in + 196608;     //  65,536
  unsigned short* b_ff1    = b_ta_out + 65536;     // 131,072
  unsigned short* b_ff2    = b_ff1 + 131072;       // 131,072
  unsigned short* b_qkvw   = b_ff2 + 131072;       //  16,384 (padded [256][64])
  unsigned short* b_wi_f   = b_qkvw + 16384;       //  24,576 ── Wcat [768][64]
  unsigned short* b_wi_b   = b_wi_f + 24576;       //  24,576 ──┘
  unsigned short* b_wh_f   = b_wi_b + 24576;       //  49,152
  unsigned short* b_wh_b   = b_wh_f + 49152;       //  49,152
  unsigned short* embb = (unsigned short*)(ws + OW_EMB);  // [(V+1)][64] bf16

  // scratch phase views (aliased; QKVall dead before GI is written):
  unsigned short* QKVall = (unsigned short*)(ws + OFF_S); // [VPAD][256] bf16 (25.5MB)
  unsigned short* GI     = (unsigned short*)(ws + OFF_S); // gru: [51200][768] bf16
  unsigned short* BIGb   = (unsigned short*)(ws + OFF_S); // transformer: [51200][768]

  // ---- prologue: 2 launches ----
  k_prep_small<<<(40960 + 768 + 256 + 4096 + 255) / 256, 256, 0, stream>>>(
      c_w, w_c, gf_bi, gb_bi, biascat, ia_in_b, biasq, b_qkvw + 12288);
  {
    CvArgs a;
    a.src[0] = ta_in_w;  a.dst[0] = b_ta_in;  a.n[0] = 196608;
    a.src[1] = ta_out_w; a.dst[1] = b_ta_out; a.n[1] = 65536;
    a.src[2] = t_ff1_w;  a.dst[2] = b_ff1;    a.n[2] = 131072;
    a.src[3] = t_ff2_w;  a.dst[3] = b_ff2;    a.n[3] = 131072;
    a.src[4] = ia_in_w;  a.dst[4] = b_qkvw;   a.n[4] = 12288;
    a.src[5] = gf_wi;    a.dst[5] = b_wi_f;   a.n[5] = 24576;
    a.src[6] = gb_wi;    a.dst[6] = b_wi_b;   a.n[6] = 24576;
    a.src[7] = gf_wh;    a.dst[7] = b_wh_f;   a.n[7] = 49152;
    a.src[8] = gb_wh;    a.dst[8] = b_wh_b;   a.n[8] = 49152;
    a.src[9] = emb;      a.dst[9] = embb;     a.n[9] = 3180096;
    int total = 196608 + 65536 + 131072 + 131072 + 12288 + 24576 + 24576 + 49152 + 49152 + 3180096;
    k_cv_multi<<<(total + 255) / 256, 256, 0, stream>>>(a);
  }

  // ---- precompute QKVall = embb @ Wqkv^T + b (vocab-wide, once) ----
  k_gemm128<0><<<dim3(256 / 128, VPAD / 128), 256, 0, stream>>>(
      embb, 64, b_qkvw, 64, biasq, QKVall, 256, VROWS);

  // ---- item attention: gather + attend (2 pairs/block) ----
  k_item_fused<<<B_ * O_ / 2, 256, 0, stream>>>(oh, QKVall, ia_out_w, ia_out_b, Xb);

  // ---- bidirectional GRU: single chunk over full batch ----
  k_gemm128<0><<<dim3(768 / 128, 51200 / 128), 256, 0, stream>>>(
      Xb, 64, b_wi_f /*Wcat [768][64]*/, 64, biascat, GI, 768, 51200);
  k_gru_mfma<<<512, 512, 0, stream>>>(GI, b_wh_f, b_wh_b, gf_bh, gb_bh, Gb);

  // ---- transformer layer: single chunk, bf16, in-place in BIGb ----
  k_gemm128<0><<<dim3(768 / 128, 51200 / 128), 256, 0, stream>>>(
      Gb, 256, b_ta_in, 256, ta_in_b, BIGb, 768, 51200);
  k_attn_core<<<B_ * 4, 256, 0, stream>>>(BIGb);
  k_gemm128<0><<<dim3(256 / 128, 51200 / 128), 256, 0, stream>>>(
      BIGb, 768, b_ta_out, 256, ta_out_b, BIGb + 256, 768, 51200);
  k_ln_res<<<51200 / 4, 256, 0, stream>>>(Gb, BIGb + 256, 768, Gb, t_ln1_g, t_ln1_b);
  k_gemm128<1><<<dim3(512 / 128, 51200 / 128), 256, 0, stream>>>(
      Gb, 256, b_ff1, 256, t_ff1_b, BIGb, 768, 51200);
  k_gemm128<0><<<dim3(256 / 128, 51200 / 128), 256, 0, stream>>>(
      BIGb, 768, b_ff2, 512, t_ff2_b, BIGb + 512, 768, 51200);
  k_ln_res<<<51200 / 4, 256, 0, stream>>>(Gb, BIGb + 512, 768, Gb, t_ln2_g, t_ln2_b);

  // ---- fused O-mean + temporal encoder + classifier ----
  k_heads<<<B_, 256, 0, stream>>>(Gb, daysb, dayss, te1_w, te1_b, te_ln1_g, te_ln1_b,
                                  te2_w, te2_b, te_ln2_g, te_ln2_b,
                                  w_c, c_b, c_ln_g, c_ln_b, (float*)d_out);
}

// Round 17
// 504.733 us; speedup vs baseline: 1.4783x; 1.0234x over previous
//
#include <hip/hip_runtime.h>

// NextBasketEncoder — round 17: k_gemm128 staged via global_load_lds (linear
// LDS, m97 2-barrier structure); item kernel P/V fragments as direct b128
// (stride-40 LDS rows). Rest identical to round 16.
// B=1024, O=50, L=20, D=64, H=128, DM=256, FF=512, V=49688.

#define B_ 1024
#define O_ 50
#define VROWS 49689            // V+1 embedding rows
#define VPAD  49792            // 389*128

typedef __attribute__((ext_vector_type(8))) short  short8v;
typedef __attribute__((ext_vector_type(8))) unsigned short ushort8v;
typedef __attribute__((ext_vector_type(4))) unsigned short ushort4v;
typedef __attribute__((ext_vector_type(4))) float f32x4;

__device__ __forceinline__ float sig_(float x)  { return 1.0f / (1.0f + __expf(-x)); }
__device__ __forceinline__ float tanh_(float x) { return 2.0f / (1.0f + __expf(-2.0f * x)) - 1.0f; }

__device__ __forceinline__ unsigned short f2bf(float f) {
  union { float f; unsigned int u; } v; v.f = f;
  unsigned int r = v.u + 0x7FFFu + ((v.u >> 16) & 1u);   // RNE
  return (unsigned short)(r >> 16);
}
__device__ __forceinline__ float bf2f(unsigned short u) {
  union { unsigned int u; float f; } v; v.u = ((unsigned int)u) << 16;
  return v.f;
}
__device__ __forceinline__ unsigned int pk2bf(float lo, float hi) {
  return (unsigned int)f2bf(lo) | ((unsigned int)f2bf(hi) << 16);
}

// async global->LDS, 16B per lane; LDS dest is wave-uniform base + lane*16
#define GL16(g, l) __builtin_amdgcn_global_load_lds( \
    (const __attribute__((address_space(1))) void*)(g), \
    (__attribute__((address_space(3))) void*)(l), 16, 0, 0)

// ---------------- segmented fp32 -> bf16 (one launch for all weights) -------
struct CvArgs {
  const float* src[10];
  unsigned short* dst[10];
  int n[10];
};
__global__ void k_cv_multi(CvArgs a) {
  int i = blockIdx.x * 256 + threadIdx.x;
#pragma unroll
  for (int s = 0; s < 10; ++s) {
    if (i < a.n[s]) { a.dst[s][i] = f2bf(a.src[s][i]); return; }
    i -= a.n[s];
  }
}

// ---------------- small prep: c_w transpose | bias concat | bias pad | fill -
__global__ void k_prep_small(const float* __restrict__ c_w, float* __restrict__ w_c,
                             const float* __restrict__ bia, const float* __restrict__ bib,
                             float* __restrict__ biascat,
                             const float* __restrict__ qb, float* __restrict__ biasq,
                             unsigned short* __restrict__ wpad) {
  int i = blockIdx.x * 256 + threadIdx.x;
  if (i < 40960) {                        // transpose c_w [128][320] -> [320][128]
    int r = i / 320, c = i - r * 320;
    w_c[c * 128 + r] = c_w[i];
    return;
  }
  i -= 40960;
  if (i < 768) { biascat[i] = (i < 384) ? bia[i] : bib[i - 384]; return; }
  i -= 768;
  if (i < 256) { biasq[i] = (i < 192) ? qb[i] : 0.f; return; }
  i -= 256;
  if (i < 4096) wpad[i] = 0;              // zero rows 192..255 of padded Wqkv
}

// ---------------- 128x128-tile bf16 GEMM via global_load_lds ---------------
// Linear LDS [128][32] (gload_lds needs contiguous dest). 2-barrier loop.
template<int RELU>
__global__ __launch_bounds__(256) void k_gemm128(
    const unsigned short* __restrict__ A, int lda,    // [M][lda] bf16
    const unsigned short* __restrict__ W, int K,      // [N][K] bf16
    const float* __restrict__ bias,
    unsigned short* __restrict__ C, int ldc, int Mclamp)
{
  __shared__ __align__(16) unsigned short As[128 * 32];
  __shared__ __align__(16) unsigned short Bs[128 * 32];
  int n0 = blockIdx.x * 128, m0 = blockIdx.y * 128;
  int t = threadIdx.x, wv = t >> 6, lane = t & 63;
  int fr = lane & 15, kg = lane >> 4;
  int wr = wv >> 1, wc = wv & 1;

  // staging map: chunk linear index il -> LDS bytes il*16; row=il/4, col8=(il&3)*8
  int il0 = wv * 128 + lane, il1 = il0 + 64;
  int ar0 = m0 + (il0 >> 2); if (ar0 >= Mclamp) ar0 = Mclamp - 1;
  int ar1 = m0 + (il1 >> 2); if (ar1 >= Mclamp) ar1 = Mclamp - 1;
  const unsigned short* gA0 = A + (size_t)ar0 * lda + (il0 & 3) * 8;
  const unsigned short* gA1 = A + (size_t)ar1 * lda + (il1 & 3) * 8;
  const unsigned short* gB0 = W + (size_t)(n0 + (il0 >> 2)) * K + (il0 & 3) * 8;
  const unsigned short* gB1 = W + (size_t)(n0 + (il1 >> 2)) * K + (il1 & 3) * 8;
  unsigned short* lA0 = &As[wv * 1024];
  unsigned short* lA1 = &As[wv * 1024 + 512];
  unsigned short* lB0 = &Bs[wv * 1024];
  unsigned short* lB1 = &Bs[wv * 1024 + 512];

  f32x4 acc[4][4];
#pragma unroll
  for (int mi = 0; mi < 4; ++mi)
#pragma unroll
    for (int ni = 0; ni < 4; ++ni) acc[mi][ni] = (f32x4){0.f, 0.f, 0.f, 0.f};

  for (int k0 = 0; k0 < K; k0 += 32) {
    __syncthreads();                        // prior reads of As/Bs complete
    GL16(gA0 + k0, lA0);
    GL16(gA1 + k0, lA1);
    GL16(gB0 + k0, lB0);
    GL16(gB1 + k0, lB1);
    __syncthreads();                        // vmcnt drained before barrier
    short8v af[4], bfv[4];
#pragma unroll
    for (int mi = 0; mi < 4; ++mi)
      af[mi] = *(const short8v*)&As[(wr * 64 + mi * 16 + fr) * 32 + kg * 8];
#pragma unroll
    for (int ni = 0; ni < 4; ++ni)
      bfv[ni] = *(const short8v*)&Bs[(wc * 64 + ni * 16 + fr) * 32 + kg * 8];
#pragma unroll
    for (int mi = 0; mi < 4; ++mi)
#pragma unroll
      for (int ni = 0; ni < 4; ++ni)
        acc[mi][ni] = __builtin_amdgcn_mfma_f32_16x16x32_bf16(af[mi], bfv[ni], acc[mi][ni], 0, 0, 0);
  }

#pragma unroll
  for (int ni = 0; ni < 4; ++ni) {
    int col = n0 + wc * 64 + ni * 16 + fr;
    float bb = bias[col];
#pragma unroll
    for (int mi = 0; mi < 4; ++mi) {
#pragma unroll
      for (int r = 0; r < 4; ++r) {
        int row = m0 + wr * 64 + mi * 16 + kg * 4 + r;
        float v = acc[mi][ni][r] + bb;
        if (RELU) v = fmaxf(v, 0.f);
        C[(size_t)row * ldc + col] = f2bf(v);
      }
    }
  }
}

// ---------------- fused item attention v6: stride-40 P/V, direct b128 -------
// 256 thr = 4 waves = 2 pairs x 2 halves. Natural-V buffer aliases Ps.
__global__ __launch_bounds__(256) void k_item_fused(
    const int* __restrict__ oh,
    const unsigned short* __restrict__ QKVall /*[VPAD][256] bf16*/,
    const float* __restrict__ wo /*[64][64] f32*/, const float* __restrict__ bob,
    unsigned short* __restrict__ X /*[B*O][64] bf16*/)
{
  __shared__ __align__(16) unsigned short QKs[2][20][144];
  __shared__ __align__(16) unsigned short VTs[2][64][40];  // 80B rows (b128-aligned)
  __shared__ __align__(16) unsigned short Ps[4][24][40];   // staging alias: Vs[2][20][72]
  __shared__ __align__(16) float mAs[2][68];
  __shared__ int ids[2][20];

  int t = threadIdx.x, wv = t >> 6, lane = t & 63;
  int fr = lane & 15, lg = lane >> 4;
  int pr = wv >> 1, half = wv & 1;
  unsigned short (*Vs)[20][72] = (unsigned short (*)[20][72])&Ps[0][0][0];  // 2880 <= 3840

  // index preload + VTs j-pad zero (j = 20..31; bV reads j<32)
  if (t < 40) ids[t / 20][t % 20] = oh[(size_t)(blockIdx.x * 2 + t / 20) * 20 + (t % 20)];
  for (int e = t; e < 768; e += 256) {        // 128 rows x 6 dwords
    int row = e / 6, cq = 20 + (e - (e / 6) * 6) * 2;
    *(unsigned int*)&VTs[row >> 6][row & 63][cq] = 0;
  }
  __syncthreads();

  // ---- gather Q|K rows (b128): 2 pairs x 20 rows x 16 chunks = 640 jobs ----
  for (int e = t; e < 640; e += 256) {
    int pp = e / 320, rem = e - pp * 320;
    int row = rem >> 4, ch = (rem & 15) * 8;
    const unsigned short* src = QKVall + (size_t)ids[pp][row] * 256 + ch;
    *(ushort8v*)&QKs[pp][row][ch] = *(const ushort8v*)src;
  }
  // ---- gather V rows natural (b128): 2 x 20 x 8 chunks = 320 jobs ----
  for (int e = t; e < 320; e += 256) {
    int pp = e / 160, rem = e - pp * 160;
    int row = rem >> 3, ch = (rem & 7) * 8;
    const unsigned short* src = QKVall + (size_t)ids[pp][row] * 256 + 128 + ch;
    *(ushort8v*)&Vs[pp][row][ch] = *(const ushort8v*)src;
  }
  __syncthreads();

  // ---- transpose V in LDS: 2 pairs x 10 jpairs x 32 cpairs = 640 jobs ----
  for (int e = t; e < 640; e += 256) {
    int pp = e / 320, rem = e - pp * 320;
    int jp = rem >> 5, c0 = (rem & 31) * 2;
    unsigned int a = *(const unsigned int*)&Vs[pp][2 * jp][c0];
    unsigned int b = *(const unsigned int*)&Vs[pp][2 * jp + 1][c0];
    *(unsigned int*)&VTs[pp][c0][2 * jp]     = (a & 0xFFFFu) | (b << 16);
    *(unsigned int*)&VTs[pp][c0 + 1][2 * jp] = (a >> 16) | (b & 0xFFFF0000u);
  }
  __syncthreads();

  // per-wave zero of Ps[wv][20] cols 0..31 (the only pad row AV reads)
  if (lane < 16) *(unsigned int*)&Ps[wv][20][lane * 2] = 0;

  // ---- this half's 2 heads: S^T = K@Q^T, no-max softmax, AV via MFMA ----
  int rj1 = (fr + 16 < 20) ? fr + 16 : 19;
  bool iv1 = fr < 4;
  int pr1 = iv1 ? 16 + fr : 20;
#pragma unroll
  for (int hi = 0; hi < 2; ++hi) {
    int h = half * 2 + hi;
    short8v aK0, aK1, bQ0, bQ1;
    {
      short8v z = {0,0,0,0,0,0,0,0};
      aK0 = z; aK1 = z; bQ0 = z; bQ1 = z;
    }
    if (lg < 2) {
      aK0 = *(const short8v*)&QKs[pr][fr][64 + h * 16 + lg * 8];
      aK1 = *(const short8v*)&QKs[pr][rj1][64 + h * 16 + lg * 8];
      bQ0 = *(const short8v*)&QKs[pr][fr][h * 16 + lg * 8];
      bQ1 = *(const short8v*)&QKs[pr][rj1][h * 16 + lg * 8];
    }
    f32x4 s00 = {0.f,0.f,0.f,0.f}, s01 = {0.f,0.f,0.f,0.f};
    f32x4 s10 = {0.f,0.f,0.f,0.f}, s11 = {0.f,0.f,0.f,0.f};
    s00 = __builtin_amdgcn_mfma_f32_16x16x32_bf16(aK0, bQ0, s00, 0, 0, 0);
    s01 = __builtin_amdgcn_mfma_f32_16x16x32_bf16(aK0, bQ1, s01, 0, 0, 0);
    s10 = __builtin_amdgcn_mfma_f32_16x16x32_bf16(aK1, bQ0, s10, 0, 0, 0);
    s11 = __builtin_amdgcn_mfma_f32_16x16x32_bf16(aK1, bQ1, s11, 0, 0, 0);

    float e00[4], e01[4], e10[4], e11[4];
    float d0 = 0.f, d1 = 0.f;
#pragma unroll
    for (int r = 0; r < 4; ++r) {
      int j1 = 16 + lg * 4 + r;
      bool jv1 = j1 < 20;
      float v00 = __expf(0.25f * s00[r]);
      float v01 = iv1 ? __expf(0.25f * s01[r]) : 0.f;
      float v10 = jv1 ? __expf(0.25f * s10[r]) : 0.f;
      float v11 = (jv1 && iv1) ? __expf(0.25f * s11[r]) : 0.f;
      e00[r] = v00; e01[r] = v01; e10[r] = v10; e11[r] = v11;
      d0 += v00 + v10; d1 += v01 + v11;
    }
    d0 += __shfl_xor(d0, 16, 64); d0 += __shfl_xor(d0, 32, 64);
    d1 += __shfl_xor(d1, 16, 64); d1 += __shfl_xor(d1, 32, 64);
    float inv0 = __fdividef(1.f, d0);
    float inv1 = iv1 ? __fdividef(1.f, d1) : 0.f;

    *(unsigned int*)&Ps[wv][fr][lg * 4]          = pk2bf(e00[0]*inv0, e00[1]*inv0);
    *(unsigned int*)&Ps[wv][fr][lg * 4 + 2]      = pk2bf(e00[2]*inv0, e00[3]*inv0);
    *(unsigned int*)&Ps[wv][fr][16 + lg * 4]     = pk2bf(e10[0]*inv0, e10[1]*inv0);
    *(unsigned int*)&Ps[wv][fr][16 + lg * 4 + 2] = pk2bf(e10[2]*inv0, e10[3]*inv0);
    if (iv1) {
      *(unsigned int*)&Ps[wv][16 + fr][lg * 4]          = pk2bf(e01[0]*inv1, e01[1]*inv1);
      *(unsigned int*)&Ps[wv][16 + fr][lg * 4 + 2]      = pk2bf(e01[2]*inv1, e01[3]*inv1);
      *(unsigned int*)&Ps[wv][16 + fr][16 + lg * 4]     = pk2bf(e11[0]*inv1, e11[1]*inv1);
      *(unsigned int*)&Ps[wv][16 + fr][16 + lg * 4 + 2] = pk2bf(e11[2]*inv1, e11[3]*inv1);
    }

    short8v pa0 = *(const short8v*)&Ps[wv][fr][lg * 8];
    short8v pa1 = *(const short8v*)&Ps[wv][pr1][lg * 8];
    short8v bV  = *(const short8v*)&VTs[pr][h * 16 + fr][lg * 8];
    f32x4 m20 = {0.f,0.f,0.f,0.f}, m21 = {0.f,0.f,0.f,0.f};
    m20 = __builtin_amdgcn_mfma_f32_16x16x32_bf16(pa0, bV, m20, 0, 0, 0);
    m21 = __builtin_amdgcn_mfma_f32_16x16x32_bf16(pa1, bV, m21, 0, 0, 0);

    float sm = m20[0] + m20[1] + m20[2] + m20[3];
    if (lg == 0) sm += m21[0] + m21[1] + m21[2] + m21[3];
    sm += __shfl_xor(sm, 16, 64);
    sm += __shfl_xor(sm, 32, 64);
    if (lg == 0) mAs[pr][h * 16 + fr] = sm * 0.05f;
  }
  __syncthreads();

  // ---- out-proj of the mean: 128 threads = 2 pairs x 64 cols, bf16 out ----
  if (t < 128) {
    int p2 = t >> 6, col = t & 63;
    float acc = bob[col];
    const float* wrow = &wo[(size_t)col * 64];
    for (int k = 0; k < 64; k += 4) {
      float4 m4 = *(const float4*)&mAs[p2][k];
      float4 w4 = *(const float4*)(wrow + k);
      acc += m4.x * w4.x + m4.y * w4.y + m4.z * w4.z + m4.w * w4.w;
    }
    X[(size_t)(blockIdx.x * 2 + p2) * 64 + col] = f2bf(acc);
  }
}

// ---------------- GRU recurrence (bf16 G output, full batch) ----------------
__global__ __launch_bounds__(512) void k_gru_mfma(
    const unsigned short* __restrict__ GI,   // [B*O][768]: 0-383 fwd, 384-767 bwd
    const unsigned short* __restrict__ whf,
    const unsigned short* __restrict__ whb,
    const float* __restrict__ bh_f, const float* __restrict__ bh_b,
    unsigned short* __restrict__ G /*[B*O][256] bf16*/)
{
  __shared__ unsigned short hsb[16][136];
  __shared__ float ah[4][392];

  int bid = blockIdx.x;
  int dir = bid >> 8;            // 256 row-groups per dir
  int rg  = bid & 255;
  const unsigned short* wh = dir ? whb : whf;
  const float* bh = dir ? bh_b : bh_f;

  int t = threadIdx.x;
  int w = t >> 6, lane = t & 63;
  int fr = lane & 15, kg = lane >> 4;

  short8v bfr[3][4];
#pragma unroll
  for (int n = 0; n < 3; ++n)
#pragma unroll
    for (int kf = 0; kf < 4; ++kf)
      bfr[n][kf] = *(const short8v*)&wh[(size_t)(w * 48 + n * 16 + fr) * 128 + kf * 32 + kg * 8];

  for (int e = t; e < 16 * 136; e += 512) ((unsigned short*)hsb)[e] = 0;

  int grow = t >> 7, gc = t & 127;
  float bh0 = bh[gc], bh1 = bh[128 + gc], bh2 = bh[256 + gc];
  float hold = 0.f;
  const unsigned short* gip = &GI[(size_t)(rg * 4 + grow) * 50 * 768 + dir * 384];
  unsigned short* gout = &G[((size_t)(rg * 4 + grow) * 50) * 256 + dir * 128 + gc];

  __syncthreads();

  int o0 = dir ? 49 : 0;
  unsigned short c0v = gip[(size_t)o0 * 768 + gc];
  unsigned short c1v = gip[(size_t)o0 * 768 + 128 + gc];
  unsigned short c2v = gip[(size_t)o0 * 768 + 256 + gc];

  for (int s = 0; s < 50; ++s) {
    int o  = dir ? 49 - s : s;
    unsigned short n0v = 0, n1v = 0, n2v = 0;
    if (s < 49) {
      int on = dir ? 48 - s : s + 1;
      n0v = gip[(size_t)on * 768 + gc];
      n1v = gip[(size_t)on * 768 + 128 + gc];
      n2v = gip[(size_t)on * 768 + 256 + gc];
    }

    short8v a0 = *(const short8v*)&hsb[fr][0 * 32 + kg * 8];
    short8v a1 = *(const short8v*)&hsb[fr][1 * 32 + kg * 8];
    short8v a2 = *(const short8v*)&hsb[fr][2 * 32 + kg * 8];
    short8v a3 = *(const short8v*)&hsb[fr][3 * 32 + kg * 8];

    f32x4 acc0 = {0.f,0.f,0.f,0.f}, acc1 = {0.f,0.f,0.f,0.f}, acc2 = {0.f,0.f,0.f,0.f};
    acc0 = __builtin_amdgcn_mfma_f32_16x16x32_bf16(a0, bfr[0][0], acc0, 0, 0, 0);
    acc1 = __builtin_amdgcn_mfma_f32_16x16x32_bf16(a0, bfr[1][0], acc1, 0, 0, 0);
    acc2 = __builtin_amdgcn_mfma_f32_16x16x32_bf16(a0, bfr[2][0], acc2, 0, 0, 0);
    acc0 = __builtin_amdgcn_mfma_f32_16x16x32_bf16(a1, bfr[0][1], acc0, 0, 0, 0);
    acc1 = __builtin_amdgcn_mfma_f32_16x16x32_bf16(a1, bfr[1][1], acc1, 0, 0, 0);
    acc2 = __builtin_amdgcn_mfma_f32_16x16x32_bf16(a1, bfr[2][1], acc2, 0, 0, 0);
    acc0 = __builtin_amdgcn_mfma_f32_16x16x32_bf16(a2, bfr[0][2], acc0, 0, 0, 0);
    acc1 = __builtin_amdgcn_mfma_f32_16x16x32_bf16(a2, bfr[1][2], acc1, 0, 0, 0);
    acc2 = __builtin_amdgcn_mfma_f32_16x16x32_bf16(a2, bfr[2][2], acc2, 0, 0, 0);
    acc0 = __builtin_amdgcn_mfma_f32_16x16x32_bf16(a3, bfr[0][3], acc0, 0, 0, 0);
    acc1 = __builtin_amdgcn_mfma_f32_16x16x32_bf16(a3, bfr[1][3], acc1, 0, 0, 0);
    acc2 = __builtin_amdgcn_mfma_f32_16x16x32_bf16(a3, bfr[2][3], acc2, 0, 0, 0);

    if (kg == 0) {
#pragma unroll
      for (int r = 0; r < 4; ++r) {
        ah[r][w * 48 + 0 * 16 + fr] = acc0[r];
        ah[r][w * 48 + 1 * 16 + fr] = acc1[r];
        ah[r][w * 48 + 2 * 16 + fr] = acc2[r];
      }
    }
    __syncthreads();

    float ai0 = bf2f(c0v), ai1 = bf2f(c1v), ai2 = bf2f(c2v);
    float ah0 = ah[grow][gc] + bh0;
    float ah1 = ah[grow][128 + gc] + bh1;
    float ah2 = ah[grow][256 + gc] + bh2;
    float rr = sig_(ai0 + ah0);
    float zz = sig_(ai1 + ah1);
    float nn = tanh_(ai2 + rr * ah2);
    float h2 = (1.f - zz) * nn + zz * hold;
    hold = h2;
    unsigned short hb = f2bf(h2);
    hsb[grow][gc] = hb;
    gout[(size_t)o * 256] = hb;
    c0v = n0v; c1v = n1v; c2v = n2v;
    __syncthreads();
  }
}

// ---------------- transformer attention core v2 (unchanged from R16) --------
__global__ __launch_bounds__(256) void k_attn_core(unsigned short* __restrict__ BIG)
{
  __shared__ __align__(16) unsigned short Qs[64][72];
  __shared__ __align__(16) unsigned short Ks[64][72];
  __shared__ __align__(16) unsigned short VTs[64][72];   // [d][j]
  __shared__ __align__(16) unsigned short Ps[4][16][72]; // per-wave P[i][j]
  unsigned short (*Vs)[64] = (unsigned short (*)[64])&Ps[0][0][0];  // [50][64] alias

  int bl = blockIdx.x >> 2, h = blockIdx.x & 3;
  int t = threadIdx.x, wv = t >> 6, lane = t & 63;
  int fr = lane & 15, lg = lane >> 4;
  size_t base = (size_t)bl * 50 * 768;
  int hc = h * 64;

  for (int e = t; e < 504; e += 256) {
    int r = e / 36, c = (e - r * 36) * 2;
    *(unsigned int*)&Qs[50 + r][c] = 0;
    *(unsigned int*)&Ks[50 + r][c] = 0;
  }
  for (int e = t; e < 2304; e += 256) {
    int r = e / 36, c = (e - r * 36) * 2;
    *(unsigned int*)&VTs[r][c] = 0;
  }
  __syncthreads();

  for (int e = t; e < 400; e += 256) {
    int row = e >> 3, ch = (e & 7) * 8;
    *(ushort8v*)&Qs[row][ch] = *(const ushort8v*)&BIG[base + (size_t)row * 768 + hc + ch];
  }
  for (int e = t; e < 400; e += 256) {
    int row = e >> 3, ch = (e & 7) * 8;
    *(ushort8v*)&Ks[row][ch] = *(const ushort8v*)&BIG[base + (size_t)row * 768 + 256 + hc + ch];
  }
  for (int e = t; e < 400; e += 256) {
    int row = e >> 3, ch = (e & 7) * 8;
    *(ushort8v*)&Vs[row][ch] = *(const ushort8v*)&BIG[base + (size_t)row * 768 + 512 + hc + ch];
  }
  __syncthreads();

  for (int e = t; e < 800; e += 256) {
    int jp = e >> 5, c0 = (e & 31) * 2;
    unsigned int a = *(const unsigned int*)&Vs[2 * jp][c0];
    unsigned int b = *(const unsigned int*)&Vs[2 * jp + 1][c0];
    *(unsigned int*)&VTs[c0][2 * jp]     = (a & 0xFFFFu) | (b << 16);
    *(unsigned int*)&VTs[c0 + 1][2 * jp] = (a >> 16) | (b & 0xFFFF0000u);
  }
  __syncthreads();

  int i0 = wv * 16;
  short8v bQ0 = *(const short8v*)&Qs[i0 + fr][lg * 8];
  short8v bQ1 = *(const short8v*)&Qs[i0 + fr][32 + lg * 8];

  f32x4 s[4];
#pragma unroll
  for (int jt = 0; jt < 4; ++jt) {
    short8v aK0 = *(const short8v*)&Ks[jt * 16 + fr][lg * 8];
    short8v aK1 = *(const short8v*)&Ks[jt * 16 + fr][32 + lg * 8];
    f32x4 acc = {0.f, 0.f, 0.f, 0.f};
    acc = __builtin_amdgcn_mfma_f32_16x16x32_bf16(aK0, bQ0, acc, 0, 0, 0);
    acc = __builtin_amdgcn_mfma_f32_16x16x32_bf16(aK1, bQ1, acc, 0, 0, 0);
    s[jt] = acc;
  }

  float m = -1e30f;
#pragma unroll
  for (int jt = 0; jt < 4; ++jt)
#pragma unroll
    for (int r = 0; r < 4; ++r) {
      int j = jt * 16 + lg * 4 + r;
      float v = s[jt][r] * 0.125f;
      if (j < 50) m = fmaxf(m, v);
    }
  m = fmaxf(m, __shfl_xor(m, 16, 64));
  m = fmaxf(m, __shfl_xor(m, 32, 64));

  float ev[4][4];
  float den = 0.f;
#pragma unroll
  for (int jt = 0; jt < 4; ++jt)
#pragma unroll
    for (int r = 0; r < 4; ++r) {
      int j = jt * 16 + lg * 4 + r;
      float e = (j < 50) ? __expf(s[jt][r] * 0.125f - m) : 0.f;
      ev[jt][r] = e;
      den += e;
    }
  den += __shfl_xor(den, 16, 64);
  den += __shfl_xor(den, 32, 64);
  float inv = __fdividef(1.f, den);

#pragma unroll
  for (int jt = 0; jt < 4; ++jt) {
    *(unsigned int*)&Ps[wv][fr][jt * 16 + lg * 4]     = pk2bf(ev[jt][0] * inv, ev[jt][1] * inv);
    *(unsigned int*)&Ps[wv][fr][jt * 16 + lg * 4 + 2] = pk2bf(ev[jt][2] * inv, ev[jt][3] * inv);
  }

  short8v pa0 = *(const short8v*)&Ps[wv][fr][lg * 8];
  short8v pa1 = *(const short8v*)&Ps[wv][fr][32 + lg * 8];
#pragma unroll
  for (int dt = 0; dt < 4; ++dt) {
    short8v bV0 = *(const short8v*)&VTs[dt * 16 + fr][lg * 8];
    short8v bV1 = *(const short8v*)&VTs[dt * 16 + fr][32 + lg * 8];
    f32x4 o = {0.f, 0.f, 0.f, 0.f};
    o = __builtin_amdgcn_mfma_f32_16x16x32_bf16(pa0, bV0, o, 0, 0, 0);
    o = __builtin_amdgcn_mfma_f32_16x16x32_bf16(pa1, bV1, o, 0, 0, 0);
#pragma unroll
    for (int r = 0; r < 4; ++r) {
      int i = i0 + lg * 4 + r;
      if (i < 50)
        BIG[base + (size_t)i * 768 + hc + dt * 16 + fr] = f2bf(o[r]);
    }
  }
}

// ---------------- fused residual + LayerNorm (bf16 I/O, wave per row) -------
__global__ __launch_bounds__(256) void k_ln_res(
    const unsigned short* __restrict__ res, const unsigned short* __restrict__ add,
    int addld, unsigned short* __restrict__ dst,
    const float* __restrict__ g, const float* __restrict__ bt)
{
  int row = blockIdx.x * 4 + (threadIdx.x >> 6);
  int lane = threadIdx.x & 63;
  int c = lane * 4;
  ushort4v rv = *(const ushort4v*)&res[(size_t)row * 256 + c];
  ushort4v av = *(const ushort4v*)&add[(size_t)row * addld + c];
  float x0 = bf2f(rv[0]) + bf2f(av[0]);
  float x1 = bf2f(rv[1]) + bf2f(av[1]);
  float x2 = bf2f(rv[2]) + bf2f(av[2]);
  float x3 = bf2f(rv[3]) + bf2f(av[3]);
  float s = x0 + x1 + x2 + x3;
  float sq = x0 * x0 + x1 * x1 + x2 * x2 + x3 * x3;
#pragma unroll
  for (int d = 1; d < 64; d <<= 1) { s += __shfl_xor(s, d, 64); sq += __shfl_xor(sq, d, 64); }
  float m = s * (1.f / 256.f);
  float var = sq * (1.f / 256.f) - m * m;
  float rs = rsqrtf(var + 1e-5f);
  float4 gv = *(const float4*)&g[c];
  float4 bv = *(const float4*)&bt[c];
  ushort4v ov;
  ov[0] = f2bf((x0 - m) * rs * gv.x + bv.x);
  ov[1] = f2bf((x1 - m) * rs * gv.y + bv.y);
  ov[2] = f2bf((x2 - m) * rs * gv.z + bv.z);
  ov[3] = f2bf((x3 - m) * rs * gv.w + bv.w);
  *(ushort4v*)&dst[(size_t)row * 256 + c] = ov;
}

// ---------------- temporal encoder + O-mean + final classifier (fused) ------
__global__ __launch_bounds__(256) void k_heads(
    const unsigned short* __restrict__ H2 /*[B*O][256] bf16*/,
    const float* __restrict__ daysb, const float* __restrict__ dayss,
    const float* __restrict__ te1_w, const float* __restrict__ te1_b,
    const float* __restrict__ ln1g, const float* __restrict__ ln1b,
    const float* __restrict__ te2_w, const float* __restrict__ te2_b,
    const float* __restrict__ ln2g, const float* __restrict__ ln2b,
    const float* __restrict__ cWT /*[320][128]*/,
    const float* __restrict__ c_b, const float* __restrict__ clng,
    const float* __restrict__ clnb, float* __restrict__ out)
{
  __shared__ float oe[256];
  __shared__ float feat[2];
  __shared__ float s1[32], s2[64], pre[128], stat[2];
  int b = blockIdx.x, t = threadIdx.x;
  {
    float s = 0.f;
    for (int o = 0; o < 50; ++o) s += bf2f(H2[((size_t)b * 50 + o) * 256 + t]);
    oe[t] = s * 0.02f;
  }
  if (t == 0) {
    float f0 = 0.f;
    for (int i = 0; i < 10; ++i) f0 += daysb[b * 10 + i];
    feat[0] = f0 * 0.1f;
    feat[1] = dayss[b];
  }
  __syncthreads();
  if (t < 32) s1[t] = te1_b[t] + feat[0] * te1_w[2 * t] + feat[1] * te1_w[2 * t + 1];
  __syncthreads();
  if (t == 0) {
    float s = 0.f; for (int j = 0; j < 32; ++j) s += s1[j];
    float m = s * (1.f / 32.f);
    float v = 0.f; for (int j = 0; j < 32; ++j) { float d = s1[j] - m; v += d * d; }
    stat[0] = m; stat[1] = rsqrtf(v * (1.f / 32.f) + 1e-5f);
  }
  __syncthreads();
  if (t < 32) s1[t] = fmaxf((s1[t] - stat[0]) * stat[1] * ln1g[t] + ln1b[t], 0.f);
  __syncthreads();
  if (t < 64) {
    float a = te2_b[t];
    for (int k = 0; k < 32; ++k) a += s1[k] * te2_w[t * 32 + k];
    s2[t] = a;
  }
  __syncthreads();
  if (t == 0) {
    float s = 0.f; for (int j = 0; j < 64; ++j) s += s2[j];
    float m = s * (1.f / 64.f);
    float v = 0.f; for (int j = 0; j < 64; ++j) { float d = s2[j] - m; v += d * d; }
    stat[0] = m; stat[1] = rsqrtf(v * (1.f / 64.f) + 1e-5f);
  }
  __syncthreads();
  if (t < 64) s2[t] = fmaxf((s2[t] - stat[0]) * stat[1] * ln2g[t] + ln2b[t], 0.f);
  __syncthreads();
  if (t < 128) {
    float p = c_b[t];
    for (int k = 0; k < 256; ++k) p += oe[k] * cWT[k * 128 + t];
    for (int k = 0; k < 64; ++k)  p += s2[k] * cWT[(256 + k) * 128 + t];
    pre[t] = p;
  }
  __syncthreads();
  if (t == 0) {
    float s = 0.f; for (int j = 0; j < 128; ++j) s += pre[j];
    float m = s * (1.f / 128.f);
    float v = 0.f; for (int j = 0; j < 128; ++j) { float d = pre[j] - m; v += d * d; }
    stat[0] = m; stat[1] = rsqrtf(v * (1.f / 128.f) + 1e-5f);
  }
  __syncthreads();
  if (t < 128)
    out[(size_t)b * 128 + t] = fmaxf((pre[t] - stat[0]) * stat[1] * clng[t] + clnb[t], 0.f);
}

// ---------------- host launcher ----------------
extern "C" void kernel_launch(void* const* d_in, const int* in_sizes, int n_in,
                              void* d_out, int out_size, void* d_ws, size_t ws_size,
                              hipStream_t stream)
{
  const int*   oh       = (const int*)d_in[0];
  const float* daysb    = (const float*)d_in[1];
  const float* dayss    = (const float*)d_in[2];
  const float* emb      = (const float*)d_in[3];
  const float* ia_in_w  = (const float*)d_in[4];
  const float* ia_in_b  = (const float*)d_in[5];
  const float* ia_out_w = (const float*)d_in[6];
  const float* ia_out_b = (const float*)d_in[7];
  const float* gf_wi = (const float*)d_in[8];
  const float* gf_wh = (const float*)d_in[9];
  const float* gf_bi = (const float*)d_in[10];
  const float* gf_bh = (const float*)d_in[11];
  const float* gb_wi = (const float*)d_in[12];
  const float* gb_wh = (const float*)d_in[13];
  const float* gb_bi = (const float*)d_in[14];
  const float* gb_bh = (const float*)d_in[15];
  const float* ta_in_w  = (const float*)d_in[16];
  const float* ta_in_b  = (const float*)d_in[17];
  const float* ta_out_w = (const float*)d_in[18];
  const float* ta_out_b = (const float*)d_in[19];
  const float* t_ln1_g = (const float*)d_in[20];
  const float* t_ln1_b = (const float*)d_in[21];
  const float* t_ln2_g = (const float*)d_in[22];
  const float* t_ln2_b = (const float*)d_in[23];
  const float* t_ff1_w = (const float*)d_in[24];
  const float* t_ff1_b = (const float*)d_in[25];
  const float* t_ff2_w = (const float*)d_in[26];
  const float* t_ff2_b = (const float*)d_in[27];
  const float* te1_w = (const float*)d_in[28];
  const float* te1_b = (const float*)d_in[29];
  const float* te_ln1_g = (const float*)d_in[30];
  const float* te_ln1_b = (const float*)d_in[31];
  const float* te2_w = (const float*)d_in[32];
  const float* te2_b = (const float*)d_in[33];
  const float* te_ln2_g = (const float*)d_in[34];
  const float* te_ln2_b = (const float*)d_in[35];
  const float* c_w   = (const float*)d_in[36];
  const float* c_b   = (const float*)d_in[37];
  const float* c_ln_g = (const float*)d_in[38];
  const float* c_ln_b = (const float*)d_in[39];

  float* ws = (float*)d_ws;
  // layout (floats):
  const size_t OFF_GB   = 0;                        // G bf16 [51200][256] = 6,553,600 fl
  const size_t OFF_X    = 6553600;                  // X bf16 [51200][64]  = 1,638,400 fl
  const size_t OFF_S    = OFF_X + 1638400;          // QKVall | GI | BIGb  = 19,660,800 fl
  const size_t OW_C     = OFF_S + 19660800;         // [320][128] 40,960
  const size_t OW_BC    = OW_C + 40960;             // 768
  const size_t OW_BQ    = OW_BC + 768;              // padded qkv bias 256
  const size_t OW_BF    = OW_BQ + 256;              // bf16 weight pool 344,064 fl
  const size_t OW_EMB   = OW_BF + 344064;           // bf16 emb table 1,590,048 fl
  const size_t TOTAL    = OW_EMB + 1590048;         // 29,828,896 fl = 119.3 MB
  if (ws_size < TOTAL * sizeof(float)) return;

  unsigned short* Gb = (unsigned short*)(ws + OFF_GB);
  unsigned short* Xb = (unsigned short*)(ws + OFF_X);
  float* w_c  = ws + OW_C;
  float* biascat = ws + OW_BC;
  float* biasq   = ws + OW_BQ;
  unsigned short* bfp = (unsigned short*)(ws + OW_BF);
  unsigned short* b_ta_in  = bfp;                  // 196,608
  unsigned short* b_ta_out = b_ta_in + 196608;     //  65,536
  unsigned short* b_ff1    = b_ta_out + 65536;     // 131,072
  unsigned short* b_ff2    = b_ff1 + 131072;       // 131,072
  unsigned short* b_qkvw   = b_ff2 + 131072;       //  16,384 (padded [256][64])
  unsigned short* b_wi_f   = b_qkvw + 16384;       //  24,576 ── Wcat [768][64]
  unsigned short* b_wi_b   = b_wi_f + 24576;       //  24,576 ──┘
  unsigned short* b_wh_f   = b_wi_b + 24576;       //  49,152
  unsigned short* b_wh_b   = b_wh_f + 49152;       //  49,152
  unsigned short* embb = (unsigned short*)(ws + OW_EMB);  // [(V+1)][64] bf16

  // scratch phase views (aliased; QKVall dead before GI is written):
  unsigned short* QKVall = (unsigned short*)(ws + OFF_S); // [VPAD][256] bf16 (25.5MB)
  unsigned short* GI     = (unsigned short*)(ws + OFF_S); // gru: [51200][768] bf16
  unsigned short* BIGb   = (unsigned short*)(ws + OFF_S); // transformer: [51200][768]

  // ---- prologue: 2 launches ----
  k_prep_small<<<(40960 + 768 + 256 + 4096 + 255) / 256, 256, 0, stream>>>(
      c_w, w_c, gf_bi, gb_bi, biascat, ia_in_b, biasq, b_qkvw + 12288);
  {
    CvArgs a;
    a.src[0] = ta_in_w;  a.dst[0] = b_ta_in;  a.n[0] = 196608;
    a.src[1] = ta_out_w; a.dst[1] = b_ta_out; a.n[1] = 65536;
    a.src[2] = t_ff1_w;  a.dst[2] = b_ff1;    a.n[2] = 131072;
    a.src[3] = t_ff2_w;  a.dst[3] = b_ff2;    a.n[3] = 131072;
    a.src[4] = ia_in_w;  a.dst[4] = b_qkvw;   a.n[4] = 12288;
    a.src[5] = gf_wi;    a.dst[5] = b_wi_f;   a.n[5] = 24576;
    a.src[6] = gb_wi;    a.dst[6] = b_wi_b;   a.n[6] = 24576;
    a.src[7] = gf_wh;    a.dst[7] = b_wh_f;   a.n[7] = 49152;
    a.src[8] = gb_wh;    a.dst[8] = b_wh_b;   a.n[8] = 49152;
    a.src[9] = emb;      a.dst[9] = embb;     a.n[9] = 3180096;
    int total = 196608 + 65536 + 131072 + 131072 + 12288 + 24576 + 24576 + 49152 + 49152 + 3180096;
    k_cv_multi<<<(total + 255) / 256, 256, 0, stream>>>(a);
  }

  // ---- precompute QKVall = embb @ Wqkv^T + b (vocab-wide, once) ----
  k_gemm128<0><<<dim3(256 / 128, VPAD / 128), 256, 0, stream>>>(
      embb, 64, b_qkvw, 64, biasq, QKVall, 256, VROWS);

  // ---- item attention: gather + attend (2 pairs/block) ----
  k_item_fused<<<B_ * O_ / 2, 256, 0, stream>>>(oh, QKVall, ia_out_w, ia_out_b, Xb);

  // ---- bidirectional GRU: single chunk over full batch ----
  k_gemm128<0><<<dim3(768 / 128, 51200 / 128), 256, 0, stream>>>(
      Xb, 64, b_wi_f /*Wcat [768][64]*/, 64, biascat, GI, 768, 51200);
  k_gru_mfma<<<512, 512, 0, stream>>>(GI, b_wh_f, b_wh_b, gf_bh, gb_bh, Gb);

  // ---- transformer layer: single chunk, bf16, in-place in BIGb ----
  k_gemm128<0><<<dim3(768 / 128, 51200 / 128), 256, 0, stream>>>(
      Gb, 256, b_ta_in, 256, ta_in_b, BIGb, 768, 51200);
  k_attn_core<<<B_ * 4, 256, 0, stream>>>(BIGb);
  k_gemm128<0><<<dim3(256 / 128, 51200 / 128), 256, 0, stream>>>(
      BIGb, 768, b_ta_out, 256, ta_out_b, BIGb + 256, 768, 51200);
  k_ln_res<<<51200 / 4, 256, 0, stream>>>(Gb, BIGb + 256, 768, Gb, t_ln1_g, t_ln1_b);
  k_gemm128<1><<<dim3(512 / 128, 51200 / 128), 256, 0, stream>>>(
      Gb, 256, b_ff1, 256, t_ff1_b, BIGb, 768, 51200);
  k_gemm128<0><<<dim3(256 / 128, 51200 / 128), 256, 0, stream>>>(
      BIGb, 768, b_ff2, 512, t_ff2_b, BIGb + 512, 768, 51200);
  k_ln_res<<<51200 / 4, 256, 0, stream>>>(Gb, BIGb + 512, 768, Gb, t_ln2_g, t_ln2_b);

  // ---- fused O-mean + temporal encoder + classifier ----
  k_heads<<<B_, 256, 0, stream>>>(Gb, daysb, dayss, te1_w, te1_b, te_ln1_g, te_ln1_b,
                                  te2_w, te2_b, te_ln2_g, te_ln2_b,
                                  w_c, c_b, c_ln_g, c_ln_b, (float*)d_out);
}

// Round 18
// 500.879 us; speedup vs baseline: 1.4896x; 1.0077x over previous
//
#include <hip/hip_runtime.h>

// NextBasketEncoder — round 18 (consolidation): best-measured variant of every
// kernel. Item = R15/R16 version (stride-36, repack; 200.1us); GEMM = R17
// global_load_lds version; attn/GRU/LN/heads unchanged.
// B=1024, O=50, L=20, D=64, H=128, DM=256, FF=512, V=49688.

#define B_ 1024
#define O_ 50
#define VROWS 49689            // V+1 embedding rows
#define VPAD  49792            // 389*128

typedef __attribute__((ext_vector_type(8))) short  short8v;
typedef __attribute__((ext_vector_type(4))) short  short4v;
typedef __attribute__((ext_vector_type(8))) unsigned short ushort8v;
typedef __attribute__((ext_vector_type(4))) unsigned short ushort4v;
typedef __attribute__((ext_vector_type(4))) float f32x4;

__device__ __forceinline__ float sig_(float x)  { return 1.0f / (1.0f + __expf(-x)); }
__device__ __forceinline__ float tanh_(float x) { return 2.0f / (1.0f + __expf(-2.0f * x)) - 1.0f; }

__device__ __forceinline__ unsigned short f2bf(float f) {
  union { float f; unsigned int u; } v; v.f = f;
  unsigned int r = v.u + 0x7FFFu + ((v.u >> 16) & 1u);   // RNE
  return (unsigned short)(r >> 16);
}
__device__ __forceinline__ float bf2f(unsigned short u) {
  union { unsigned int u; float f; } v; v.u = ((unsigned int)u) << 16;
  return v.f;
}
__device__ __forceinline__ unsigned int pk2bf(float lo, float hi) {
  return (unsigned int)f2bf(lo) | ((unsigned int)f2bf(hi) << 16);
}

// async global->LDS, 16B per lane; LDS dest is wave-uniform base + lane*16
#define GL16(g, l) __builtin_amdgcn_global_load_lds( \
    (const __attribute__((address_space(1))) void*)(g), \
    (__attribute__((address_space(3))) void*)(l), 16, 0, 0)

// ---------------- segmented fp32 -> bf16 (one launch for all weights) -------
struct CvArgs {
  const float* src[10];
  unsigned short* dst[10];
  int n[10];
};
__global__ void k_cv_multi(CvArgs a) {
  int i = blockIdx.x * 256 + threadIdx.x;
#pragma unroll
  for (int s = 0; s < 10; ++s) {
    if (i < a.n[s]) { a.dst[s][i] = f2bf(a.src[s][i]); return; }
    i -= a.n[s];
  }
}

// ---------------- small prep: c_w transpose | bias concat | bias pad | fill -
__global__ void k_prep_small(const float* __restrict__ c_w, float* __restrict__ w_c,
                             const float* __restrict__ bia, const float* __restrict__ bib,
                             float* __restrict__ biascat,
                             const float* __restrict__ qb, float* __restrict__ biasq,
                             unsigned short* __restrict__ wpad) {
  int i = blockIdx.x * 256 + threadIdx.x;
  if (i < 40960) {                        // transpose c_w [128][320] -> [320][128]
    int r = i / 320, c = i - r * 320;
    w_c[c * 128 + r] = c_w[i];
    return;
  }
  i -= 40960;
  if (i < 768) { biascat[i] = (i < 384) ? bia[i] : bib[i - 384]; return; }
  i -= 768;
  if (i < 256) { biasq[i] = (i < 192) ? qb[i] : 0.f; return; }
  i -= 256;
  if (i < 4096) wpad[i] = 0;              // zero rows 192..255 of padded Wqkv
}

// ---------------- 128x128-tile bf16 GEMM via global_load_lds ---------------
// Linear LDS [128][32] (gload_lds needs contiguous dest). 2-barrier loop.
template<int RELU>
__global__ __launch_bounds__(256) void k_gemm128(
    const unsigned short* __restrict__ A, int lda,    // [M][lda] bf16
    const unsigned short* __restrict__ W, int K,      // [N][K] bf16
    const float* __restrict__ bias,
    unsigned short* __restrict__ C, int ldc, int Mclamp)
{
  __shared__ __align__(16) unsigned short As[128 * 32];
  __shared__ __align__(16) unsigned short Bs[128 * 32];
  int n0 = blockIdx.x * 128, m0 = blockIdx.y * 128;
  int t = threadIdx.x, wv = t >> 6, lane = t & 63;
  int fr = lane & 15, kg = lane >> 4;
  int wr = wv >> 1, wc = wv & 1;

  int il0 = wv * 128 + lane, il1 = il0 + 64;
  int ar0 = m0 + (il0 >> 2); if (ar0 >= Mclamp) ar0 = Mclamp - 1;
  int ar1 = m0 + (il1 >> 2); if (ar1 >= Mclamp) ar1 = Mclamp - 1;
  const unsigned short* gA0 = A + (size_t)ar0 * lda + (il0 & 3) * 8;
  const unsigned short* gA1 = A + (size_t)ar1 * lda + (il1 & 3) * 8;
  const unsigned short* gB0 = W + (size_t)(n0 + (il0 >> 2)) * K + (il0 & 3) * 8;
  const unsigned short* gB1 = W + (size_t)(n0 + (il1 >> 2)) * K + (il1 & 3) * 8;
  unsigned short* lA0 = &As[wv * 1024];
  unsigned short* lA1 = &As[wv * 1024 + 512];
  unsigned short* lB0 = &Bs[wv * 1024];
  unsigned short* lB1 = &Bs[wv * 1024 + 512];

  f32x4 acc[4][4];
#pragma unroll
  for (int mi = 0; mi < 4; ++mi)
#pragma unroll
    for (int ni = 0; ni < 4; ++ni) acc[mi][ni] = (f32x4){0.f, 0.f, 0.f, 0.f};

  for (int k0 = 0; k0 < K; k0 += 32) {
    __syncthreads();                        // prior reads of As/Bs complete
    GL16(gA0 + k0, lA0);
    GL16(gA1 + k0, lA1);
    GL16(gB0 + k0, lB0);
    GL16(gB1 + k0, lB1);
    __syncthreads();                        // vmcnt drained before barrier
    short8v af[4], bfv[4];
#pragma unroll
    for (int mi = 0; mi < 4; ++mi)
      af[mi] = *(const short8v*)&As[(wr * 64 + mi * 16 + fr) * 32 + kg * 8];
#pragma unroll
    for (int ni = 0; ni < 4; ++ni)
      bfv[ni] = *(const short8v*)&Bs[(wc * 64 + ni * 16 + fr) * 32 + kg * 8];
#pragma unroll
    for (int mi = 0; mi < 4; ++mi)
#pragma unroll
      for (int ni = 0; ni < 4; ++ni)
        acc[mi][ni] = __builtin_amdgcn_mfma_f32_16x16x32_bf16(af[mi], bfv[ni], acc[mi][ni], 0, 0, 0);
  }

#pragma unroll
  for (int ni = 0; ni < 4; ++ni) {
    int col = n0 + wc * 64 + ni * 16 + fr;
    float bb = bias[col];
#pragma unroll
    for (int mi = 0; mi < 4; ++mi) {
#pragma unroll
      for (int r = 0; r < 4; ++r) {
        int row = m0 + wr * 64 + mi * 16 + kg * 4 + r;
        float v = acc[mi][ni][r] + bb;
        if (RELU) v = fmaxf(v, 0.f);
        C[(size_t)row * ldc + col] = f2bf(v);
      }
    }
  }
}

// ---------------- fused item attention (R15/R16 best-measured version) ------
// 256 thr = 4 waves = 2 pairs x 2 halves. Natural-V buffer aliases Ps.
__global__ __launch_bounds__(256) void k_item_fused(
    const int* __restrict__ oh,
    const unsigned short* __restrict__ QKVall /*[VPAD][256] bf16*/,
    const float* __restrict__ wo /*[64][64] f32*/, const float* __restrict__ bob,
    unsigned short* __restrict__ X /*[B*O][64] bf16*/)
{
  __shared__ __align__(16) unsigned short QKs[2][20][144];
  __shared__ __align__(16) unsigned short VTs[2][64][36];
  __shared__ __align__(16) unsigned short Ps[4][24][36];   // staging: aliased as Vs[2][20][72]
  __shared__ __align__(16) float mAs[2][68];
  __shared__ int ids[2][20];

  int t = threadIdx.x, wv = t >> 6, lane = t & 63;
  int fr = lane & 15, lg = lane >> 4;
  int pr = wv >> 1, half = wv & 1;
  unsigned short (*Vs)[20][72] = (unsigned short (*)[20][72])&Ps[0][0][0];  // 5760B <= 6912B

  // index preload + VTs seq-pad zero (20..35)
  if (t < 40) ids[t / 20][t % 20] = oh[(size_t)(blockIdx.x * 2 + t / 20) * 20 + (t % 20)];
  {
    unsigned int* vz = (unsigned int*)&VTs[t >> 7][(t >> 1) & 63][20 + (t & 1) * 8];
    vz[0] = 0; vz[1] = 0; vz[2] = 0; vz[3] = 0;
  }
  __syncthreads();

  // ---- gather Q|K rows (b128): 2 pairs x 20 rows x 16 chunks = 640 jobs ----
  for (int e = t; e < 640; e += 256) {
    int pp = e / 320, rem = e - pp * 320;
    int row = rem >> 4, ch = (rem & 15) * 8;
    const unsigned short* src = QKVall + (size_t)ids[pp][row] * 256 + ch;
    *(ushort8v*)&QKs[pp][row][ch] = *(const ushort8v*)src;
  }
  // ---- gather V rows natural (b128): 2 x 20 x 8 chunks = 320 jobs ----
  for (int e = t; e < 320; e += 256) {
    int pp = e / 160, rem = e - pp * 160;
    int row = rem >> 3, ch = (rem & 7) * 8;
    const unsigned short* src = QKVall + (size_t)ids[pp][row] * 256 + 128 + ch;
    *(ushort8v*)&Vs[pp][row][ch] = *(const ushort8v*)src;
  }
  __syncthreads();

  // ---- transpose V in LDS: 2 pairs x 10 jpairs x 32 cpairs = 640 jobs ----
  for (int e = t; e < 640; e += 256) {
    int pp = e / 320, rem = e - pp * 320;
    int jp = rem >> 5, c0 = (rem & 31) * 2;
    unsigned int a = *(const unsigned int*)&Vs[pp][2 * jp][c0];
    unsigned int b = *(const unsigned int*)&Vs[pp][2 * jp + 1][c0];
    *(unsigned int*)&VTs[pp][c0][2 * jp]     = (a & 0xFFFFu) | (b << 16);
    *(unsigned int*)&VTs[pp][c0 + 1][2 * jp] = (a >> 16) | (b & 0xFFFF0000u);
  }
  __syncthreads();

  // per-wave zero of Ps[wv] rows 20..23 (read as zero-pad by AV A-frags)
  for (int e = lane; e < 72; e += 64) {
    int row = 20 + e / 18, col = (e - (e / 18) * 18) * 2;
    *(unsigned int*)&Ps[wv][row][col] = 0;
  }

  // ---- this half's 2 heads: S^T = K@Q^T, no-max softmax, AV via MFMA ----
  int rj1 = (fr + 16 < 20) ? fr + 16 : 19;
  bool iv1 = fr < 4;
  int pr1 = iv1 ? 16 + fr : 20;
#pragma unroll
  for (int hi = 0; hi < 2; ++hi) {
    int h = half * 2 + hi;
    short8v aK0, aK1, bQ0, bQ1;
    {
      short8v z = {0,0,0,0,0,0,0,0};
      aK0 = z; aK1 = z; bQ0 = z; bQ1 = z;
    }
    if (lg < 2) {
      aK0 = *(const short8v*)&QKs[pr][fr][64 + h * 16 + lg * 8];
      aK1 = *(const short8v*)&QKs[pr][rj1][64 + h * 16 + lg * 8];
      bQ0 = *(const short8v*)&QKs[pr][fr][h * 16 + lg * 8];
      bQ1 = *(const short8v*)&QKs[pr][rj1][h * 16 + lg * 8];
    }
    f32x4 s00 = {0.f,0.f,0.f,0.f}, s01 = {0.f,0.f,0.f,0.f};
    f32x4 s10 = {0.f,0.f,0.f,0.f}, s11 = {0.f,0.f,0.f,0.f};
    s00 = __builtin_amdgcn_mfma_f32_16x16x32_bf16(aK0, bQ0, s00, 0, 0, 0);
    s01 = __builtin_amdgcn_mfma_f32_16x16x32_bf16(aK0, bQ1, s01, 0, 0, 0);
    s10 = __builtin_amdgcn_mfma_f32_16x16x32_bf16(aK1, bQ0, s10, 0, 0, 0);
    s11 = __builtin_amdgcn_mfma_f32_16x16x32_bf16(aK1, bQ1, s11, 0, 0, 0);

    float e00[4], e01[4], e10[4], e11[4];
    float d0 = 0.f, d1 = 0.f;
#pragma unroll
    for (int r = 0; r < 4; ++r) {
      int j1 = 16 + lg * 4 + r;
      bool jv1 = j1 < 20;
      float v00 = __expf(0.25f * s00[r]);
      float v01 = iv1 ? __expf(0.25f * s01[r]) : 0.f;
      float v10 = jv1 ? __expf(0.25f * s10[r]) : 0.f;
      float v11 = (jv1 && iv1) ? __expf(0.25f * s11[r]) : 0.f;
      e00[r] = v00; e01[r] = v01; e10[r] = v10; e11[r] = v11;
      d0 += v00 + v10; d1 += v01 + v11;
    }
    d0 += __shfl_xor(d0, 16, 64); d0 += __shfl_xor(d0, 32, 64);
    d1 += __shfl_xor(d1, 16, 64); d1 += __shfl_xor(d1, 32, 64);
    float inv0 = __fdividef(1.f, d0);
    float inv1 = iv1 ? __fdividef(1.f, d1) : 0.f;

    *(unsigned int*)&Ps[wv][fr][lg * 4]          = pk2bf(e00[0]*inv0, e00[1]*inv0);
    *(unsigned int*)&Ps[wv][fr][lg * 4 + 2]      = pk2bf(e00[2]*inv0, e00[3]*inv0);
    *(unsigned int*)&Ps[wv][fr][16 + lg * 4]     = pk2bf(e10[0]*inv0, e10[1]*inv0);
    *(unsigned int*)&Ps[wv][fr][16 + lg * 4 + 2] = pk2bf(e10[2]*inv0, e10[3]*inv0);
    if (iv1) {
      *(unsigned int*)&Ps[wv][16 + fr][lg * 4]          = pk2bf(e01[0]*inv1, e01[1]*inv1);
      *(unsigned int*)&Ps[wv][16 + fr][lg * 4 + 2]      = pk2bf(e01[2]*inv1, e01[3]*inv1);
      *(unsigned int*)&Ps[wv][16 + fr][16 + lg * 4]     = pk2bf(e11[0]*inv1, e11[1]*inv1);
      *(unsigned int*)&Ps[wv][16 + fr][16 + lg * 4 + 2] = pk2bf(e11[2]*inv1, e11[3]*inv1);
    }

    short8v pa0, pa1, bV;
    {
      short4v l0 = *(const short4v*)&Ps[wv][fr][lg * 8];
      short4v h0 = *(const short4v*)&Ps[wv][fr][lg * 8 + 4];
      short4v l1 = *(const short4v*)&Ps[wv][pr1][lg * 8];
      short4v h1 = *(const short4v*)&Ps[wv][pr1][lg * 8 + 4];
      short4v lv = *(const short4v*)&VTs[pr][h * 16 + fr][lg * 8];
      short4v hv = *(const short4v*)&VTs[pr][h * 16 + fr][lg * 8 + 4];
      pa0[0]=l0[0]; pa0[1]=l0[1]; pa0[2]=l0[2]; pa0[3]=l0[3];
      pa0[4]=h0[0]; pa0[5]=h0[1]; pa0[6]=h0[2]; pa0[7]=h0[3];
      pa1[0]=l1[0]; pa1[1]=l1[1]; pa1[2]=l1[2]; pa1[3]=l1[3];
      pa1[4]=h1[0]; pa1[5]=h1[1]; pa1[6]=h1[2]; pa1[7]=h1[3];
      bV[0]=lv[0]; bV[1]=lv[1]; bV[2]=lv[2]; bV[3]=lv[3];
      bV[4]=hv[0]; bV[5]=hv[1]; bV[6]=hv[2]; bV[7]=hv[3];
    }
    f32x4 m20 = {0.f,0.f,0.f,0.f}, m21 = {0.f,0.f,0.f,0.f};
    m20 = __builtin_amdgcn_mfma_f32_16x16x32_bf16(pa0, bV, m20, 0, 0, 0);
    m21 = __builtin_amdgcn_mfma_f32_16x16x32_bf16(pa1, bV, m21, 0, 0, 0);

    float sm = m20[0] + m20[1] + m20[2] + m20[3];
    if (lg == 0) sm += m21[0] + m21[1] + m21[2] + m21[3];
    sm += __shfl_xor(sm, 16, 64);
    sm += __shfl_xor(sm, 32, 64);
    if (lg == 0) mAs[pr][h * 16 + fr] = sm * 0.05f;
  }
  __syncthreads();

  // ---- out-proj of the mean: 128 threads = 2 pairs x 64 cols, bf16 out ----
  if (t < 128) {
    int p2 = t >> 6, col = t & 63;
    float acc = bob[col];
    const float* wrow = &wo[(size_t)col * 64];
    for (int k = 0; k < 64; k += 4) {
      float4 m4 = *(const float4*)&mAs[p2][k];
      float4 w4 = *(const float4*)(wrow + k);
      acc += m4.x * w4.x + m4.y * w4.y + m4.z * w4.z + m4.w * w4.w;
    }
    X[(size_t)(blockIdx.x * 2 + p2) * 64 + col] = f2bf(acc);
  }
}

// ---------------- GRU recurrence (bf16 G output, full batch) ----------------
__global__ __launch_bounds__(512) void k_gru_mfma(
    const unsigned short* __restrict__ GI,   // [B*O][768]: 0-383 fwd, 384-767 bwd
    const unsigned short* __restrict__ whf,
    const unsigned short* __restrict__ whb,
    const float* __restrict__ bh_f, const float* __restrict__ bh_b,
    unsigned short* __restrict__ G /*[B*O][256] bf16*/)
{
  __shared__ unsigned short hsb[16][136];
  __shared__ float ah[4][392];

  int bid = blockIdx.x;
  int dir = bid >> 8;            // 256 row-groups per dir
  int rg  = bid & 255;
  const unsigned short* wh = dir ? whb : whf;
  const float* bh = dir ? bh_b : bh_f;

  int t = threadIdx.x;
  int w = t >> 6, lane = t & 63;
  int fr = lane & 15, kg = lane >> 4;

  short8v bfr[3][4];
#pragma unroll
  for (int n = 0; n < 3; ++n)
#pragma unroll
    for (int kf = 0; kf < 4; ++kf)
      bfr[n][kf] = *(const short8v*)&wh[(size_t)(w * 48 + n * 16 + fr) * 128 + kf * 32 + kg * 8];

  for (int e = t; e < 16 * 136; e += 512) ((unsigned short*)hsb)[e] = 0;

  int grow = t >> 7, gc = t & 127;
  float bh0 = bh[gc], bh1 = bh[128 + gc], bh2 = bh[256 + gc];
  float hold = 0.f;
  const unsigned short* gip = &GI[(size_t)(rg * 4 + grow) * 50 * 768 + dir * 384];
  unsigned short* gout = &G[((size_t)(rg * 4 + grow) * 50) * 256 + dir * 128 + gc];

  __syncthreads();

  int o0 = dir ? 49 : 0;
  unsigned short c0v = gip[(size_t)o0 * 768 + gc];
  unsigned short c1v = gip[(size_t)o0 * 768 + 128 + gc];
  unsigned short c2v = gip[(size_t)o0 * 768 + 256 + gc];

  for (int s = 0; s < 50; ++s) {
    int o  = dir ? 49 - s : s;
    unsigned short n0v = 0, n1v = 0, n2v = 0;
    if (s < 49) {
      int on = dir ? 48 - s : s + 1;
      n0v = gip[(size_t)on * 768 + gc];
      n1v = gip[(size_t)on * 768 + 128 + gc];
      n2v = gip[(size_t)on * 768 + 256 + gc];
    }

    short8v a0 = *(const short8v*)&hsb[fr][0 * 32 + kg * 8];
    short8v a1 = *(const short8v*)&hsb[fr][1 * 32 + kg * 8];
    short8v a2 = *(const short8v*)&hsb[fr][2 * 32 + kg * 8];
    short8v a3 = *(const short8v*)&hsb[fr][3 * 32 + kg * 8];

    f32x4 acc0 = {0.f,0.f,0.f,0.f}, acc1 = {0.f,0.f,0.f,0.f}, acc2 = {0.f,0.f,0.f,0.f};
    acc0 = __builtin_amdgcn_mfma_f32_16x16x32_bf16(a0, bfr[0][0], acc0, 0, 0, 0);
    acc1 = __builtin_amdgcn_mfma_f32_16x16x32_bf16(a0, bfr[1][0], acc1, 0, 0, 0);
    acc2 = __builtin_amdgcn_mfma_f32_16x16x32_bf16(a0, bfr[2][0], acc2, 0, 0, 0);
    acc0 = __builtin_amdgcn_mfma_f32_16x16x32_bf16(a1, bfr[0][1], acc0, 0, 0, 0);
    acc1 = __builtin_amdgcn_mfma_f32_16x16x32_bf16(a1, bfr[1][1], acc1, 0, 0, 0);
    acc2 = __builtin_amdgcn_mfma_f32_16x16x32_bf16(a1, bfr[2][1], acc2, 0, 0, 0);
    acc0 = __builtin_amdgcn_mfma_f32_16x16x32_bf16(a2, bfr[0][2], acc0, 0, 0, 0);
    acc1 = __builtin_amdgcn_mfma_f32_16x16x32_bf16(a2, bfr[1][2], acc1, 0, 0, 0);
    acc2 = __builtin_amdgcn_mfma_f32_16x16x32_bf16(a2, bfr[2][2], acc2, 0, 0, 0);
    acc0 = __builtin_amdgcn_mfma_f32_16x16x32_bf16(a3, bfr[0][3], acc0, 0, 0, 0);
    acc1 = __builtin_amdgcn_mfma_f32_16x16x32_bf16(a3, bfr[1][3], acc1, 0, 0, 0);
    acc2 = __builtin_amdgcn_mfma_f32_16x16x32_bf16(a3, bfr[2][3], acc2, 0, 0, 0);

    if (kg == 0) {
#pragma unroll
      for (int r = 0; r < 4; ++r) {
        ah[r][w * 48 + 0 * 16 + fr] = acc0[r];
        ah[r][w * 48 + 1 * 16 + fr] = acc1[r];
        ah[r][w * 48 + 2 * 16 + fr] = acc2[r];
      }
    }
    __syncthreads();

    float ai0 = bf2f(c0v), ai1 = bf2f(c1v), ai2 = bf2f(c2v);
    float ah0 = ah[grow][gc] + bh0;
    float ah1 = ah[grow][128 + gc] + bh1;
    float ah2 = ah[grow][256 + gc] + bh2;
    float rr = sig_(ai0 + ah0);
    float zz = sig_(ai1 + ah1);
    float nn = tanh_(ai2 + rr * ah2);
    float h2 = (1.f - zz) * nn + zz * hold;
    hold = h2;
    unsigned short hb = f2bf(h2);
    hsb[grow][gc] = hb;
    gout[(size_t)o * 256] = hb;
    c0v = n0v; c1v = n1v; c2v = n2v;
    __syncthreads();
  }
}

// ---------------- transformer attention core v2 (MFMA, in-place) ------------
__global__ __launch_bounds__(256) void k_attn_core(unsigned short* __restrict__ BIG)
{
  __shared__ __align__(16) unsigned short Qs[64][72];
  __shared__ __align__(16) unsigned short Ks[64][72];
  __shared__ __align__(16) unsigned short VTs[64][72];   // [d][j]
  __shared__ __align__(16) unsigned short Ps[4][16][72]; // per-wave P[i][j]
  unsigned short (*Vs)[64] = (unsigned short (*)[64])&Ps[0][0][0];  // [50][64] alias

  int bl = blockIdx.x >> 2, h = blockIdx.x & 3;
  int t = threadIdx.x, wv = t >> 6, lane = t & 63;
  int fr = lane & 15, lg = lane >> 4;
  size_t base = (size_t)bl * 50 * 768;
  int hc = h * 64;

  for (int e = t; e < 504; e += 256) {
    int r = e / 36, c = (e - r * 36) * 2;
    *(unsigned int*)&Qs[50 + r][c] = 0;
    *(unsigned int*)&Ks[50 + r][c] = 0;
  }
  for (int e = t; e < 2304; e += 256) {
    int r = e / 36, c = (e - r * 36) * 2;
    *(unsigned int*)&VTs[r][c] = 0;
  }
  __syncthreads();

  for (int e = t; e < 400; e += 256) {
    int row = e >> 3, ch = (e & 7) * 8;
    *(ushort8v*)&Qs[row][ch] = *(const ushort8v*)&BIG[base + (size_t)row * 768 + hc + ch];
  }
  for (int e = t; e < 400; e += 256) {
    int row = e >> 3, ch = (e & 7) * 8;
    *(ushort8v*)&Ks[row][ch] = *(const ushort8v*)&BIG[base + (size_t)row * 768 + 256 + hc + ch];
  }
  for (int e = t; e < 400; e += 256) {
    int row = e >> 3, ch = (e & 7) * 8;
    *(ushort8v*)&Vs[row][ch] = *(const ushort8v*)&BIG[base + (size_t)row * 768 + 512 + hc + ch];
  }
  __syncthreads();

  for (int e = t; e < 800; e += 256) {
    int jp = e >> 5, c0 = (e & 31) * 2;
    unsigned int a = *(const unsigned int*)&Vs[2 * jp][c0];
    unsigned int b = *(const unsigned int*)&Vs[2 * jp + 1][c0];
    *(unsigned int*)&VTs[c0][2 * jp]     = (a & 0xFFFFu) | (b << 16);
    *(unsigned int*)&VTs[c0 + 1][2 * jp] = (a >> 16) | (b & 0xFFFF0000u);
  }
  __syncthreads();

  int i0 = wv * 16;
  short8v bQ0 = *(const short8v*)&Qs[i0 + fr][lg * 8];
  short8v bQ1 = *(const short8v*)&Qs[i0 + fr][32 + lg * 8];

  f32x4 s[4];
#pragma unroll
  for (int jt = 0; jt < 4; ++jt) {
    short8v aK0 = *(const short8v*)&Ks[jt * 16 + fr][lg * 8];
    short8v aK1 = *(const short8v*)&Ks[jt * 16 + fr][32 + lg * 8];
    f32x4 acc = {0.f, 0.f, 0.f, 0.f};
    acc = __builtin_amdgcn_mfma_f32_16x16x32_bf16(aK0, bQ0, acc, 0, 0, 0);
    acc = __builtin_amdgcn_mfma_f32_16x16x32_bf16(aK1, bQ1, acc, 0, 0, 0);
    s[jt] = acc;
  }

  float m = -1e30f;
#pragma unroll
  for (int jt = 0; jt < 4; ++jt)
#pragma unroll
    for (int r = 0; r < 4; ++r) {
      int j = jt * 16 + lg * 4 + r;
      float v = s[jt][r] * 0.125f;
      if (j < 50) m = fmaxf(m, v);
    }
  m = fmaxf(m, __shfl_xor(m, 16, 64));
  m = fmaxf(m, __shfl_xor(m, 32, 64));

  float ev[4][4];
  float den = 0.f;
#pragma unroll
  for (int jt = 0; jt < 4; ++jt)
#pragma unroll
    for (int r = 0; r < 4; ++r) {
      int j = jt * 16 + lg * 4 + r;
      float e = (j < 50) ? __expf(s[jt][r] * 0.125f - m) : 0.f;
      ev[jt][r] = e;
      den += e;
    }
  den += __shfl_xor(den, 16, 64);
  den += __shfl_xor(den, 32, 64);
  float inv = __fdividef(1.f, den);

#pragma unroll
  for (int jt = 0; jt < 4; ++jt) {
    *(unsigned int*)&Ps[wv][fr][jt * 16 + lg * 4]     = pk2bf(ev[jt][0] * inv, ev[jt][1] * inv);
    *(unsigned int*)&Ps[wv][fr][jt * 16 + lg * 4 + 2] = pk2bf(ev[jt][2] * inv, ev[jt][3] * inv);
  }

  short8v pa0 = *(const short8v*)&Ps[wv][fr][lg * 8];
  short8v pa1 = *(const short8v*)&Ps[wv][fr][32 + lg * 8];
#pragma unroll
  for (int dt = 0; dt < 4; ++dt) {
    short8v bV0 = *(const short8v*)&VTs[dt * 16 + fr][lg * 8];
    short8v bV1 = *(const short8v*)&VTs[dt * 16 + fr][32 + lg * 8];
    f32x4 o = {0.f, 0.f, 0.f, 0.f};
    o = __builtin_amdgcn_mfma_f32_16x16x32_bf16(pa0, bV0, o, 0, 0, 0);
    o = __builtin_amdgcn_mfma_f32_16x16x32_bf16(pa1, bV1, o, 0, 0, 0);
#pragma unroll
    for (int r = 0; r < 4; ++r) {
      int i = i0 + lg * 4 + r;
      if (i < 50)
        BIG[base + (size_t)i * 768 + hc + dt * 16 + fr] = f2bf(o[r]);
    }
  }
}

// ---------------- fused residual + LayerNorm (bf16 I/O, wave per row) -------
__global__ __launch_bounds__(256) void k_ln_res(
    const unsigned short* __restrict__ res, const unsigned short* __restrict__ add,
    int addld, unsigned short* __restrict__ dst,
    const float* __restrict__ g, const float* __restrict__ bt)
{
  int row = blockIdx.x * 4 + (threadIdx.x >> 6);
  int lane = threadIdx.x & 63;
  int c = lane * 4;
  ushort4v rv = *(const ushort4v*)&res[(size_t)row * 256 + c];
  ushort4v av = *(const ushort4v*)&add[(size_t)row * addld + c];
  float x0 = bf2f(rv[0]) + bf2f(av[0]);
  float x1 = bf2f(rv[1]) + bf2f(av[1]);
  float x2 = bf2f(rv[2]) + bf2f(av[2]);
  float x3 = bf2f(rv[3]) + bf2f(av[3]);
  float s = x0 + x1 + x2 + x3;
  float sq = x0 * x0 + x1 * x1 + x2 * x2 + x3 * x3;
#pragma unroll
  for (int d = 1; d < 64; d <<= 1) { s += __shfl_xor(s, d, 64); sq += __shfl_xor(sq, d, 64); }
  float m = s * (1.f / 256.f);
  float var = sq * (1.f / 256.f) - m * m;
  float rs = rsqrtf(var + 1e-5f);
  float4 gv = *(const float4*)&g[c];
  float4 bv = *(const float4*)&bt[c];
  ushort4v ov;
  ov[0] = f2bf((x0 - m) * rs * gv.x + bv.x);
  ov[1] = f2bf((x1 - m) * rs * gv.y + bv.y);
  ov[2] = f2bf((x2 - m) * rs * gv.z + bv.z);
  ov[3] = f2bf((x3 - m) * rs * gv.w + bv.w);
  *(ushort4v*)&dst[(size_t)row * 256 + c] = ov;
}

// ---------------- temporal encoder + O-mean + final classifier (fused) ------
__global__ __launch_bounds__(256) void k_heads(
    const unsigned short* __restrict__ H2 /*[B*O][256] bf16*/,
    const float* __restrict__ daysb, const float* __restrict__ dayss,
    const float* __restrict__ te1_w, const float* __restrict__ te1_b,
    const float* __restrict__ ln1g, const float* __restrict__ ln1b,
    const float* __restrict__ te2_w, const float* __restrict__ te2_b,
    const float* __restrict__ ln2g, const float* __restrict__ ln2b,
    const float* __restrict__ cWT /*[320][128]*/,
    const float* __restrict__ c_b, const float* __restrict__ clng,
    const float* __restrict__ clnb, float* __restrict__ out)
{
  __shared__ float oe[256];
  __shared__ float feat[2];
  __shared__ float s1[32], s2[64], pre[128], stat[2];
  int b = blockIdx.x, t = threadIdx.x;
  {
    float s = 0.f;
    for (int o = 0; o < 50; ++o) s += bf2f(H2[((size_t)b * 50 + o) * 256 + t]);
    oe[t] = s * 0.02f;
  }
  if (t == 0) {
    float f0 = 0.f;
    for (int i = 0; i < 10; ++i) f0 += daysb[b * 10 + i];
    feat[0] = f0 * 0.1f;
    feat[1] = dayss[b];
  }
  __syncthreads();
  if (t < 32) s1[t] = te1_b[t] + feat[0] * te1_w[2 * t] + feat[1] * te1_w[2 * t + 1];
  __syncthreads();
  if (t == 0) {
    float s = 0.f; for (int j = 0; j < 32; ++j) s += s1[j];
    float m = s * (1.f / 32.f);
    float v = 0.f; for (int j = 0; j < 32; ++j) { float d = s1[j] - m; v += d * d; }
    stat[0] = m; stat[1] = rsqrtf(v * (1.f / 32.f) + 1e-5f);
  }
  __syncthreads();
  if (t < 32) s1[t] = fmaxf((s1[t] - stat[0]) * stat[1] * ln1g[t] + ln1b[t], 0.f);
  __syncthreads();
  if (t < 64) {
    float a = te2_b[t];
    for (int k = 0; k < 32; ++k) a += s1[k] * te2_w[t * 32 + k];
    s2[t] = a;
  }
  __syncthreads();
  if (t == 0) {
    float s = 0.f; for (int j = 0; j < 64; ++j) s += s2[j];
    float m = s * (1.f / 64.f);
    float v = 0.f; for (int j = 0; j < 64; ++j) { float d = s2[j] - m; v += d * d; }
    stat[0] = m; stat[1] = rsqrtf(v * (1.f / 64.f) + 1e-5f);
  }
  __syncthreads();
  if (t < 64) s2[t] = fmaxf((s2[t] - stat[0]) * stat[1] * ln2g[t] + ln2b[t], 0.f);
  __syncthreads();
  if (t < 128) {
    float p = c_b[t];
    for (int k = 0; k < 256; ++k) p += oe[k] * cWT[k * 128 + t];
    for (int k = 0; k < 64; ++k)  p += s2[k] * cWT[(256 + k) * 128 + t];
    pre[t] = p;
  }
  __syncthreads();
  if (t == 0) {
    float s = 0.f; for (int j = 0; j < 128; ++j) s += pre[j];
    float m = s * (1.f / 128.f);
    float v = 0.f; for (int j = 0; j < 128; ++j) { float d = pre[j] - m; v += d * d; }
    stat[0] = m; stat[1] = rsqrtf(v * (1.f / 128.f) + 1e-5f);
  }
  __syncthreads();
  if (t < 128)
    out[(size_t)b * 128 + t] = fmaxf((pre[t] - stat[0]) * stat[1] * clng[t] + clnb[t], 0.f);
}

// ---------------- host launcher ----------------
extern "C" void kernel_launch(void* const* d_in, const int* in_sizes, int n_in,
                              void* d_out, int out_size, void* d_ws, size_t ws_size,
                              hipStream_t stream)
{
  const int*   oh       = (const int*)d_in[0];
  const float* daysb    = (const float*)d_in[1];
  const float* dayss    = (const float*)d_in[2];
  const float* emb      = (const float*)d_in[3];
  const float* ia_in_w  = (const float*)d_in[4];
  const float* ia_in_b  = (const float*)d_in[5];
  const float* ia_out_w = (const float*)d_in[6];
  const float* ia_out_b = (const float*)d_in[7];
  const float* gf_wi = (const float*)d_in[8];
  const float* gf_wh = (const float*)d_in[9];
  const float* gf_bi = (const float*)d_in[10];
  const float* gf_bh = (const float*)d_in[11];
  const float* gb_wi = (const float*)d_in[12];
  const float* gb_wh = (const float*)d_in[13];
  const float* gb_bi = (const float*)d_in[14];
  const float* gb_bh = (const float*)d_in[15];
  const float* ta_in_w  = (const float*)d_in[16];
  const float* ta_in_b  = (const float*)d_in[17];
  const float* ta_out_w = (const float*)d_in[18];
  const float* ta_out_b = (const float*)d_in[19];
  const float* t_ln1_g = (const float*)d_in[20];
  const float* t_ln1_b = (const float*)d_in[21];
  const float* t_ln2_g = (const float*)d_in[22];
  const float* t_ln2_b = (const float*)d_in[23];
  const float* t_ff1_w = (const float*)d_in[24];
  const float* t_ff1_b = (const float*)d_in[25];
  const float* t_ff2_w = (const float*)d_in[26];
  const float* t_ff2_b = (const float*)d_in[27];
  const float* te1_w = (const float*)d_in[28];
  const float* te1_b = (const float*)d_in[29];
  const float* te_ln1_g = (const float*)d_in[30];
  const float* te_ln1_b = (const float*)d_in[31];
  const float* te2_w = (const float*)d_in[32];
  const float* te2_b = (const float*)d_in[33];
  const float* te_ln2_g = (const float*)d_in[34];
  const float* te_ln2_b = (const float*)d_in[35];
  const float* c_w   = (const float*)d_in[36];
  const float* c_b   = (const float*)d_in[37];
  const float* c_ln_g = (const float*)d_in[38];
  const float* c_ln_b = (const float*)d_in[39];

  float* ws = (float*)d_ws;
  // layout (floats):
  const size_t OFF_GB   = 0;                        // G bf16 [51200][256] = 6,553,600 fl
  const size_t OFF_X    = 6553600;                  // X bf16 [51200][64]  = 1,638,400 fl
  const size_t OFF_S    = OFF_X + 1638400;          // QKVall | GI | BIGb  = 19,660,800 fl
  const size_t OW_C     = OFF_S + 19660800;         // [320][128] 40,960
  const size_t OW_BC    = OW_C + 40960;             // 768
  const size_t OW_BQ    = OW_BC + 768;              // padded qkv bias 256
  const size_t OW_BF    = OW_BQ + 256;              // bf16 weight pool 344,064 fl
  const size_t OW_EMB   = OW_BF + 344064;           // bf16 emb table 1,590,048 fl
  const size_t TOTAL    = OW_EMB + 1590048;         // 29,828,896 fl = 119.3 MB
  if (ws_size < TOTAL * sizeof(float)) return;

  unsigned short* Gb = (unsigned short*)(ws + OFF_GB);
  unsigned short* Xb = (unsigned short*)(ws + OFF_X);
  float* w_c  = ws + OW_C;
  float* biascat = ws + OW_BC;
  float* biasq   = ws + OW_BQ;
  unsigned short* bfp = (unsigned short*)(ws + OW_BF);
  unsigned short* b_ta_in  = bfp;                  // 196,608
  unsigned short* b_ta_out = b_ta_in + 196608;     //  65,536
  unsigned short* b_ff1    = b_ta_out + 65536;     // 131,072
  unsigned short* b_ff2    = b_ff1 + 131072;       // 131,072
  unsigned short* b_qkvw   = b_ff2 + 131072;       //  16,384 (padded [256][64])
  unsigned short* b_wi_f   = b_qkvw + 16384;       //  24,576 ── Wcat [768][64]
  unsigned short* b_wi_b   = b_wi_f + 24576;       //  24,576 ──┘
  unsigned short* b_wh_f   = b_wi_b + 24576;       //  49,152
  unsigned short* b_wh_b   = b_wh_f + 49152;       //  49,152
  unsigned short* embb = (unsigned short*)(ws + OW_EMB);  // [(V+1)][64] bf16

  // scratch phase views (aliased; QKVall dead before GI is written):
  unsigned short* QKVall = (unsigned short*)(ws + OFF_S); // [VPAD][256] bf16 (25.5MB)
  unsigned short* GI     = (unsigned short*)(ws + OFF_S); // gru: [51200][768] bf16
  unsigned short* BIGb   = (unsigned short*)(ws + OFF_S); // transformer: [51200][768]

  // ---- prologue: 2 launches ----
  k_prep_small<<<(40960 + 768 + 256 + 4096 + 255) / 256, 256, 0, stream>>>(
      c_w, w_c, gf_bi, gb_bi, biascat, ia_in_b, biasq, b_qkvw + 12288);
  {
    CvArgs a;
    a.src[0] = ta_in_w;  a.dst[0] = b_ta_in;  a.n[0] = 196608;
    a.src[1] = ta_out_w; a.dst[1] = b_ta_out; a.n[1] = 65536;
    a.src[2] = t_ff1_w;  a.dst[2] = b_ff1;    a.n[2] = 131072;
    a.src[3] = t_ff2_w;  a.dst[3] = b_ff2;    a.n[3] = 131072;
    a.src[4] = ia_in_w;  a.dst[4] = b_qkvw;   a.n[4] = 12288;
    a.src[5] = gf_wi;    a.dst[5] = b_wi_f;   a.n[5] = 24576;
    a.src[6] = gb_wi;    a.dst[6] = b_wi_b;   a.n[6] = 24576;
    a.src[7] = gf_wh;    a.dst[7] = b_wh_f;   a.n[7] = 49152;
    a.src[8] = gb_wh;    a.dst[8] = b_wh_b;   a.n[8] = 49152;
    a.src[9] = emb;      a.dst[9] = embb;     a.n[9] = 3180096;
    int total = 196608 + 65536 + 131072 + 131072 + 12288 + 24576 + 24576 + 49152 + 49152 + 3180096;
    k_cv_multi<<<(total + 255) / 256, 256, 0, stream>>>(a);
  }

  // ---- precompute QKVall = embb @ Wqkv^T + b (vocab-wide, once) ----
  k_gemm128<0><<<dim3(256 / 128, VPAD / 128), 256, 0, stream>>>(
      embb, 64, b_qkvw, 64, biasq, QKVall, 256, VROWS);

  // ---- item attention: gather + attend (2 pairs/block) ----
  k_item_fused<<<B_ * O_ / 2, 256, 0, stream>>>(oh, QKVall, ia_out_w, ia_out_b, Xb);

  // ---- bidirectional GRU: single chunk over full batch ----
  k_gemm128<0><<<dim3(768 / 128, 51200 / 128), 256, 0, stream>>>(
      Xb, 64, b_wi_f /*Wcat [768][64]*/, 64, biascat, GI, 768, 51200);
  k_gru_mfma<<<512, 512, 0, stream>>>(GI, b_wh_f, b_wh_b, gf_bh, gb_bh, Gb);

  // ---- transformer layer: single chunk, bf16, in-place in BIGb ----
  k_gemm128<0><<<dim3(768 / 128, 51200 / 128), 256, 0, stream>>>(
      Gb, 256, b_ta_in, 256, ta_in_b, BIGb, 768, 51200);
  k_attn_core<<<B_ * 4, 256, 0, stream>>>(BIGb);
  k_gemm128<0><<<dim3(256 / 128, 51200 / 128), 256, 0, stream>>>(
      BIGb, 768, b_ta_out, 256, ta_out_b, BIGb + 256, 768, 51200);
  k_ln_res<<<51200 / 4, 256, 0, stream>>>(Gb, BIGb + 256, 768, Gb, t_ln1_g, t_ln1_b);
  k_gemm128<1><<<dim3(512 / 128, 51200 / 128), 256, 0, stream>>>(
      Gb, 256, b_ff1, 256, t_ff1_b, BIGb, 768, 51200);
  k_gemm128<0><<<dim3(256 / 128, 51200 / 128), 256, 0, stream>>>(
      BIGb, 768, b_ff2, 512, t_ff2_b, BIGb + 512, 768, 51200);
  k_ln_res<<<51200 / 4, 256, 0, stream>>>(Gb, BIGb + 512, 768, Gb, t_ln2_g, t_ln2_b);

  // ---- fused O-mean + temporal encoder + classifier ----
  k_heads<<<B_, 256, 0, stream>>>(Gb, daysb, dayss, te1_w, te1_b, te_ln1_g, te_ln1_b,
                                  te2_w, te2_b, te_ln2_g, te_ln2_b,
                                  w_c, c_b, c_ln_g, c_ln_b, (float*)d_out);
}